// Round 3
// baseline (106813.000 us; speedup 1.0000x reference)
//
#include <hip/hip_runtime.h>
#include <cstddef>

// Sparse 3D CNN. Adaptive batch-group pipeline (G in {8,4,2,1} chosen from ws_size).
// Spatial chain per item:
// 50,60,65 -> c1 47,57,62 -> c2 44,54,59 -> p1 40,50,55 -> c3 37,47,52
// -> c4 34,44,49 -> p2 30,40,45 -> c5 27,37,42 -> c6 24,34,39 -> c7 21,31,36
// -> p3 17,27,32 ; flatten 14688 -> FC 1000 -> 1000 -> 1

#define NEGSLOPE 0.01f
#define NINF (-3.0e38f)

__device__ __forceinline__ float lrelu(float v) { return v >= 0.f ? v : NEGSLOPE * v; }

// ---------------- scatter (last-write-wins), full batch ----------------
__global__ void k_claim(const int* __restrict__ coors, unsigned* __restrict__ claim, int N) {
  int i = blockIdx.x * blockDim.x + threadIdx.x;
  if (i >= N) return;
  int b = coors[4*i], z = coors[4*i+1], y = coors[4*i+2], x = coors[4*i+3];
  int v = ((b*50 + z)*60 + y)*65 + x;
  atomicMax(&claim[v], (unsigned)(i + 1));
}

__global__ void k_scatter(const int* __restrict__ coors, const float* __restrict__ feat,
                          const unsigned* __restrict__ claim,
                          float* __restrict__ x0, float* __restrict__ m0, int N) {
  int i = blockIdx.x * blockDim.x + threadIdx.x;
  if (i >= N) return;
  int b = coors[4*i], z = coors[4*i+1], y = coors[4*i+2], x = coors[4*i+3];
  int v = ((b*50 + z)*60 + y)*65 + x;
  m0[v] = 1.f;
  if (claim[v] == (unsigned)(i + 1)) x0[v] = feat[i];
}

// ---------------- weight repack: w[co][ci][k64] -> wr[k64][ci][co] ----------------
__global__ void k_repack(const float* __restrict__ w, float* __restrict__ wr, int CI, int CO) {
  int i = blockIdx.x * blockDim.x + threadIdx.x;
  int tot = CO * CI * 64;
  if (i >= tot) return;
  int k = i & 63;
  int ci = (i >> 6) % CI;
  int co = i / (64 * CI);
  wr[(k * CI + ci) * CO + co] = w[i];
}

// ---------------- batched mask dilation (window K, VALID) ----------------
__global__ void k_dilate(const float* __restrict__ m, float* __restrict__ o,
                         int Zi, int Yi, int Xi, int Zo, int Yo, int Xo, int K, int nI) {
  int gid = blockIdx.x * blockDim.x + threadIdx.x;
  int perOut = Zo * Yo * Xo;
  int tot = nI * perOut;
  if (gid >= tot) return;
  int item = gid / perOut;
  int r = gid - item * perOut;
  int x = r % Xo; int t = r / Xo;
  int y = t % Yo; int z = t / Yo;
  const float* mb = m + (size_t)item * Zi * Yi * Xi;
  float mx = 0.f;
  for (int dz = 0; dz < K; dz++)
    for (int dy = 0; dy < K; dy++) {
      const float* row = mb + (size_t)(((z + dz)*Yi + y + dy)*Xi + x);
      for (int dx = 0; dx < K; dx++) mx = fmaxf(mx, row[dx]);
    }
  o[gid] = mx;
}

// ---------------- tiled conv 32->32: 128 thr, V voxels/thread, LDS 8-tap weight slabs
template<int V>
__global__ void k_conv32t(const float* __restrict__ in, const float* __restrict__ wr,
                          const float* __restrict__ bias, const float* __restrict__ mo,
                          float* __restrict__ out,
                          int Zi, int Yi, int Xi, int Zo, int Yo, int Xo, int nI) {
  __shared__ float wsh[8192];   // 8 taps x 32ci x 32co
  const int perOut = Zo * Yo * Xo;
  const int perIn  = Zi * Yi * Xi;
  const int total  = nI * perOut;
  const int tid = threadIdx.x;   // 0..127
  int vb = blockIdx.x * (128 * V) + tid;

  int inoff[V], outv[V];
#pragma unroll
  for (int i = 0; i < V; ++i) {
    int v = vb + i * 128;
    if (v < total) {
      int item = v / perOut;
      int r = v - item * perOut;
      int x = r % Xo; int t = r / Xo;
      int y = t % Yo; int z = t / Yo;
      inoff[i] = (item * perIn + (z * Yi + y) * Xi + x) * 32;
      outv[i] = v;
    } else { inoff[i] = 0; outv[i] = -1; }
  }

  float acc[V][32];
#pragma unroll
  for (int i = 0; i < V; ++i)
#pragma unroll
    for (int c = 0; c < 32; ++c) acc[i][c] = 0.f;

#pragma unroll 1
  for (int sl = 0; sl < 8; ++sl) {
    __syncthreads();
    {
      const float* src = wr + sl * 8192;
      for (int idx = tid; idx < 2048; idx += 128)
        *(float4*)(wsh + idx * 4) = *(const float4*)(src + idx * 4);
    }
    __syncthreads();
#pragma unroll 1
    for (int t8 = 0; t8 < 8; ++t8) {
      int tap = sl * 8 + t8;
      int kz = tap >> 4, ky = (tap >> 2) & 3, kx = tap & 3;
      int tapoff = ((kz * Yi + ky) * Xi + kx) * 32;
      const float* wt = wsh + t8 * 1024;
      int base[V];
#pragma unroll
      for (int i = 0; i < V; ++i) base[i] = inoff[i] + tapoff;
#pragma unroll 2
      for (int ci4 = 0; ci4 < 8; ++ci4) {
        float4 a[V];
#pragma unroll
        for (int i = 0; i < V; ++i)
          a[i] = *(const float4*)(in + base[i] + ci4 * 4);
#pragma unroll
        for (int u = 0; u < 4; ++u) {
          const float* wrow = wt + (ci4 * 4 + u) * 32;
          float w[32];
#pragma unroll
          for (int j = 0; j < 8; ++j)
            *(float4*)(w + 4 * j) = *(const float4*)(wrow + 4 * j);
#pragma unroll
          for (int i = 0; i < V; ++i) {
            float vv = (u == 0) ? a[i].x : (u == 1) ? a[i].y : (u == 2) ? a[i].z : a[i].w;
#pragma unroll
            for (int c = 0; c < 32; ++c) acc[i][c] = fmaf(vv, w[c], acc[i][c]);
          }
        }
      }
    }
  }

#pragma unroll
  for (int i = 0; i < V; ++i) {
    if (outv[i] < 0) continue;
    bool act = mo[outv[i]] > 0.f;
    float* op = out + (size_t)outv[i] * 32;
#pragma unroll
    for (int c = 0; c < 32; ++c) {
      float r = act ? (acc[i][c] + bias[c]) : 0.f;
      acc[i][c] = lrelu(r);
    }
#pragma unroll
    for (int j = 0; j < 8; ++j)
      *(float4*)(op + 4 * j) = *(const float4*)(&acc[i][4 * j]);
  }
}

// ---------------- conv 1->32 (c1): 256 thr, 2 voxels/thread, weights fully in LDS ---
__global__ void k_conv1(const float* __restrict__ in, const float* __restrict__ wr,
                        const float* __restrict__ bias, const float* __restrict__ mo,
                        float* __restrict__ out,
                        int Zi, int Yi, int Xi, int Zo, int Yo, int Xo, int nI) {
  __shared__ float wsh[2048];   // 64 taps x 32 co
  for (int idx = threadIdx.x; idx < 512; idx += 256)
    *(float4*)(wsh + idx * 4) = *(const float4*)(wr + idx * 4);
  __syncthreads();
  const int perOut = Zo * Yo * Xo;
  const int perIn  = Zi * Yi * Xi;
  const int total  = nI * perOut;
  int vb = blockIdx.x * 512 + threadIdx.x;

  int inoff[2], outv[2];
#pragma unroll
  for (int i = 0; i < 2; ++i) {
    int v = vb + i * 256;
    if (v < total) {
      int item = v / perOut;
      int r = v - item * perOut;
      int x = r % Xo; int t = r / Xo;
      int y = t % Yo; int z = t / Yo;
      inoff[i] = item * perIn + (z * Yi + y) * Xi + x;
      outv[i] = v;
    } else { inoff[i] = 0; outv[i] = -1; }
  }
  float acc[2][32];
#pragma unroll
  for (int i = 0; i < 2; ++i)
#pragma unroll
    for (int c = 0; c < 32; ++c) acc[i][c] = 0.f;

#pragma unroll 1
  for (int tap = 0; tap < 64; ++tap) {
    int kz = tap >> 4, ky = (tap >> 2) & 3, kx = tap & 3;
    int tapoff = (kz * Yi + ky) * Xi + kx;
    float v0 = in[inoff[0] + tapoff];
    float v1 = in[inoff[1] + tapoff];
    const float* wt = wsh + tap * 32;
    float w[32];
#pragma unroll
    for (int j = 0; j < 8; ++j)
      *(float4*)(w + 4 * j) = *(const float4*)(wt + 4 * j);
#pragma unroll
    for (int c = 0; c < 32; ++c) {
      acc[0][c] = fmaf(v0, w[c], acc[0][c]);
      acc[1][c] = fmaf(v1, w[c], acc[1][c]);
    }
  }
#pragma unroll
  for (int i = 0; i < 2; ++i) {
    if (outv[i] < 0) continue;
    bool act = mo[outv[i]] > 0.f;
    float* op = out + (size_t)outv[i] * 32;
#pragma unroll
    for (int c = 0; c < 32; ++c) {
      float r = act ? (acc[i][c] + bias[c]) : 0.f;
      acc[i][c] = lrelu(r);
    }
#pragma unroll
    for (int j = 0; j < 8; ++j)
      *(float4*)(op + 4 * j) = *(const float4*)(&acc[i][4 * j]);
  }
}

// ---------------- conv 32->1 (c7): 1 voxel/thread, weights fully in LDS -----------
__global__ void k_conv7(const float* __restrict__ in, const float* __restrict__ wr,
                        const float* __restrict__ bias, const float* __restrict__ mo,
                        float* __restrict__ out,
                        int Zi, int Yi, int Xi, int Zo, int Yo, int Xo, int nI) {
  __shared__ float wsh[2048];   // 64 taps x 32 ci
  for (int idx = threadIdx.x; idx < 512; idx += 256)
    *(float4*)(wsh + idx * 4) = *(const float4*)(wr + idx * 4);
  __syncthreads();
  const int perOut = Zo * Yo * Xo;
  const int perIn  = Zi * Yi * Xi;
  const int total  = nI * perOut;
  int gid = blockIdx.x * blockDim.x + threadIdx.x;
  if (gid >= total) return;
  int item = gid / perOut;
  int r = gid - item * perOut;
  int x = r % Xo; int t = r / Xo;
  int y = t % Yo; int z = t / Yo;
  int inoff = (item * perIn + (z * Yi + y) * Xi + x) * 32;
  float acc = 0.f;
#pragma unroll 1
  for (int tap = 0; tap < 64; ++tap) {
    int kz = tap >> 4, ky = (tap >> 2) & 3, kx = tap & 3;
    int base = inoff + ((kz * Yi + ky) * Xi + kx) * 32;
#pragma unroll
    for (int ci4 = 0; ci4 < 8; ++ci4) {
      float4 a = *(const float4*)(in + base + ci4 * 4);
      float4 w = *(const float4*)(wsh + tap * 32 + ci4 * 4);
      acc += a.x * w.x + a.y * w.y + a.z * w.z + a.w * w.w;
    }
  }
  bool act = mo[gid] > 0.f;
  float rr = act ? (acc + bias[0]) : 0.f;
  out[gid] = lrelu(rr);
}

// ---------------- batched separable sparse maxpool (C=32, float4/thread) -----------
__global__ void k_pool_z(const float* __restrict__ in, const float* __restrict__ m,
                         float* __restrict__ out, int Zi, int Yi, int Xi, int Zo, int nI) {
  int gid = blockIdx.x * blockDim.x + threadIdx.x;
  int perOut = Zo * Yi * Xi;
  int tot = nI * perOut * 8;
  if (gid >= tot) return;
  int c4 = gid & 7; int v = gid >> 3;
  int item = v / perOut;
  int r = v - item * perOut;
  int x = r % Xi; int t = r / Xi;
  int y = t % Yi; int z = t / Yi;
  int ib = item * Zi * Yi * Xi;
  float4 acc = {NINF, NINF, NINF, NINF};
  for (int j = 0; j < 5; j++) {
    int vi = ib + ((z + j)*Yi + y)*Xi + x;
    if (m[vi] > 0.f) {
      float4 val = *(const float4*)(in + (size_t)vi*32 + c4*4);
      acc.x = fmaxf(acc.x, val.x); acc.y = fmaxf(acc.y, val.y);
      acc.z = fmaxf(acc.z, val.z); acc.w = fmaxf(acc.w, val.w);
    }
  }
  *(float4*)(out + (size_t)v*32 + c4*4) = acc;
}

__global__ void k_pool_y(const float* __restrict__ in, float* __restrict__ out,
                         int Z, int Yi, int Xi, int Yo, int nI) {
  int gid = blockIdx.x * blockDim.x + threadIdx.x;
  int perOut = Z * Yo * Xi;
  int tot = nI * perOut * 8;
  if (gid >= tot) return;
  int c4 = gid & 7; int v = gid >> 3;
  int item = v / perOut;
  int r = v - item * perOut;
  int x = r % Xi; int t = r / Xi;
  int y = t % Yo; int z = t / Yo;
  int ib = item * Z * Yi * Xi;
  float4 acc = {NINF, NINF, NINF, NINF};
  for (int j = 0; j < 5; j++) {
    int vi = ib + (z*Yi + y + j)*Xi + x;
    float4 val = *(const float4*)(in + (size_t)vi*32 + c4*4);
    acc.x = fmaxf(acc.x, val.x); acc.y = fmaxf(acc.y, val.y);
    acc.z = fmaxf(acc.z, val.z); acc.w = fmaxf(acc.w, val.w);
  }
  *(float4*)(out + (size_t)v*32 + c4*4) = acc;
}

__global__ void k_pool_x(const float* __restrict__ in, const float* __restrict__ mp,
                         float* __restrict__ out, int Z, int Y, int Xi, int Xo, int nI) {
  int gid = blockIdx.x * blockDim.x + threadIdx.x;
  int perOut = Z * Y * Xo;
  int tot = nI * perOut * 8;
  if (gid >= tot) return;
  int c4 = gid & 7; int v = gid >> 3;
  int item = v / perOut;
  int r = v - item * perOut;
  int x = r % Xo; int t = r / Xo;
  int y = t % Y; int z = t / Y;
  int ib = item * Z * Y * Xi;
  float4 acc = {NINF, NINF, NINF, NINF};
  for (int j = 0; j < 5; j++) {
    int vi = ib + (z*Y + y)*Xi + x + j;
    float4 val = *(const float4*)(in + (size_t)vi*32 + c4*4);
    acc.x = fmaxf(acc.x, val.x); acc.y = fmaxf(acc.y, val.y);
    acc.z = fmaxf(acc.z, val.z); acc.w = fmaxf(acc.w, val.w);
  }
  bool act = mp[v] > 0.f;
  float4 rr;
  rr.x = act ? acc.x : 0.f; rr.y = act ? acc.y : 0.f;
  rr.z = act ? acc.z : 0.f; rr.w = act ? acc.w : 0.f;
  *(float4*)(out + (size_t)v*32 + c4*4) = rr;
}

// ---------------- final pool (C=1, direct 5^3), 21,31,36 -> 17,27,32, batched ------
__global__ void k_pool3(const float* __restrict__ xin, const float* __restrict__ m,
                        const float* __restrict__ mp, float* __restrict__ out, int nI) {
  int gid = blockIdx.x * blockDim.x + threadIdx.x;
  int perOut = 17 * 27 * 32;
  int tot = nI * perOut;
  if (gid >= tot) return;
  int item = gid / perOut;
  int r = gid - item * perOut;
  int x = r & 31; int t = r >> 5;
  int y = t % 27; int z = t / 27;
  const float* xb = xin + (size_t)item * 23436;
  const float* mb = m + (size_t)item * 23436;
  float acc = NINF;
  for (int dz = 0; dz < 5; dz++)
    for (int dy = 0; dy < 5; dy++) {
      const float* rowx = xb + (size_t)(((z + dz)*31 + y + dy)*36 + x);
      const float* rowm = mb + (size_t)(((z + dz)*31 + y + dy)*36 + x);
      for (int dx = 0; dx < 5; dx++)
        if (rowm[dx] > 0.f) acc = fmaxf(acc, rowx[dx]);
    }
  out[gid] = (mp[gid] > 0.f) ? acc : 0.f;
}

// ---------------- FC split-K partial + finalize ----------------
__global__ void k_fc_part(const float* __restrict__ X, const float* __restrict__ Wm,
                          float* __restrict__ part, int K, int Ncol, int Kc) {
  __shared__ float sm[16][16][8];
  int ks = blockIdx.y;
  int k0 = ks * Kc;
  int k1 = k0 + Kc; if (k1 > K) k1 = K;
  int cl = threadIdx.x & 15;
  int kt = threadIdx.x >> 4;
  int col = blockIdx.x * 16 + cl;
  float acc[8];
#pragma unroll
  for (int b = 0; b < 8; b++) acc[b] = 0.f;
  if (col < Ncol) {
    for (int k = k0 + kt; k < k1; k += 16) {
      float w = Wm[(size_t)k * Ncol + col];
#pragma unroll
      for (int b = 0; b < 8; b++) acc[b] += X[b * K + k] * w;
    }
  }
#pragma unroll
  for (int b = 0; b < 8; b++) sm[kt][cl][b] = acc[b];
  __syncthreads();
  if (threadIdx.x < 128) {
    int c = threadIdx.x & 15;
    int b = threadIdx.x >> 4;
    float s = 0.f;
#pragma unroll
    for (int k = 0; k < 16; k++) s += sm[k][c][b];
    int cc = blockIdx.x * 16 + c;
    if (cc < Ncol) part[((size_t)ks * 8 + b) * Ncol + cc] = s;
  }
}

__global__ void k_fc_fin(const float* __restrict__ part, int ns,
                         const float* __restrict__ bias, float* __restrict__ out, int Ncol) {
  int i = blockIdx.x * blockDim.x + threadIdx.x;
  if (i >= 8 * Ncol) return;
  int b = i / Ncol;
  int c = i - b * Ncol;
  float s = 0.f;
  for (int ks = 0; ks < ns; ks++) s += part[((size_t)ks * 8 + b) * Ncol + c];
  out[i] = lrelu(s + bias[c]);
}

// last FC (K=1000 -> 1), small
__global__ void k_fc(const float* __restrict__ X, const float* __restrict__ Wm,
                     const float* __restrict__ bias, float* __restrict__ out,
                     int K, int Ncol) {
  __shared__ float sm[16][16][8];
  int cl = threadIdx.x & 15;
  int kt = threadIdx.x >> 4;
  int col = blockIdx.x * 16 + cl;
  float acc[8];
#pragma unroll
  for (int b = 0; b < 8; b++) acc[b] = 0.f;
  if (col < Ncol) {
    for (int k = kt; k < K; k += 16) {
      float w = Wm[(size_t)k * Ncol + col];
#pragma unroll
      for (int b = 0; b < 8; b++) acc[b] += X[b * K + k] * w;
    }
  }
#pragma unroll
  for (int b = 0; b < 8; b++) sm[kt][cl][b] = acc[b];
  __syncthreads();
  if (threadIdx.x < 128) {
    int c = threadIdx.x & 15;
    int b = threadIdx.x >> 4;
    float s = 0.f;
#pragma unroll
    for (int k = 0; k < 16; k++) s += sm[k][c][b];
    int cc = blockIdx.x * 16 + c;
    if (cc < Ncol) out[b * Ncol + cc] = lrelu(s + bias[cc]);
  }
}

// ---------------- host ----------------
static inline int G256(long long n) { return (int)((n + 255) / 256); }

extern "C" void kernel_launch(void* const* d_in, const int* in_sizes, int n_in,
                              void* d_out, int out_size, void* d_ws, size_t ws_size,
                              hipStream_t stream) {
  const float* feat  = (const float*)d_in[0];
  const int*   coors = (const int*)d_in[1];
  const float* w1 = (const float*)d_in[3];  const float* b1 = (const float*)d_in[4];
  const float* w2 = (const float*)d_in[5];  const float* b2 = (const float*)d_in[6];
  const float* w3 = (const float*)d_in[7];  const float* b3 = (const float*)d_in[8];
  const float* w4 = (const float*)d_in[9];  const float* b4 = (const float*)d_in[10];
  const float* w5 = (const float*)d_in[11]; const float* b5 = (const float*)d_in[12];
  const float* w6 = (const float*)d_in[13]; const float* b6 = (const float*)d_in[14];
  const float* w7 = (const float*)d_in[15]; const float* b7 = (const float*)d_in[16];
  const float* W8 = (const float*)d_in[17]; const float* b8 = (const float*)d_in[18];
  const float* W9 = (const float*)d_in[19]; const float* b9 = (const float*)d_in[20];
  const float* W10= (const float*)d_in[21]; const float* b10= (const float*)d_in[22];
  float* out = (float*)d_out;

  char* ws = (char*)d_ws;
  size_t off = 0;
  auto alloc = [&](size_t nfloats) -> float* {
    float* p = (float*)(ws + off);
    off += ((nfloats * 4 + 1023) / 1024) * 1024;
    return p;
  };

  // ---- fixed allocations ----
  float* x0  = alloc(1560000);
  float* m0  = alloc(1560000);
  // masks, batched all 8 items
  float* m1  = alloc(8 * 166098);
  float* m2  = alloc(8 * 140184);
  float* mp1 = alloc(8 * 110000);
  float* m3  = alloc(8 * 90428);
  float* m4  = alloc(8 * 73304);
  float* mp2 = alloc(8 * 54000);
  float* m5  = alloc(8 * 41958);
  float* m6  = alloc(8 * 31824);
  float* m7  = alloc(8 * 23436);
  float* mp3 = alloc(8 * 14688);
  float* p3  = alloc(8 * 14688);
  float* wr1 = alloc(2048);
  float* wr2 = alloc(65536);
  float* wr3 = alloc(65536);
  float* wr4 = alloc(65536);
  float* wr5 = alloc(65536);
  float* wr6 = alloc(65536);
  float* wr7 = alloc(2048);
  float* part= alloc(64000);
  float* h8  = alloc(8000);
  float* h9  = alloc(8000);
  size_t fixedOff = off;

  // ---- pick group size G from remaining workspace ----
  const size_t perItemAB = ((size_t)5315136*4 + 1023)/1024*1024
                         + ((size_t)4485888*4 + 1023)/1024*1024
                         + ((size_t)23436*4 + 1023)/1024*1024;
  int G = 0;
  for (int g : {8, 4, 2, 1})
    if (fixedOff + (size_t)g * perItemAB <= ws_size) { G = g; break; }
  if (G == 0) return;  // workspace too small (should not happen; 1-item need < 80 MB)

  float* A  = alloc((size_t)G * 5315136);
  float* Bb = alloc((size_t)G * 4485888);
  float* x7 = alloc((size_t)G * 23436);
  unsigned* claim = (unsigned*)A;   // claim aliases A (dead before first conv use)

  // ---- init ----
  hipMemsetAsync(claim, 0, 1560000 * 4, stream);
  hipMemsetAsync(x0,    0, 1560000 * 4, stream);
  hipMemsetAsync(m0,    0, 1560000 * 4, stream);

  k_repack<<<G256(32*1*64),  256, 0, stream>>>(w1, wr1, 1, 32);
  k_repack<<<G256(32*32*64), 256, 0, stream>>>(w2, wr2, 32, 32);
  k_repack<<<G256(32*32*64), 256, 0, stream>>>(w3, wr3, 32, 32);
  k_repack<<<G256(32*32*64), 256, 0, stream>>>(w4, wr4, 32, 32);
  k_repack<<<G256(32*32*64), 256, 0, stream>>>(w5, wr5, 32, 32);
  k_repack<<<G256(32*32*64), 256, 0, stream>>>(w6, wr6, 32, 32);
  k_repack<<<G256(1*32*64),  256, 0, stream>>>(w7, wr7, 32, 1);

  const int N = 80000;
  k_claim  <<<G256(N), 256, 0, stream>>>(coors, claim, N);
  k_scatter<<<G256(N), 256, 0, stream>>>(coors, feat, claim, x0, m0, N);

  // ---- all mask dilations, batched over 8 items ----
  k_dilate<<<G256(8*166098), 256, 0, stream>>>(m0,  m1,  50,60,65, 47,57,62, 4, 8);
  k_dilate<<<G256(8*140184), 256, 0, stream>>>(m1,  m2,  47,57,62, 44,54,59, 4, 8);
  k_dilate<<<G256(8*110000), 256, 0, stream>>>(m2,  mp1, 44,54,59, 40,50,55, 5, 8);
  k_dilate<<<G256(8*90428),  256, 0, stream>>>(mp1, m3,  40,50,55, 37,47,52, 4, 8);
  k_dilate<<<G256(8*73304),  256, 0, stream>>>(m3,  m4,  37,47,52, 34,44,49, 4, 8);
  k_dilate<<<G256(8*54000),  256, 0, stream>>>(m4,  mp2, 34,44,49, 30,40,45, 5, 8);
  k_dilate<<<G256(8*41958),  256, 0, stream>>>(mp2, m5,  30,40,45, 27,37,42, 4, 8);
  k_dilate<<<G256(8*31824),  256, 0, stream>>>(m5,  m6,  27,37,42, 24,34,39, 4, 8);
  k_dilate<<<G256(8*23436),  256, 0, stream>>>(m6,  m7,  24,34,39, 21,31,36, 4, 8);
  k_dilate<<<G256(8*14688),  256, 0, stream>>>(m7,  mp3, 21,31,36, 17,27,32, 5, 8);

  auto conv32 = [&](const float* in, const float* wr, const float* bias,
                    const float* mo, float* o,
                    int Zi, int Yi, int Xi, int Zo, int Yo, int Xo, int nI) {
    long long vox = (long long)nI * Zo * Yo * Xo;
    if (vox >= 131072) {
      int blocks = (int)((vox + 511) / 512);
      k_conv32t<4><<<blocks, 128, 0, stream>>>(in, wr, bias, mo, o, Zi,Yi,Xi, Zo,Yo,Xo, nI);
    } else {
      int blocks = (int)((vox + 255) / 256);
      k_conv32t<2><<<blocks, 128, 0, stream>>>(in, wr, bias, mo, o, Zi,Yi,Xi, Zo,Yo,Xo, nI);
    }
  };

  for (int g0 = 0; g0 < 8; g0 += G) {
    const float* x0g  = x0  + (size_t)g0 * 195000;
    const float* m1g  = m1  + (size_t)g0 * 166098;
    const float* m2g  = m2  + (size_t)g0 * 140184;
    const float* mp1g = mp1 + (size_t)g0 * 110000;
    const float* m3g  = m3  + (size_t)g0 * 90428;
    const float* m4g  = m4  + (size_t)g0 * 73304;
    const float* mp2g = mp2 + (size_t)g0 * 54000;
    const float* m5g  = m5  + (size_t)g0 * 41958;
    const float* m6g  = m6  + (size_t)g0 * 31824;
    const float* m7g  = m7  + (size_t)g0 * 23436;
    const float* mp3g = mp3 + (size_t)g0 * 14688;

    // c1: 50,60,65 -> 47,57,62
    k_conv1<<<(int)(((long long)G*166098 + 511)/512), 256, 0, stream>>>(
        x0g, wr1, b1, m1g, A, 50,60,65, 47,57,62, G);
    // c2 -> 44,54,59
    conv32(A, wr2, b2, m2g, Bb, 47,57,62, 44,54,59, G);
    // p1 -> 40,50,55
    k_pool_z<<<G256((long long)G*127440*8), 256, 0, stream>>>(Bb, m2g,  A,  44,54,59, 40, G);
    k_pool_y<<<G256((long long)G*118000*8), 256, 0, stream>>>(A,  Bb, 40,54,59, 50, G);
    k_pool_x<<<G256((long long)G*110000*8), 256, 0, stream>>>(Bb, mp1g, A,  40,50,59, 55, G);
    // c3 -> 37,47,52
    conv32(A, wr3, b3, m3g, Bb, 40,50,55, 37,47,52, G);
    // c4 -> 34,44,49
    conv32(Bb, wr4, b4, m4g, A, 37,47,52, 34,44,49, G);
    // p2 -> 30,40,45
    k_pool_z<<<G256((long long)G*64680*8), 256, 0, stream>>>(A,  m4g,  Bb, 34,44,49, 30, G);
    k_pool_y<<<G256((long long)G*58800*8), 256, 0, stream>>>(Bb, A,  30,44,49, 40, G);
    k_pool_x<<<G256((long long)G*54000*8), 256, 0, stream>>>(A,  mp2g, Bb, 30,40,49, 45, G);
    // c5 -> 27,37,42
    conv32(Bb, wr5, b5, m5g, A, 30,40,45, 27,37,42, G);
    // c6 -> 24,34,39
    conv32(A, wr6, b6, m6g, Bb, 27,37,42, 24,34,39, G);
    // c7 (32->1) -> 21,31,36
    k_conv7<<<G256((long long)G*23436), 256, 0, stream>>>(
        Bb, wr7, b7, m7g, x7, 24,34,39, 21,31,36, G);
    // p3 -> 17,27,32
    k_pool3<<<G256((long long)G*14688), 256, 0, stream>>>(
        x7, m7g, mp3g, p3 + (size_t)g0 * 14688, G);
  }

  // ---- FC head ----
  k_fc_part<<<dim3(63, 8), 256, 0, stream>>>(p3, W8, part, 14688, 1000, 1836);
  k_fc_fin <<<G256(8000), 256, 0, stream>>>(part, 8, b8, h8, 1000);
  k_fc_part<<<dim3(63, 4), 256, 0, stream>>>(h8, W9, part, 1000, 1000, 250);
  k_fc_fin <<<G256(8000), 256, 0, stream>>>(part, 4, b9, h9, 1000);
  k_fc<<<1, 256, 0, stream>>>(h9, W10, b10, out, 1000, 1);
}

// Round 4
// 19554.817 us; speedup vs baseline: 5.4622x; 5.4622x over previous
//
#include <hip/hip_runtime.h>
#include <cstddef>

// Sparse 3D CNN. Adaptive batch-group pipeline (G in {8,4,2,1} chosen from ws_size).
// Spatial chain per item:
// 50,60,65 -> c1 47,57,62 -> c2 44,54,59 -> p1 40,50,55 -> c3 37,47,52
// -> c4 34,44,49 -> p2 30,40,45 -> c5 27,37,42 -> c6 24,34,39 -> c7 21,31,36
// -> p3 17,27,32 ; flatten 14688 -> FC 1000 -> 1000 -> 1
//
// R3: spill-proof conv codegen. R2's conv kernels took address of private
// arrays ((float4*)&acc[..]) -> allocas stayed in scratch -> 30+ GB HBM
// spill traffic per dispatch, VALUBusy 2.3%. Now accumulators are float4
// arrays touched only with constant indices, plus explicit __launch_bounds__.

#define NEGSLOPE 0.01f
#define NINF (-3.0e38f)

__device__ __forceinline__ float lrelu(float v) { return v >= 0.f ? v : NEGSLOPE * v; }

// ---------------- scatter (last-write-wins), full batch ----------------
__global__ void k_claim(const int* __restrict__ coors, unsigned* __restrict__ claim, int N) {
  int i = blockIdx.x * blockDim.x + threadIdx.x;
  if (i >= N) return;
  int b = coors[4*i], z = coors[4*i+1], y = coors[4*i+2], x = coors[4*i+3];
  int v = ((b*50 + z)*60 + y)*65 + x;
  atomicMax(&claim[v], (unsigned)(i + 1));
}

__global__ void k_scatter(const int* __restrict__ coors, const float* __restrict__ feat,
                          const unsigned* __restrict__ claim,
                          float* __restrict__ x0, float* __restrict__ m0, int N) {
  int i = blockIdx.x * blockDim.x + threadIdx.x;
  if (i >= N) return;
  int b = coors[4*i], z = coors[4*i+1], y = coors[4*i+2], x = coors[4*i+3];
  int v = ((b*50 + z)*60 + y)*65 + x;
  m0[v] = 1.f;
  if (claim[v] == (unsigned)(i + 1)) x0[v] = feat[i];
}

// ---------------- weight repack: w[co][ci][k64] -> wr[k64][ci][co] ----------------
__global__ void k_repack(const float* __restrict__ w, float* __restrict__ wr, int CI, int CO) {
  int i = blockIdx.x * blockDim.x + threadIdx.x;
  int tot = CO * CI * 64;
  if (i >= tot) return;
  int k = i & 63;
  int ci = (i >> 6) % CI;
  int co = i / (64 * CI);
  wr[(k * CI + ci) * CO + co] = w[i];
}

// ---------------- batched mask dilation (window K, VALID) ----------------
__global__ void k_dilate(const float* __restrict__ m, float* __restrict__ o,
                         int Zi, int Yi, int Xi, int Zo, int Yo, int Xo, int K, int nI) {
  int gid = blockIdx.x * blockDim.x + threadIdx.x;
  int perOut = Zo * Yo * Xo;
  int tot = nI * perOut;
  if (gid >= tot) return;
  int item = gid / perOut;
  int r = gid - item * perOut;
  int x = r % Xo; int t = r / Xo;
  int y = t % Yo; int z = t / Yo;
  const float* mb = m + (size_t)item * Zi * Yi * Xi;
  float mx = 0.f;
  for (int dz = 0; dz < K; dz++)
    for (int dy = 0; dy < K; dy++) {
      const float* row = mb + (size_t)(((z + dz)*Yi + y + dy)*Xi + x);
      for (int dx = 0; dx < K; dx++) mx = fmaxf(mx, row[dx]);
    }
  o[gid] = mx;
}

// ---------------- tiled conv 32->32: 128 thr, V voxels/thread, LDS 8-tap weight slabs
template<int V>
__global__ __launch_bounds__(128, 2)
void k_conv32t(const float* __restrict__ in, const float* __restrict__ wr,
               const float* __restrict__ bias, const float* __restrict__ mo,
               float* __restrict__ out,
               int Zi, int Yi, int Xi, int Zo, int Yo, int Xo, int nI) {
  __shared__ float4 wsh[2048];   // 8 taps x 32ci x 8 co-quads (32 KB)
  const int perOut = Zo * Yo * Xo;
  const int perIn  = Zi * Yi * Xi;
  const int total  = nI * perOut;
  const int tid = threadIdx.x;   // 0..127
  int vb = blockIdx.x * (128 * V) + tid;

  int inoff[V], outv[V];
#pragma unroll
  for (int i = 0; i < V; ++i) {
    int v = vb + i * 128;
    if (v < total) {
      int item = v / perOut;
      int r = v - item * perOut;
      int x = r % Xo; int t = r / Xo;
      int y = t % Yo; int z = t / Yo;
      inoff[i] = (item * perIn + (z * Yi + y) * Xi + x) * 32;
      outv[i] = v;
    } else { inoff[i] = 0; outv[i] = -1; }
  }

  float4 acc[V][8];
#pragma unroll
  for (int i = 0; i < V; ++i)
#pragma unroll
    for (int j = 0; j < 8; ++j) acc[i][j] = make_float4(0.f, 0.f, 0.f, 0.f);

  const float4* wr4 = (const float4*)wr;

#pragma unroll 1
  for (int sl = 0; sl < 8; ++sl) {
    __syncthreads();
    for (int idx = tid; idx < 2048; idx += 128) wsh[idx] = wr4[sl * 2048 + idx];
    __syncthreads();
#pragma unroll 1
    for (int t8 = 0; t8 < 8; ++t8) {
      int tap = sl * 8 + t8;
      int kz = tap >> 4, ky = (tap >> 2) & 3, kx = tap & 3;
      int tapoff = ((kz * Yi + ky) * Xi + kx) * 32;
#pragma unroll 2
      for (int ci4 = 0; ci4 < 8; ++ci4) {
        float4 a[V];
#pragma unroll
        for (int i = 0; i < V; ++i)
          a[i] = *(const float4*)(in + inoff[i] + tapoff + ci4 * 4);
#pragma unroll
        for (int u = 0; u < 4; ++u) {
          const float4* wrow = &wsh[(t8 * 32 + ci4 * 4 + u) * 8];
#pragma unroll
          for (int j = 0; j < 8; ++j) {
            float4 wv = wrow[j];
#pragma unroll
            for (int i = 0; i < V; ++i) {
              float av = (u == 0) ? a[i].x : (u == 1) ? a[i].y : (u == 2) ? a[i].z : a[i].w;
              acc[i][j].x = fmaf(av, wv.x, acc[i][j].x);
              acc[i][j].y = fmaf(av, wv.y, acc[i][j].y);
              acc[i][j].z = fmaf(av, wv.z, acc[i][j].z);
              acc[i][j].w = fmaf(av, wv.w, acc[i][j].w);
            }
          }
        }
      }
    }
  }

  const float4* b4 = (const float4*)bias;
#pragma unroll
  for (int i = 0; i < V; ++i) {
    if (outv[i] < 0) continue;
    bool act = mo[outv[i]] > 0.f;
    float4* op = (float4*)(out + (size_t)outv[i] * 32);
#pragma unroll
    for (int j = 0; j < 8; ++j) {
      float4 r = acc[i][j];
      float4 bj = b4[j];
      r.x = lrelu(act ? (r.x + bj.x) : 0.f);
      r.y = lrelu(act ? (r.y + bj.y) : 0.f);
      r.z = lrelu(act ? (r.z + bj.z) : 0.f);
      r.w = lrelu(act ? (r.w + bj.w) : 0.f);
      op[j] = r;
    }
  }
}

// ---------------- conv 1->32 (c1): 256 thr, 2 voxels/thread, weights fully in LDS ---
__global__ __launch_bounds__(256, 2)
void k_conv1(const float* __restrict__ in, const float* __restrict__ wr,
             const float* __restrict__ bias, const float* __restrict__ mo,
             float* __restrict__ out,
             int Zi, int Yi, int Xi, int Zo, int Yo, int Xo, int nI) {
  __shared__ float4 wsh[512];   // 64 taps x 8 co-quads
  {
    const float4* wr4 = (const float4*)wr;
    for (int idx = threadIdx.x; idx < 512; idx += 256) wsh[idx] = wr4[idx];
  }
  __syncthreads();
  const int perOut = Zo * Yo * Xo;
  const int perIn  = Zi * Yi * Xi;
  const int total  = nI * perOut;
  int vb = blockIdx.x * 512 + threadIdx.x;

  int inoff[2], outv[2];
#pragma unroll
  for (int i = 0; i < 2; ++i) {
    int v = vb + i * 256;
    if (v < total) {
      int item = v / perOut;
      int r = v - item * perOut;
      int x = r % Xo; int t = r / Xo;
      int y = t % Yo; int z = t / Yo;
      inoff[i] = item * perIn + (z * Yi + y) * Xi + x;
      outv[i] = v;
    } else { inoff[i] = 0; outv[i] = -1; }
  }
  float4 acc[2][8];
#pragma unroll
  for (int i = 0; i < 2; ++i)
#pragma unroll
    for (int j = 0; j < 8; ++j) acc[i][j] = make_float4(0.f, 0.f, 0.f, 0.f);

#pragma unroll 1
  for (int tap = 0; tap < 64; ++tap) {
    int kz = tap >> 4, ky = (tap >> 2) & 3, kx = tap & 3;
    int tapoff = (kz * Yi + ky) * Xi + kx;
    float v0 = in[inoff[0] + tapoff];
    float v1 = in[inoff[1] + tapoff];
#pragma unroll
    for (int j = 0; j < 8; ++j) {
      float4 wv = wsh[tap * 8 + j];
      acc[0][j].x = fmaf(v0, wv.x, acc[0][j].x);
      acc[0][j].y = fmaf(v0, wv.y, acc[0][j].y);
      acc[0][j].z = fmaf(v0, wv.z, acc[0][j].z);
      acc[0][j].w = fmaf(v0, wv.w, acc[0][j].w);
      acc[1][j].x = fmaf(v1, wv.x, acc[1][j].x);
      acc[1][j].y = fmaf(v1, wv.y, acc[1][j].y);
      acc[1][j].z = fmaf(v1, wv.z, acc[1][j].z);
      acc[1][j].w = fmaf(v1, wv.w, acc[1][j].w);
    }
  }
  const float4* b4 = (const float4*)bias;
#pragma unroll
  for (int i = 0; i < 2; ++i) {
    if (outv[i] < 0) continue;
    bool act = mo[outv[i]] > 0.f;
    float4* op = (float4*)(out + (size_t)outv[i] * 32);
#pragma unroll
    for (int j = 0; j < 8; ++j) {
      float4 r = acc[i][j];
      float4 bj = b4[j];
      r.x = lrelu(act ? (r.x + bj.x) : 0.f);
      r.y = lrelu(act ? (r.y + bj.y) : 0.f);
      r.z = lrelu(act ? (r.z + bj.z) : 0.f);
      r.w = lrelu(act ? (r.w + bj.w) : 0.f);
      op[j] = r;
    }
  }
}

// ---------------- conv 32->1 (c7): 1 voxel/thread, weights fully in LDS -----------
__global__ __launch_bounds__(256, 4)
void k_conv7(const float* __restrict__ in, const float* __restrict__ wr,
             const float* __restrict__ bias, const float* __restrict__ mo,
             float* __restrict__ out,
             int Zi, int Yi, int Xi, int Zo, int Yo, int Xo, int nI) {
  __shared__ float4 wsh[512];   // 64 taps x 8 ci-quads
  {
    const float4* wr4 = (const float4*)wr;
    for (int idx = threadIdx.x; idx < 512; idx += 256) wsh[idx] = wr4[idx];
  }
  __syncthreads();
  const int perOut = Zo * Yo * Xo;
  const int perIn  = Zi * Yi * Xi;
  const int total  = nI * perOut;
  int gid = blockIdx.x * blockDim.x + threadIdx.x;
  if (gid >= total) return;
  int item = gid / perOut;
  int r = gid - item * perOut;
  int x = r % Xo; int t = r / Xo;
  int y = t % Yo; int z = t / Yo;
  int inoff = (item * perIn + (z * Yi + y) * Xi + x) * 32;
  float acc = 0.f;
#pragma unroll 1
  for (int tap = 0; tap < 64; ++tap) {
    int kz = tap >> 4, ky = (tap >> 2) & 3, kx = tap & 3;
    int base = inoff + ((kz * Yi + ky) * Xi + kx) * 32;
#pragma unroll
    for (int ci4 = 0; ci4 < 8; ++ci4) {
      float4 a = *(const float4*)(in + base + ci4 * 4);
      float4 w = wsh[tap * 8 + ci4];
      acc += a.x * w.x + a.y * w.y + a.z * w.z + a.w * w.w;
    }
  }
  bool act = mo[gid] > 0.f;
  float rr = act ? (acc + bias[0]) : 0.f;
  out[gid] = lrelu(rr);
}

// ---------------- batched separable sparse maxpool (C=32, float4/thread) -----------
__global__ void k_pool_z(const float* __restrict__ in, const float* __restrict__ m,
                         float* __restrict__ out, int Zi, int Yi, int Xi, int Zo, int nI) {
  int gid = blockIdx.x * blockDim.x + threadIdx.x;
  int perOut = Zo * Yi * Xi;
  int tot = nI * perOut * 8;
  if (gid >= tot) return;
  int c4 = gid & 7; int v = gid >> 3;
  int item = v / perOut;
  int r = v - item * perOut;
  int x = r % Xi; int t = r / Xi;
  int y = t % Yi; int z = t / Yi;
  int ib = item * Zi * Yi * Xi;
  float4 acc = {NINF, NINF, NINF, NINF};
  for (int j = 0; j < 5; j++) {
    int vi = ib + ((z + j)*Yi + y)*Xi + x;
    if (m[vi] > 0.f) {
      float4 val = *(const float4*)(in + (size_t)vi*32 + c4*4);
      acc.x = fmaxf(acc.x, val.x); acc.y = fmaxf(acc.y, val.y);
      acc.z = fmaxf(acc.z, val.z); acc.w = fmaxf(acc.w, val.w);
    }
  }
  *(float4*)(out + (size_t)v*32 + c4*4) = acc;
}

__global__ void k_pool_y(const float* __restrict__ in, float* __restrict__ out,
                         int Z, int Yi, int Xi, int Yo, int nI) {
  int gid = blockIdx.x * blockDim.x + threadIdx.x;
  int perOut = Z * Yo * Xi;
  int tot = nI * perOut * 8;
  if (gid >= tot) return;
  int c4 = gid & 7; int v = gid >> 3;
  int item = v / perOut;
  int r = v - item * perOut;
  int x = r % Xi; int t = r / Xi;
  int y = t % Yo; int z = t / Yo;
  int ib = item * Z * Yi * Xi;
  float4 acc = {NINF, NINF, NINF, NINF};
  for (int j = 0; j < 5; j++) {
    int vi = ib + (z*Yi + y + j)*Xi + x;
    float4 val = *(const float4*)(in + (size_t)vi*32 + c4*4);
    acc.x = fmaxf(acc.x, val.x); acc.y = fmaxf(acc.y, val.y);
    acc.z = fmaxf(acc.z, val.z); acc.w = fmaxf(acc.w, val.w);
  }
  *(float4*)(out + (size_t)v*32 + c4*4) = acc;
}

__global__ void k_pool_x(const float* __restrict__ in, const float* __restrict__ mp,
                         float* __restrict__ out, int Z, int Y, int Xi, int Xo, int nI) {
  int gid = blockIdx.x * blockDim.x + threadIdx.x;
  int perOut = Z * Y * Xo;
  int tot = nI * perOut * 8;
  if (gid >= tot) return;
  int c4 = gid & 7; int v = gid >> 3;
  int item = v / perOut;
  int r = v - item * perOut;
  int x = r % Xo; int t = r / Xo;
  int y = t % Y; int z = t / Y;
  int ib = item * Z * Y * Xi;
  float4 acc = {NINF, NINF, NINF, NINF};
  for (int j = 0; j < 5; j++) {
    int vi = ib + (z*Y + y)*Xi + x + j;
    float4 val = *(const float4*)(in + (size_t)vi*32 + c4*4);
    acc.x = fmaxf(acc.x, val.x); acc.y = fmaxf(acc.y, val.y);
    acc.z = fmaxf(acc.z, val.z); acc.w = fmaxf(acc.w, val.w);
  }
  bool act = mp[v] > 0.f;
  float4 rr;
  rr.x = act ? acc.x : 0.f; rr.y = act ? acc.y : 0.f;
  rr.z = act ? acc.z : 0.f; rr.w = act ? acc.w : 0.f;
  *(float4*)(out + (size_t)v*32 + c4*4) = rr;
}

// ---------------- final pool (C=1, direct 5^3), 21,31,36 -> 17,27,32, batched ------
__global__ void k_pool3(const float* __restrict__ xin, const float* __restrict__ m,
                        const float* __restrict__ mp, float* __restrict__ out, int nI) {
  int gid = blockIdx.x * blockDim.x + threadIdx.x;
  int perOut = 17 * 27 * 32;
  int tot = nI * perOut;
  if (gid >= tot) return;
  int item = gid / perOut;
  int r = gid - item * perOut;
  int x = r & 31; int t = r >> 5;
  int y = t % 27; int z = t / 27;
  const float* xb = xin + (size_t)item * 23436;
  const float* mb = m + (size_t)item * 23436;
  float acc = NINF;
  for (int dz = 0; dz < 5; dz++)
    for (int dy = 0; dy < 5; dy++) {
      const float* rowx = xb + (size_t)(((z + dz)*31 + y + dy)*36 + x);
      const float* rowm = mb + (size_t)(((z + dz)*31 + y + dy)*36 + x);
      for (int dx = 0; dx < 5; dx++)
        if (rowm[dx] > 0.f) acc = fmaxf(acc, rowx[dx]);
    }
  out[gid] = (mp[gid] > 0.f) ? acc : 0.f;
}

// ---------------- FC split-K partial + finalize ----------------
__global__ __launch_bounds__(256, 4)
void k_fc_part(const float* __restrict__ X, const float* __restrict__ Wm,
               float* __restrict__ part, int K, int Ncol, int Kc) {
  __shared__ float sm[16][16][8];
  int ks = blockIdx.y;
  int k0 = ks * Kc;
  int k1 = k0 + Kc; if (k1 > K) k1 = K;
  int cl = threadIdx.x & 15;
  int kt = threadIdx.x >> 4;
  int col = blockIdx.x * 16 + cl;
  float a0=0.f,a1=0.f,a2=0.f,a3=0.f,a4=0.f,a5=0.f,a6=0.f,a7=0.f;
  if (col < Ncol) {
    for (int k = k0 + kt; k < k1; k += 16) {
      float w = Wm[(size_t)k * Ncol + col];
      a0 += X[0 * K + k] * w; a1 += X[1 * K + k] * w;
      a2 += X[2 * K + k] * w; a3 += X[3 * K + k] * w;
      a4 += X[4 * K + k] * w; a5 += X[5 * K + k] * w;
      a6 += X[6 * K + k] * w; a7 += X[7 * K + k] * w;
    }
  }
  sm[kt][cl][0]=a0; sm[kt][cl][1]=a1; sm[kt][cl][2]=a2; sm[kt][cl][3]=a3;
  sm[kt][cl][4]=a4; sm[kt][cl][5]=a5; sm[kt][cl][6]=a6; sm[kt][cl][7]=a7;
  __syncthreads();
  if (threadIdx.x < 128) {
    int c = threadIdx.x & 15;
    int b = threadIdx.x >> 4;
    float s = 0.f;
#pragma unroll
    for (int k = 0; k < 16; k++) s += sm[k][c][b];
    int cc = blockIdx.x * 16 + c;
    if (cc < Ncol) part[((size_t)ks * 8 + b) * Ncol + cc] = s;
  }
}

__global__ void k_fc_fin(const float* __restrict__ part, int ns,
                         const float* __restrict__ bias, float* __restrict__ out, int Ncol) {
  int i = blockIdx.x * blockDim.x + threadIdx.x;
  if (i >= 8 * Ncol) return;
  int b = i / Ncol;
  int c = i - b * Ncol;
  float s = 0.f;
  for (int ks = 0; ks < ns; ks++) s += part[((size_t)ks * 8 + b) * Ncol + c];
  out[i] = lrelu(s + bias[c]);
}

// last FC (K=1000 -> 1), small
__global__ __launch_bounds__(256, 4)
void k_fc(const float* __restrict__ X, const float* __restrict__ Wm,
          const float* __restrict__ bias, float* __restrict__ out,
          int K, int Ncol) {
  __shared__ float sm[16][16][8];
  int cl = threadIdx.x & 15;
  int kt = threadIdx.x >> 4;
  int col = blockIdx.x * 16 + cl;
  float a0=0.f,a1=0.f,a2=0.f,a3=0.f,a4=0.f,a5=0.f,a6=0.f,a7=0.f;
  if (col < Ncol) {
    for (int k = kt; k < K; k += 16) {
      float w = Wm[(size_t)k * Ncol + col];
      a0 += X[0 * K + k] * w; a1 += X[1 * K + k] * w;
      a2 += X[2 * K + k] * w; a3 += X[3 * K + k] * w;
      a4 += X[4 * K + k] * w; a5 += X[5 * K + k] * w;
      a6 += X[6 * K + k] * w; a7 += X[7 * K + k] * w;
    }
  }
  sm[kt][cl][0]=a0; sm[kt][cl][1]=a1; sm[kt][cl][2]=a2; sm[kt][cl][3]=a3;
  sm[kt][cl][4]=a4; sm[kt][cl][5]=a5; sm[kt][cl][6]=a6; sm[kt][cl][7]=a7;
  __syncthreads();
  if (threadIdx.x < 128) {
    int c = threadIdx.x & 15;
    int b = threadIdx.x >> 4;
    float s = 0.f;
#pragma unroll
    for (int k = 0; k < 16; k++) s += sm[k][c][b];
    int cc = blockIdx.x * 16 + c;
    if (cc < Ncol) out[b * Ncol + cc] = lrelu(s + bias[cc]);
  }
}

// ---------------- host ----------------
static inline int G256(long long n) { return (int)((n + 255) / 256); }

extern "C" void kernel_launch(void* const* d_in, const int* in_sizes, int n_in,
                              void* d_out, int out_size, void* d_ws, size_t ws_size,
                              hipStream_t stream) {
  const float* feat  = (const float*)d_in[0];
  const int*   coors = (const int*)d_in[1];
  const float* w1 = (const float*)d_in[3];  const float* b1 = (const float*)d_in[4];
  const float* w2 = (const float*)d_in[5];  const float* b2 = (const float*)d_in[6];
  const float* w3 = (const float*)d_in[7];  const float* b3 = (const float*)d_in[8];
  const float* w4 = (const float*)d_in[9];  const float* b4 = (const float*)d_in[10];
  const float* w5 = (const float*)d_in[11]; const float* b5 = (const float*)d_in[12];
  const float* w6 = (const float*)d_in[13]; const float* b6 = (const float*)d_in[14];
  const float* w7 = (const float*)d_in[15]; const float* b7 = (const float*)d_in[16];
  const float* W8 = (const float*)d_in[17]; const float* b8 = (const float*)d_in[18];
  const float* W9 = (const float*)d_in[19]; const float* b9 = (const float*)d_in[20];
  const float* W10= (const float*)d_in[21]; const float* b10= (const float*)d_in[22];
  float* out = (float*)d_out;

  char* ws = (char*)d_ws;
  size_t off = 0;
  auto alloc = [&](size_t nfloats) -> float* {
    float* p = (float*)(ws + off);
    off += ((nfloats * 4 + 1023) / 1024) * 1024;
    return p;
  };

  // ---- fixed allocations ----
  float* x0  = alloc(1560000);
  float* m0  = alloc(1560000);
  float* m1  = alloc(8 * 166098);
  float* m2  = alloc(8 * 140184);
  float* mp1 = alloc(8 * 110000);
  float* m3  = alloc(8 * 90428);
  float* m4  = alloc(8 * 73304);
  float* mp2 = alloc(8 * 54000);
  float* m5  = alloc(8 * 41958);
  float* m6  = alloc(8 * 31824);
  float* m7  = alloc(8 * 23436);
  float* mp3 = alloc(8 * 14688);
  float* p3  = alloc(8 * 14688);
  float* wr1 = alloc(2048);
  float* wr2 = alloc(65536);
  float* wr3 = alloc(65536);
  float* wr4 = alloc(65536);
  float* wr5 = alloc(65536);
  float* wr6 = alloc(65536);
  float* wr7 = alloc(2048);
  float* part= alloc(64000);
  float* h8  = alloc(8000);
  float* h9  = alloc(8000);
  size_t fixedOff = off;

  // ---- pick group size G from remaining workspace ----
  const size_t perItemAB = ((size_t)5315136*4 + 1023)/1024*1024
                         + ((size_t)4485888*4 + 1023)/1024*1024
                         + ((size_t)23436*4 + 1023)/1024*1024;
  int G = 0;
  for (int g : {8, 4, 2, 1})
    if (fixedOff + (size_t)g * perItemAB <= ws_size) { G = g; break; }
  if (G == 0) return;

  float* A  = alloc((size_t)G * 5315136);
  float* Bb = alloc((size_t)G * 4485888);
  float* x7 = alloc((size_t)G * 23436);
  unsigned* claim = (unsigned*)A;   // claim aliases A (dead before first conv use)

  // ---- init ----
  hipMemsetAsync(claim, 0, 1560000 * 4, stream);
  hipMemsetAsync(x0,    0, 1560000 * 4, stream);
  hipMemsetAsync(m0,    0, 1560000 * 4, stream);

  k_repack<<<G256(32*1*64),  256, 0, stream>>>(w1, wr1, 1, 32);
  k_repack<<<G256(32*32*64), 256, 0, stream>>>(w2, wr2, 32, 32);
  k_repack<<<G256(32*32*64), 256, 0, stream>>>(w3, wr3, 32, 32);
  k_repack<<<G256(32*32*64), 256, 0, stream>>>(w4, wr4, 32, 32);
  k_repack<<<G256(32*32*64), 256, 0, stream>>>(w5, wr5, 32, 32);
  k_repack<<<G256(32*32*64), 256, 0, stream>>>(w6, wr6, 32, 32);
  k_repack<<<G256(1*32*64),  256, 0, stream>>>(w7, wr7, 32, 1);

  const int N = 80000;
  k_claim  <<<G256(N), 256, 0, stream>>>(coors, claim, N);
  k_scatter<<<G256(N), 256, 0, stream>>>(coors, feat, claim, x0, m0, N);

  // ---- all mask dilations, batched over 8 items ----
  k_dilate<<<G256(8*166098), 256, 0, stream>>>(m0,  m1,  50,60,65, 47,57,62, 4, 8);
  k_dilate<<<G256(8*140184), 256, 0, stream>>>(m1,  m2,  47,57,62, 44,54,59, 4, 8);
  k_dilate<<<G256(8*110000), 256, 0, stream>>>(m2,  mp1, 44,54,59, 40,50,55, 5, 8);
  k_dilate<<<G256(8*90428),  256, 0, stream>>>(mp1, m3,  40,50,55, 37,47,52, 4, 8);
  k_dilate<<<G256(8*73304),  256, 0, stream>>>(m3,  m4,  37,47,52, 34,44,49, 4, 8);
  k_dilate<<<G256(8*54000),  256, 0, stream>>>(m4,  mp2, 34,44,49, 30,40,45, 5, 8);
  k_dilate<<<G256(8*41958),  256, 0, stream>>>(mp2, m5,  30,40,45, 27,37,42, 4, 8);
  k_dilate<<<G256(8*31824),  256, 0, stream>>>(m5,  m6,  27,37,42, 24,34,39, 4, 8);
  k_dilate<<<G256(8*23436),  256, 0, stream>>>(m6,  m7,  24,34,39, 21,31,36, 4, 8);
  k_dilate<<<G256(8*14688),  256, 0, stream>>>(m7,  mp3, 21,31,36, 17,27,32, 5, 8);

  auto conv32 = [&](const float* in, const float* wr, const float* bias,
                    const float* mo, float* o,
                    int Zi, int Yi, int Xi, int Zo, int Yo, int Xo, int nI) {
    long long vox = (long long)nI * Zo * Yo * Xo;
    if (vox >= 131072) {
      int blocks = (int)((vox + 511) / 512);
      k_conv32t<4><<<blocks, 128, 0, stream>>>(in, wr, bias, mo, o, Zi,Yi,Xi, Zo,Yo,Xo, nI);
    } else {
      int blocks = (int)((vox + 255) / 256);
      k_conv32t<2><<<blocks, 128, 0, stream>>>(in, wr, bias, mo, o, Zi,Yi,Xi, Zo,Yo,Xo, nI);
    }
  };

  for (int g0 = 0; g0 < 8; g0 += G) {
    const float* x0g  = x0  + (size_t)g0 * 195000;
    const float* m1g  = m1  + (size_t)g0 * 166098;
    const float* m2g  = m2  + (size_t)g0 * 140184;
    const float* mp1g = mp1 + (size_t)g0 * 110000;
    const float* m3g  = m3  + (size_t)g0 * 90428;
    const float* m4g  = m4  + (size_t)g0 * 73304;
    const float* mp2g = mp2 + (size_t)g0 * 54000;
    const float* m5g  = m5  + (size_t)g0 * 41958;
    const float* m6g  = m6  + (size_t)g0 * 31824;
    const float* m7g  = m7  + (size_t)g0 * 23436;
    const float* mp3g = mp3 + (size_t)g0 * 14688;

    // c1: 50,60,65 -> 47,57,62
    k_conv1<<<(int)(((long long)G*166098 + 511)/512), 256, 0, stream>>>(
        x0g, wr1, b1, m1g, A, 50,60,65, 47,57,62, G);
    // c2 -> 44,54,59
    conv32(A, wr2, b2, m2g, Bb, 47,57,62, 44,54,59, G);
    // p1 -> 40,50,55
    k_pool_z<<<G256((long long)G*127440*8), 256, 0, stream>>>(Bb, m2g,  A,  44,54,59, 40, G);
    k_pool_y<<<G256((long long)G*118000*8), 256, 0, stream>>>(A,  Bb, 40,54,59, 50, G);
    k_pool_x<<<G256((long long)G*110000*8), 256, 0, stream>>>(Bb, mp1g, A,  40,50,59, 55, G);
    // c3 -> 37,47,52
    conv32(A, wr3, b3, m3g, Bb, 40,50,55, 37,47,52, G);
    // c4 -> 34,44,49
    conv32(Bb, wr4, b4, m4g, A, 37,47,52, 34,44,49, G);
    // p2 -> 30,40,45
    k_pool_z<<<G256((long long)G*64680*8), 256, 0, stream>>>(A,  m4g,  Bb, 34,44,49, 30, G);
    k_pool_y<<<G256((long long)G*58800*8), 256, 0, stream>>>(Bb, A,  30,44,49, 40, G);
    k_pool_x<<<G256((long long)G*54000*8), 256, 0, stream>>>(A,  mp2g, Bb, 30,40,49, 45, G);
    // c5 -> 27,37,42
    conv32(Bb, wr5, b5, m5g, A, 30,40,45, 27,37,42, G);
    // c6 -> 24,34,39
    conv32(A, wr6, b6, m6g, Bb, 27,37,42, 24,34,39, G);
    // c7 (32->1) -> 21,31,36
    k_conv7<<<G256((long long)G*23436), 256, 0, stream>>>(
        Bb, wr7, b7, m7g, x7, 24,34,39, 21,31,36, G);
    // p3 -> 17,27,32
    k_pool3<<<G256((long long)G*14688), 256, 0, stream>>>(
        x7, m7g, mp3g, p3 + (size_t)g0 * 14688, G);
  }

  // ---- FC head ----
  k_fc_part<<<dim3(63, 8), 256, 0, stream>>>(p3, W8, part, 14688, 1000, 1836);
  k_fc_fin <<<G256(8000), 256, 0, stream>>>(part, 8, b8, h8, 1000);
  k_fc_part<<<dim3(63, 4), 256, 0, stream>>>(h8, W9, part, 1000, 1000, 250);
  k_fc_fin <<<G256(8000), 256, 0, stream>>>(part, 4, b9, h9, 1000);
  k_fc<<<1, 256, 0, stream>>>(h9, W10, b10, out, 1000, 1);
}

// Round 5
// 14450.262 us; speedup vs baseline: 7.3918x; 1.3532x over previous
//
#include <hip/hip_runtime.h>
#include <cstddef>

// Sparse 3D CNN. Adaptive batch-group pipeline (G in {8,4,2,1} chosen from ws_size).
// Spatial chain per item:
// 50,60,65 -> c1 47,57,62 -> c2 44,54,59 -> p1 40,50,55 -> c3 37,47,52
// -> c4 34,44,49 -> p2 30,40,45 -> c5 27,37,42 -> c6 24,34,39 -> c7 21,31,36
// -> p3 17,27,32 ; flatten 14688 -> FC 1000 -> 1000 -> 1
//
// R4: LDS-tiled convs. R3 was fetch-bound (15.6 GB HBM per conv dispatch —
// every tap re-read inputs from memory). Now each block stages a 7x7x19
// input halo in LDS (two 16-channel passes, 58 KB) and reads weights via
// wave-uniform (scalar-pipe) loads. Convs should be VALU-bound.

#define NEGSLOPE 0.01f
#define NINF (-3.0e38f)

#define TZ 4
#define TY 4
#define TXT 16
#define IZ 7
#define IY 7
#define IX 19
#define NV (IZ*IY*IX)   // 931 voxels, 58.2 KB at 16ch

__device__ __forceinline__ float lrelu(float v) { return v >= 0.f ? v : NEGSLOPE * v; }

// ---------------- scatter (last-write-wins), full batch ----------------
__global__ void k_claim(const int* __restrict__ coors, unsigned* __restrict__ claim, int N) {
  int i = blockIdx.x * blockDim.x + threadIdx.x;
  if (i >= N) return;
  int b = coors[4*i], z = coors[4*i+1], y = coors[4*i+2], x = coors[4*i+3];
  int v = ((b*50 + z)*60 + y)*65 + x;
  atomicMax(&claim[v], (unsigned)(i + 1));
}

__global__ void k_scatter(const int* __restrict__ coors, const float* __restrict__ feat,
                          const unsigned* __restrict__ claim,
                          float* __restrict__ x0, float* __restrict__ m0, int N) {
  int i = blockIdx.x * blockDim.x + threadIdx.x;
  if (i >= N) return;
  int b = coors[4*i], z = coors[4*i+1], y = coors[4*i+2], x = coors[4*i+3];
  int v = ((b*50 + z)*60 + y)*65 + x;
  m0[v] = 1.f;
  if (claim[v] == (unsigned)(i + 1)) x0[v] = feat[i];
}

// ---------------- weight repack: w[co][ci][k64] -> wr[k64][ci][co] ----------------
__global__ void k_repack(const float* __restrict__ w, float* __restrict__ wr, int CI, int CO) {
  int i = blockIdx.x * blockDim.x + threadIdx.x;
  int tot = CO * CI * 64;
  if (i >= tot) return;
  int k = i & 63;
  int ci = (i >> 6) % CI;
  int co = i / (64 * CI);
  wr[(k * CI + ci) * CO + co] = w[i];
}

// ---------------- batched mask dilation (window K, VALID) ----------------
__global__ void k_dilate(const float* __restrict__ m, float* __restrict__ o,
                         int Zi, int Yi, int Xi, int Zo, int Yo, int Xo, int K, int nI) {
  int gid = blockIdx.x * blockDim.x + threadIdx.x;
  int perOut = Zo * Yo * Xo;
  int tot = nI * perOut;
  if (gid >= tot) return;
  int item = gid / perOut;
  int r = gid - item * perOut;
  int x = r % Xo; int t = r / Xo;
  int y = t % Yo; int z = t / Yo;
  const float* mb = m + (size_t)item * Zi * Yi * Xi;
  float mx = 0.f;
  for (int dz = 0; dz < K; dz++)
    for (int dy = 0; dy < K; dy++) {
      const float* row = mb + (size_t)(((z + dz)*Yi + y + dy)*Xi + x);
      for (int dx = 0; dx < K; dx++) mx = fmaxf(mx, row[dx]);
    }
  o[gid] = mx;
}

// ---------------- LDS-tiled conv 32->32 ----------------
// block = 4x4x16 output tile, 256 threads, 1 voxel x 32co per thread.
// Input halo 7x7x19 staged in LDS as two 16-channel passes (58 KB).
// Weights read with wave-uniform (scalar-pipe) loads.
__global__ __launch_bounds__(256, 2)
void k_conv32t(const float* __restrict__ in, const float* __restrict__ wr,
               const float* __restrict__ bias, const float* __restrict__ mo,
               float* __restrict__ out,
               int Zi, int Yi, int Xi, int Zo, int Yo, int Xo,
               int tilesZ, int tilesY, int tilesX) {
  __shared__ float4 sin4[4][NV];
  const int perIn = Zi * Yi * Xi;
  const int perOut = Zo * Yo * Xo;
  int bid = blockIdx.x;
  int txi = bid % tilesX; bid /= tilesX;
  int tyi = bid % tilesY; bid /= tilesY;
  int tzi = bid % tilesZ; int item = bid / tilesZ;
  const int z0 = tzi * TZ, y0 = tyi * TY, x0 = txi * TXT;
  const int tid = threadIdx.x;
  const int ox = tid & 15, oy = (tid >> 4) & 3, oz = tid >> 6;

  float4 acc[8];
#pragma unroll
  for (int j = 0; j < 8; ++j) acc[j] = make_float4(0.f, 0.f, 0.f, 0.f);

  const float* inb = in + (size_t)item * perIn * 32;

#pragma unroll 1
  for (int h = 0; h < 2; ++h) {
    __syncthreads();
    for (int idx = tid; idx < NV * 4; idx += 256) {
      int q = idx / NV; int v = idx - q * NV;
      int iz = v / (IY * IX); int r = v - iz * (IY * IX);
      int iy = r / IX; int ix = r - iy * IX;
      int gz = z0 + iz, gy = y0 + iy, gx = x0 + ix;
      float4 val = make_float4(0.f, 0.f, 0.f, 0.f);
      if (gz < Zi && gy < Yi && gx < Xi)
        val = *(const float4*)(inb + (size_t)((gz * Yi + gy) * Xi + gx) * 32 + h * 16 + q * 4);
      sin4[q][v] = val;
    }
    __syncthreads();
#pragma unroll 1
    for (int tap = 0; tap < 64; ++tap) {
      int kz = tap >> 4, ky = (tap >> 2) & 3, kx = tap & 3;
      int lv = ((oz + kz) * IY + (oy + ky)) * IX + (ox + kx);
      float4 a0 = sin4[0][lv];
      float4 a1 = sin4[1][lv];
      float4 a2 = sin4[2][lv];
      float4 a3 = sin4[3][lv];
      const float* wt = wr + __builtin_amdgcn_readfirstlane(tap * 1024 + h * 512);
#pragma unroll
      for (int cq = 0; cq < 4; ++cq) {
        float4 av4 = (cq == 0) ? a0 : (cq == 1) ? a1 : (cq == 2) ? a2 : a3;
#pragma unroll
        for (int u = 0; u < 4; ++u) {
          float av = (u == 0) ? av4.x : (u == 1) ? av4.y : (u == 2) ? av4.z : av4.w;
          const float* wrow = wt + (cq * 4 + u) * 32;
#pragma unroll
          for (int j = 0; j < 8; ++j) {
            float4 wv = *(const float4*)(wrow + j * 4);
            acc[j].x = fmaf(av, wv.x, acc[j].x);
            acc[j].y = fmaf(av, wv.y, acc[j].y);
            acc[j].z = fmaf(av, wv.z, acc[j].z);
            acc[j].w = fmaf(av, wv.w, acc[j].w);
          }
        }
      }
    }
  }

  int gz = z0 + oz, gy = y0 + oy, gx = x0 + ox;
  if (gz < Zo && gy < Yo && gx < Xo) {
    int ov = item * perOut + (gz * Yo + gy) * Xo + gx;
    bool act = mo[ov] > 0.f;
    const float4* b4 = (const float4*)bias;
    float* op = out + (size_t)ov * 32;
#pragma unroll
    for (int j = 0; j < 8; ++j) {
      float4 r = acc[j]; float4 bj = b4[j];
      r.x = lrelu(act ? (r.x + bj.x) : 0.f);
      r.y = lrelu(act ? (r.y + bj.y) : 0.f);
      r.z = lrelu(act ? (r.z + bj.z) : 0.f);
      r.w = lrelu(act ? (r.w + bj.w) : 0.f);
      *(float4*)(op + j * 4) = r;
    }
  }
}

// ---------------- LDS-tiled conv 1->32 (c1) ----------------
__global__ __launch_bounds__(256, 2)
void k_conv1t(const float* __restrict__ in, const float* __restrict__ wr,
              const float* __restrict__ bias, const float* __restrict__ mo,
              float* __restrict__ out,
              int Zi, int Yi, int Xi, int Zo, int Yo, int Xo,
              int tilesZ, int tilesY, int tilesX) {
  __shared__ float sinf[NV];
  const int perIn = Zi * Yi * Xi;
  const int perOut = Zo * Yo * Xo;
  int bid = blockIdx.x;
  int txi = bid % tilesX; bid /= tilesX;
  int tyi = bid % tilesY; bid /= tilesY;
  int tzi = bid % tilesZ; int item = bid / tilesZ;
  const int z0 = tzi * TZ, y0 = tyi * TY, x0 = txi * TXT;
  const int tid = threadIdx.x;
  const int ox = tid & 15, oy = (tid >> 4) & 3, oz = tid >> 6;

  const float* inb = in + (size_t)item * perIn;
  for (int idx = tid; idx < NV; idx += 256) {
    int iz = idx / (IY * IX); int r = idx - iz * (IY * IX);
    int iy = r / IX; int ix = r - iy * IX;
    int gz = z0 + iz, gy = y0 + iy, gx = x0 + ix;
    float val = 0.f;
    if (gz < Zi && gy < Yi && gx < Xi)
      val = inb[(size_t)((gz * Yi + gy) * Xi + gx)];
    sinf[idx] = val;
  }
  __syncthreads();

  float4 acc[8];
#pragma unroll
  for (int j = 0; j < 8; ++j) acc[j] = make_float4(0.f, 0.f, 0.f, 0.f);

#pragma unroll 1
  for (int tap = 0; tap < 64; ++tap) {
    int kz = tap >> 4, ky = (tap >> 2) & 3, kx = tap & 3;
    int lv = ((oz + kz) * IY + (oy + ky)) * IX + (ox + kx);
    float av = sinf[lv];
    const float* wt = wr + __builtin_amdgcn_readfirstlane(tap * 32);
#pragma unroll
    for (int j = 0; j < 8; ++j) {
      float4 wv = *(const float4*)(wt + j * 4);
      acc[j].x = fmaf(av, wv.x, acc[j].x);
      acc[j].y = fmaf(av, wv.y, acc[j].y);
      acc[j].z = fmaf(av, wv.z, acc[j].z);
      acc[j].w = fmaf(av, wv.w, acc[j].w);
    }
  }

  int gz = z0 + oz, gy = y0 + oy, gx = x0 + ox;
  if (gz < Zo && gy < Yo && gx < Xo) {
    int ov = item * perOut + (gz * Yo + gy) * Xo + gx;
    bool act = mo[ov] > 0.f;
    const float4* b4 = (const float4*)bias;
    float* op = out + (size_t)ov * 32;
#pragma unroll
    for (int j = 0; j < 8; ++j) {
      float4 r = acc[j]; float4 bj = b4[j];
      r.x = lrelu(act ? (r.x + bj.x) : 0.f);
      r.y = lrelu(act ? (r.y + bj.y) : 0.f);
      r.z = lrelu(act ? (r.z + bj.z) : 0.f);
      r.w = lrelu(act ? (r.w + bj.w) : 0.f);
      *(float4*)(op + j * 4) = r;
    }
  }
}

// ---------------- LDS-tiled conv 32->1 (c7) ----------------
__global__ __launch_bounds__(256, 2)
void k_conv7t(const float* __restrict__ in, const float* __restrict__ wr,
              const float* __restrict__ bias, const float* __restrict__ mo,
              float* __restrict__ out,
              int Zi, int Yi, int Xi, int Zo, int Yo, int Xo,
              int tilesZ, int tilesY, int tilesX) {
  __shared__ float4 sin4[4][NV];
  const int perIn = Zi * Yi * Xi;
  const int perOut = Zo * Yo * Xo;
  int bid = blockIdx.x;
  int txi = bid % tilesX; bid /= tilesX;
  int tyi = bid % tilesY; bid /= tilesY;
  int tzi = bid % tilesZ; int item = bid / tilesZ;
  const int z0 = tzi * TZ, y0 = tyi * TY, x0 = txi * TXT;
  const int tid = threadIdx.x;
  const int ox = tid & 15, oy = (tid >> 4) & 3, oz = tid >> 6;

  const float* inb = in + (size_t)item * perIn * 32;
  float acc = 0.f;

#pragma unroll 1
  for (int h = 0; h < 2; ++h) {
    __syncthreads();
    for (int idx = tid; idx < NV * 4; idx += 256) {
      int q = idx / NV; int v = idx - q * NV;
      int iz = v / (IY * IX); int r = v - iz * (IY * IX);
      int iy = r / IX; int ix = r - iy * IX;
      int gz = z0 + iz, gy = y0 + iy, gx = x0 + ix;
      float4 val = make_float4(0.f, 0.f, 0.f, 0.f);
      if (gz < Zi && gy < Yi && gx < Xi)
        val = *(const float4*)(inb + (size_t)((gz * Yi + gy) * Xi + gx) * 32 + h * 16 + q * 4);
      sin4[q][v] = val;
    }
    __syncthreads();
#pragma unroll 1
    for (int tap = 0; tap < 64; ++tap) {
      int kz = tap >> 4, ky = (tap >> 2) & 3, kx = tap & 3;
      int lv = ((oz + kz) * IY + (oy + ky)) * IX + (ox + kx);
      float4 a0 = sin4[0][lv];
      float4 a1 = sin4[1][lv];
      float4 a2 = sin4[2][lv];
      float4 a3 = sin4[3][lv];
      const float* wt = wr + __builtin_amdgcn_readfirstlane(tap * 32 + h * 16);
      float4 w0 = *(const float4*)(wt + 0);
      float4 w1 = *(const float4*)(wt + 4);
      float4 w2 = *(const float4*)(wt + 8);
      float4 w3 = *(const float4*)(wt + 12);
      acc += a0.x*w0.x + a0.y*w0.y + a0.z*w0.z + a0.w*w0.w
           + a1.x*w1.x + a1.y*w1.y + a1.z*w1.z + a1.w*w1.w
           + a2.x*w2.x + a2.y*w2.y + a2.z*w2.z + a2.w*w2.w
           + a3.x*w3.x + a3.y*w3.y + a3.z*w3.z + a3.w*w3.w;
    }
  }

  int gz = z0 + oz, gy = y0 + oy, gx = x0 + ox;
  if (gz < Zo && gy < Yo && gx < Xo) {
    int ov = item * perOut + (gz * Yo + gy) * Xo + gx;
    bool act = mo[ov] > 0.f;
    out[ov] = lrelu(act ? (acc + bias[0]) : 0.f);
  }
}

// ---------------- batched separable sparse maxpool (C=32, float4/thread) -----------
__global__ void k_pool_z(const float* __restrict__ in, const float* __restrict__ m,
                         float* __restrict__ out, int Zi, int Yi, int Xi, int Zo, int nI) {
  int gid = blockIdx.x * blockDim.x + threadIdx.x;
  int perOut = Zo * Yi * Xi;
  int tot = nI * perOut * 8;
  if (gid >= tot) return;
  int c4 = gid & 7; int v = gid >> 3;
  int item = v / perOut;
  int r = v - item * perOut;
  int x = r % Xi; int t = r / Xi;
  int y = t % Yi; int z = t / Yi;
  int ib = item * Zi * Yi * Xi;
  float4 acc = {NINF, NINF, NINF, NINF};
  for (int j = 0; j < 5; j++) {
    int vi = ib + ((z + j)*Yi + y)*Xi + x;
    if (m[vi] > 0.f) {
      float4 val = *(const float4*)(in + (size_t)vi*32 + c4*4);
      acc.x = fmaxf(acc.x, val.x); acc.y = fmaxf(acc.y, val.y);
      acc.z = fmaxf(acc.z, val.z); acc.w = fmaxf(acc.w, val.w);
    }
  }
  *(float4*)(out + (size_t)v*32 + c4*4) = acc;
}

__global__ void k_pool_y(const float* __restrict__ in, float* __restrict__ out,
                         int Z, int Yi, int Xi, int Yo, int nI) {
  int gid = blockIdx.x * blockDim.x + threadIdx.x;
  int perOut = Z * Yo * Xi;
  int tot = nI * perOut * 8;
  if (gid >= tot) return;
  int c4 = gid & 7; int v = gid >> 3;
  int item = v / perOut;
  int r = v - item * perOut;
  int x = r % Xi; int t = r / Xi;
  int y = t % Yo; int z = t / Yo;
  int ib = item * Z * Yi * Xi;
  float4 acc = {NINF, NINF, NINF, NINF};
  for (int j = 0; j < 5; j++) {
    int vi = ib + (z*Yi + y + j)*Xi + x;
    float4 val = *(const float4*)(in + (size_t)vi*32 + c4*4);
    acc.x = fmaxf(acc.x, val.x); acc.y = fmaxf(acc.y, val.y);
    acc.z = fmaxf(acc.z, val.z); acc.w = fmaxf(acc.w, val.w);
  }
  *(float4*)(out + (size_t)v*32 + c4*4) = acc;
}

__global__ void k_pool_x(const float* __restrict__ in, const float* __restrict__ mp,
                         float* __restrict__ out, int Z, int Y, int Xi, int Xo, int nI) {
  int gid = blockIdx.x * blockDim.x + threadIdx.x;
  int perOut = Z * Y * Xo;
  int tot = nI * perOut * 8;
  if (gid >= tot) return;
  int c4 = gid & 7; int v = gid >> 3;
  int item = v / perOut;
  int r = v - item * perOut;
  int x = r % Xo; int t = r / Xo;
  int y = t % Y; int z = t / Y;
  int ib = item * Z * Y * Xi;
  float4 acc = {NINF, NINF, NINF, NINF};
  for (int j = 0; j < 5; j++) {
    int vi = ib + (z*Y + y)*Xi + x + j;
    float4 val = *(const float4*)(in + (size_t)vi*32 + c4*4);
    acc.x = fmaxf(acc.x, val.x); acc.y = fmaxf(acc.y, val.y);
    acc.z = fmaxf(acc.z, val.z); acc.w = fmaxf(acc.w, val.w);
  }
  bool act = mp[v] > 0.f;
  float4 rr;
  rr.x = act ? acc.x : 0.f; rr.y = act ? acc.y : 0.f;
  rr.z = act ? acc.z : 0.f; rr.w = act ? acc.w : 0.f;
  *(float4*)(out + (size_t)v*32 + c4*4) = rr;
}

// ---------------- final pool (C=1, direct 5^3), 21,31,36 -> 17,27,32, batched ------
__global__ void k_pool3(const float* __restrict__ xin, const float* __restrict__ m,
                        const float* __restrict__ mp, float* __restrict__ out, int nI) {
  int gid = blockIdx.x * blockDim.x + threadIdx.x;
  int perOut = 17 * 27 * 32;
  int tot = nI * perOut;
  if (gid >= tot) return;
  int item = gid / perOut;
  int r = gid - item * perOut;
  int x = r & 31; int t = r >> 5;
  int y = t % 27; int z = t / 27;
  const float* xb = xin + (size_t)item * 23436;
  const float* mb = m + (size_t)item * 23436;
  float acc = NINF;
  for (int dz = 0; dz < 5; dz++)
    for (int dy = 0; dy < 5; dy++) {
      const float* rowx = xb + (size_t)(((z + dz)*31 + y + dy)*36 + x);
      const float* rowm = mb + (size_t)(((z + dz)*31 + y + dy)*36 + x);
      for (int dx = 0; dx < 5; dx++)
        if (rowm[dx] > 0.f) acc = fmaxf(acc, rowx[dx]);
    }
  out[gid] = (mp[gid] > 0.f) ? acc : 0.f;
}

// ---------------- FC split-K partial + finalize ----------------
__global__ __launch_bounds__(256, 4)
void k_fc_part(const float* __restrict__ X, const float* __restrict__ Wm,
               float* __restrict__ part, int K, int Ncol, int Kc) {
  __shared__ float sm[16][16][8];
  int ks = blockIdx.y;
  int k0 = ks * Kc;
  int k1 = k0 + Kc; if (k1 > K) k1 = K;
  int cl = threadIdx.x & 15;
  int kt = threadIdx.x >> 4;
  int col = blockIdx.x * 16 + cl;
  float a0=0.f,a1=0.f,a2=0.f,a3=0.f,a4=0.f,a5=0.f,a6=0.f,a7=0.f;
  if (col < Ncol) {
    for (int k = k0 + kt; k < k1; k += 16) {
      float w = Wm[(size_t)k * Ncol + col];
      a0 += X[0 * K + k] * w; a1 += X[1 * K + k] * w;
      a2 += X[2 * K + k] * w; a3 += X[3 * K + k] * w;
      a4 += X[4 * K + k] * w; a5 += X[5 * K + k] * w;
      a6 += X[6 * K + k] * w; a7 += X[7 * K + k] * w;
    }
  }
  sm[kt][cl][0]=a0; sm[kt][cl][1]=a1; sm[kt][cl][2]=a2; sm[kt][cl][3]=a3;
  sm[kt][cl][4]=a4; sm[kt][cl][5]=a5; sm[kt][cl][6]=a6; sm[kt][cl][7]=a7;
  __syncthreads();
  if (threadIdx.x < 128) {
    int c = threadIdx.x & 15;
    int b = threadIdx.x >> 4;
    float s = 0.f;
#pragma unroll
    for (int k = 0; k < 16; k++) s += sm[k][c][b];
    int cc = blockIdx.x * 16 + c;
    if (cc < Ncol) part[((size_t)ks * 8 + b) * Ncol + cc] = s;
  }
}

__global__ void k_fc_fin(const float* __restrict__ part, int ns,
                         const float* __restrict__ bias, float* __restrict__ out, int Ncol) {
  int i = blockIdx.x * blockDim.x + threadIdx.x;
  if (i >= 8 * Ncol) return;
  int b = i / Ncol;
  int c = i - b * Ncol;
  float s = 0.f;
  for (int ks = 0; ks < ns; ks++) s += part[((size_t)ks * 8 + b) * Ncol + c];
  out[i] = lrelu(s + bias[c]);
}

// last FC (K=1000 -> 1), small
__global__ __launch_bounds__(256, 4)
void k_fc(const float* __restrict__ X, const float* __restrict__ Wm,
          const float* __restrict__ bias, float* __restrict__ out,
          int K, int Ncol) {
  __shared__ float sm[16][16][8];
  int cl = threadIdx.x & 15;
  int kt = threadIdx.x >> 4;
  int col = blockIdx.x * 16 + cl;
  float a0=0.f,a1=0.f,a2=0.f,a3=0.f,a4=0.f,a5=0.f,a6=0.f,a7=0.f;
  if (col < Ncol) {
    for (int k = kt; k < K; k += 16) {
      float w = Wm[(size_t)k * Ncol + col];
      a0 += X[0 * K + k] * w; a1 += X[1 * K + k] * w;
      a2 += X[2 * K + k] * w; a3 += X[3 * K + k] * w;
      a4 += X[4 * K + k] * w; a5 += X[5 * K + k] * w;
      a6 += X[6 * K + k] * w; a7 += X[7 * K + k] * w;
    }
  }
  sm[kt][cl][0]=a0; sm[kt][cl][1]=a1; sm[kt][cl][2]=a2; sm[kt][cl][3]=a3;
  sm[kt][cl][4]=a4; sm[kt][cl][5]=a5; sm[kt][cl][6]=a6; sm[kt][cl][7]=a7;
  __syncthreads();
  if (threadIdx.x < 128) {
    int c = threadIdx.x & 15;
    int b = threadIdx.x >> 4;
    float s = 0.f;
#pragma unroll
    for (int k = 0; k < 16; k++) s += sm[k][c][b];
    int cc = blockIdx.x * 16 + c;
    if (cc < Ncol) out[b * Ncol + cc] = lrelu(s + bias[cc]);
  }
}

// ---------------- host ----------------
static inline int G256(long long n) { return (int)((n + 255) / 256); }

extern "C" void kernel_launch(void* const* d_in, const int* in_sizes, int n_in,
                              void* d_out, int out_size, void* d_ws, size_t ws_size,
                              hipStream_t stream) {
  const float* feat  = (const float*)d_in[0];
  const int*   coors = (const int*)d_in[1];
  const float* w1 = (const float*)d_in[3];  const float* b1 = (const float*)d_in[4];
  const float* w2 = (const float*)d_in[5];  const float* b2 = (const float*)d_in[6];
  const float* w3 = (const float*)d_in[7];  const float* b3 = (const float*)d_in[8];
  const float* w4 = (const float*)d_in[9];  const float* b4 = (const float*)d_in[10];
  const float* w5 = (const float*)d_in[11]; const float* b5 = (const float*)d_in[12];
  const float* w6 = (const float*)d_in[13]; const float* b6 = (const float*)d_in[14];
  const float* w7 = (const float*)d_in[15]; const float* b7 = (const float*)d_in[16];
  const float* W8 = (const float*)d_in[17]; const float* b8 = (const float*)d_in[18];
  const float* W9 = (const float*)d_in[19]; const float* b9 = (const float*)d_in[20];
  const float* W10= (const float*)d_in[21]; const float* b10= (const float*)d_in[22];
  float* out = (float*)d_out;

  char* ws = (char*)d_ws;
  size_t off = 0;
  auto alloc = [&](size_t nfloats) -> float* {
    float* p = (float*)(ws + off);
    off += ((nfloats * 4 + 1023) / 1024) * 1024;
    return p;
  };

  // ---- fixed allocations ----
  float* x0  = alloc(1560000);
  float* m0  = alloc(1560000);
  float* m1  = alloc(8 * 166098);
  float* m2  = alloc(8 * 140184);
  float* mp1 = alloc(8 * 110000);
  float* m3  = alloc(8 * 90428);
  float* m4  = alloc(8 * 73304);
  float* mp2 = alloc(8 * 54000);
  float* m5  = alloc(8 * 41958);
  float* m6  = alloc(8 * 31824);
  float* m7  = alloc(8 * 23436);
  float* mp3 = alloc(8 * 14688);
  float* p3  = alloc(8 * 14688);
  float* wr1 = alloc(2048);
  float* wr2 = alloc(65536);
  float* wr3 = alloc(65536);
  float* wr4 = alloc(65536);
  float* wr5 = alloc(65536);
  float* wr6 = alloc(65536);
  float* wr7 = alloc(2048);
  float* part= alloc(64000);
  float* h8  = alloc(8000);
  float* h9  = alloc(8000);
  size_t fixedOff = off;

  // ---- pick group size G from remaining workspace ----
  const size_t perItemAB = ((size_t)5315136*4 + 1023)/1024*1024
                         + ((size_t)4485888*4 + 1023)/1024*1024
                         + ((size_t)23436*4 + 1023)/1024*1024;
  int G = 0;
  for (int g : {8, 4, 2, 1})
    if (fixedOff + (size_t)g * perItemAB <= ws_size) { G = g; break; }
  if (G == 0) return;

  float* A  = alloc((size_t)G * 5315136);
  float* Bb = alloc((size_t)G * 4485888);
  float* x7 = alloc((size_t)G * 23436);
  unsigned* claim = (unsigned*)A;   // claim aliases A (dead before first conv use)

  // ---- init ----
  hipMemsetAsync(claim, 0, 1560000 * 4, stream);
  hipMemsetAsync(x0,    0, 1560000 * 4, stream);
  hipMemsetAsync(m0,    0, 1560000 * 4, stream);

  k_repack<<<G256(32*1*64),  256, 0, stream>>>(w1, wr1, 1, 32);
  k_repack<<<G256(32*32*64), 256, 0, stream>>>(w2, wr2, 32, 32);
  k_repack<<<G256(32*32*64), 256, 0, stream>>>(w3, wr3, 32, 32);
  k_repack<<<G256(32*32*64), 256, 0, stream>>>(w4, wr4, 32, 32);
  k_repack<<<G256(32*32*64), 256, 0, stream>>>(w5, wr5, 32, 32);
  k_repack<<<G256(32*32*64), 256, 0, stream>>>(w6, wr6, 32, 32);
  k_repack<<<G256(1*32*64),  256, 0, stream>>>(w7, wr7, 32, 1);

  const int N = 80000;
  k_claim  <<<G256(N), 256, 0, stream>>>(coors, claim, N);
  k_scatter<<<G256(N), 256, 0, stream>>>(coors, feat, claim, x0, m0, N);

  // ---- all mask dilations, batched over 8 items ----
  k_dilate<<<G256(8*166098), 256, 0, stream>>>(m0,  m1,  50,60,65, 47,57,62, 4, 8);
  k_dilate<<<G256(8*140184), 256, 0, stream>>>(m1,  m2,  47,57,62, 44,54,59, 4, 8);
  k_dilate<<<G256(8*110000), 256, 0, stream>>>(m2,  mp1, 44,54,59, 40,50,55, 5, 8);
  k_dilate<<<G256(8*90428),  256, 0, stream>>>(mp1, m3,  40,50,55, 37,47,52, 4, 8);
  k_dilate<<<G256(8*73304),  256, 0, stream>>>(m3,  m4,  37,47,52, 34,44,49, 4, 8);
  k_dilate<<<G256(8*54000),  256, 0, stream>>>(m4,  mp2, 34,44,49, 30,40,45, 5, 8);
  k_dilate<<<G256(8*41958),  256, 0, stream>>>(mp2, m5,  30,40,45, 27,37,42, 4, 8);
  k_dilate<<<G256(8*31824),  256, 0, stream>>>(m5,  m6,  27,37,42, 24,34,39, 4, 8);
  k_dilate<<<G256(8*23436),  256, 0, stream>>>(m6,  m7,  24,34,39, 21,31,36, 4, 8);
  k_dilate<<<G256(8*14688),  256, 0, stream>>>(m7,  mp3, 21,31,36, 17,27,32, 5, 8);

  auto conv32 = [&](const float* in, const float* wrp, const float* bias,
                    const float* mo, float* o,
                    int Zi, int Yi, int Xi, int Zo, int Yo, int Xo, int nI) {
    int tz = (Zo + TZ - 1) / TZ, ty = (Yo + TY - 1) / TY, tx = (Xo + TXT - 1) / TXT;
    k_conv32t<<<nI * tz * ty * tx, 256, 0, stream>>>(
        in, wrp, bias, mo, o, Zi, Yi, Xi, Zo, Yo, Xo, tz, ty, tx);
  };

  for (int g0 = 0; g0 < 8; g0 += G) {
    const float* x0g  = x0  + (size_t)g0 * 195000;
    const float* m1g  = m1  + (size_t)g0 * 166098;
    const float* m2g  = m2  + (size_t)g0 * 140184;
    const float* mp1g = mp1 + (size_t)g0 * 110000;
    const float* m3g  = m3  + (size_t)g0 * 90428;
    const float* m4g  = m4  + (size_t)g0 * 73304;
    const float* mp2g = mp2 + (size_t)g0 * 54000;
    const float* m5g  = m5  + (size_t)g0 * 41958;
    const float* m6g  = m6  + (size_t)g0 * 31824;
    const float* m7g  = m7  + (size_t)g0 * 23436;
    const float* mp3g = mp3 + (size_t)g0 * 14688;

    // c1: 50,60,65 -> 47,57,62
    {
      int tz = (47 + TZ - 1) / TZ, ty = (57 + TY - 1) / TY, tx = (62 + TXT - 1) / TXT;
      k_conv1t<<<G * tz * ty * tx, 256, 0, stream>>>(
          x0g, wr1, b1, m1g, A, 50,60,65, 47,57,62, tz, ty, tx);
    }
    // c2 -> 44,54,59
    conv32(A, wr2, b2, m2g, Bb, 47,57,62, 44,54,59, G);
    // p1 -> 40,50,55
    k_pool_z<<<G256((long long)G*127440*8), 256, 0, stream>>>(Bb, m2g,  A,  44,54,59, 40, G);
    k_pool_y<<<G256((long long)G*118000*8), 256, 0, stream>>>(A,  Bb, 40,54,59, 50, G);
    k_pool_x<<<G256((long long)G*110000*8), 256, 0, stream>>>(Bb, mp1g, A,  40,50,59, 55, G);
    // c3 -> 37,47,52
    conv32(A, wr3, b3, m3g, Bb, 40,50,55, 37,47,52, G);
    // c4 -> 34,44,49
    conv32(Bb, wr4, b4, m4g, A, 37,47,52, 34,44,49, G);
    // p2 -> 30,40,45
    k_pool_z<<<G256((long long)G*64680*8), 256, 0, stream>>>(A,  m4g,  Bb, 34,44,49, 30, G);
    k_pool_y<<<G256((long long)G*58800*8), 256, 0, stream>>>(Bb, A,  30,44,49, 40, G);
    k_pool_x<<<G256((long long)G*54000*8), 256, 0, stream>>>(A,  mp2g, Bb, 30,40,49, 45, G);
    // c5 -> 27,37,42
    conv32(Bb, wr5, b5, m5g, A, 30,40,45, 27,37,42, G);
    // c6 -> 24,34,39
    conv32(A, wr6, b6, m6g, Bb, 27,37,42, 24,34,39, G);
    // c7 (32->1) -> 21,31,36
    {
      int tz = (21 + TZ - 1) / TZ, ty = (31 + TY - 1) / TY, tx = (36 + TXT - 1) / TXT;
      k_conv7t<<<G * tz * ty * tx, 256, 0, stream>>>(
          Bb, wr7, b7, m7g, x7, 24,34,39, 21,31,36, tz, ty, tx);
    }
    // p3 -> 17,27,32
    k_pool3<<<G256((long long)G*14688), 256, 0, stream>>>(
        x7, m7g, mp3g, p3 + (size_t)g0 * 14688, G);
  }

  // ---- FC head ----
  k_fc_part<<<dim3(63, 8), 256, 0, stream>>>(p3, W8, part, 14688, 1000, 1836);
  k_fc_fin <<<G256(8000), 256, 0, stream>>>(part, 8, b8, h8, 1000);
  k_fc_part<<<dim3(63, 4), 256, 0, stream>>>(h8, W9, part, 1000, 1000, 250);
  k_fc_fin <<<G256(8000), 256, 0, stream>>>(part, 4, b9, h9, 1000);
  k_fc<<<1, 256, 0, stream>>>(h9, W10, b10, out, 1000, 1);
}

// Round 6
// 3699.907 us; speedup vs baseline: 28.8691x; 3.9056x over previous
//
#include <hip/hip_runtime.h>
#include <cstddef>

// Sparse 3D CNN. R5: conv32 layers moved to MFMA (bf16 hi/lo split, 2-mfma
// K-pack trick => full 4-term product in 2x mfma count, fp32 accumulate).
// R4 was scalar-weight-stall-bound (36 TF, VALUBusy 29%): 512 weight floats
// per tap streamed via s_load with ~200cyc L2 waits. Now weights are
// precomputed per-lane B-fragments (L2-hot vector loads) and activations are
// bf16-split slabs in LDS read as A-fragments.
// Chain: 50,60,65 -> c1 47,57,62 -> c2 44,54,59 -> p1 40,50,55 -> c3 37,47,52
// -> c4 34,44,49 -> p2 30,40,45 -> c5 27,37,42 -> c6 24,34,39 -> c7 21,31,36
// -> p3 17,27,32 ; flatten 14688 -> FC 1000 -> 1000 -> 1

#define NEGSLOPE 0.01f
#define NINF (-3.0e38f)

#define TZ 4
#define TY 4
#define TXT 16
#define IZ 7
#define IY 7
#define IX 19
#define NV (IZ*IY*IX)   // 931 halo voxels

typedef __attribute__((ext_vector_type(8)))  short  short8;    // 8 bf16
typedef __attribute__((ext_vector_type(16))) float  floatx16;  // 32x32 acc

__device__ __forceinline__ float lrelu(float v) { return v >= 0.f ? v : NEGSLOPE * v; }

__device__ __forceinline__ unsigned short f2bf(float f) {
  unsigned b = __float_as_uint(f);
  return (unsigned short)((b + 0x7fffu + ((b >> 16) & 1u)) >> 16);   // RNE
}
__device__ __forceinline__ float bf2f(unsigned short h) {
  return __uint_as_float(((unsigned)h) << 16);
}
__device__ __forceinline__ unsigned splitpair(float a, float b, unsigned& lo) {
  unsigned short ha = f2bf(a), hb = f2bf(b);
  unsigned short la = f2bf(a - bf2f(ha)), lb = f2bf(b - bf2f(hb));
  lo = (unsigned)la | ((unsigned)lb << 16);
  return (unsigned)ha | ((unsigned)hb << 16);
}

// ---------------- scatter (last-write-wins), full batch ----------------
__global__ void k_claim(const int* __restrict__ coors, unsigned* __restrict__ claim, int N) {
  int i = blockIdx.x * blockDim.x + threadIdx.x;
  if (i >= N) return;
  int b = coors[4*i], z = coors[4*i+1], y = coors[4*i+2], x = coors[4*i+3];
  int v = ((b*50 + z)*60 + y)*65 + x;
  atomicMax(&claim[v], (unsigned)(i + 1));
}

__global__ void k_scatter(const int* __restrict__ coors, const float* __restrict__ feat,
                          const unsigned* __restrict__ claim,
                          float* __restrict__ x0, float* __restrict__ m0, int N) {
  int i = blockIdx.x * blockDim.x + threadIdx.x;
  if (i >= N) return;
  int b = coors[4*i], z = coors[4*i+1], y = coors[4*i+2], x = coors[4*i+3];
  int v = ((b*50 + z)*60 + y)*65 + x;
  m0[v] = 1.f;
  if (claim[v] == (unsigned)(i + 1)) x0[v] = feat[i];
}

// ---------------- weight repack (c1/c7): w[co][ci][k64] -> wr[k64][ci][co] --------
__global__ void k_repack(const float* __restrict__ w, float* __restrict__ wr, int CI, int CO) {
  int i = blockIdx.x * blockDim.x + threadIdx.x;
  int tot = CO * CI * 64;
  if (i >= tot) return;
  int k = i & 63;
  int ci = (i >> 6) % CI;
  int co = i / (64 * CI);
  wr[(k * CI + ci) * CO + co] = w[i];
}

// ---------------- MFMA B-fragment table build for 32->32 layers ----------------
// tbl layout: [(tap*4 + pass)*2 + pack][lane 0..63][8 bf16]  (1 KB per frag)
// pack0: k 0..7 = wh(ci), k 8..15 = wl(ci); pack1 swapped. ci = pass*8 + (k&7).
__global__ void k_repack_mfma(const float* __restrict__ w, unsigned short* __restrict__ tbl) {
  int i = blockIdx.x * blockDim.x + threadIdx.x;   // 0..32767
  if (i >= 64*4*2*64) return;
  int lane = i & 63; int t = i >> 6;
  int pack = t & 1; t >>= 1;
  int pass = t & 3; int tap = t >> 2;
  int co = lane & 31; int oct = lane >> 5;
#pragma unroll
  for (int j = 0; j < 8; ++j) {
    int k = oct * 8 + j;
    int ci = pass * 8 + (k & 7);
    int part = ((k >> 3) ^ pack) & 1;
    float wv = w[((co * 32 + ci) << 6) + tap];
    unsigned short wh = f2bf(wv);
    unsigned short r = part ? f2bf(wv - bf2f(wh)) : wh;
    tbl[(size_t)i * 8 + j] = r;
  }
}

// ---------------- batched mask dilation (window K, VALID) ----------------
__global__ void k_dilate(const float* __restrict__ m, float* __restrict__ o,
                         int Zi, int Yi, int Xi, int Zo, int Yo, int Xo, int K, int nI) {
  int gid = blockIdx.x * blockDim.x + threadIdx.x;
  int perOut = Zo * Yo * Xo;
  int tot = nI * perOut;
  if (gid >= tot) return;
  int item = gid / perOut;
  int r = gid - item * perOut;
  int x = r % Xo; int t = r / Xo;
  int y = t % Yo; int z = t / Yo;
  const float* mb = m + (size_t)item * Zi * Yi * Xi;
  float mx = 0.f;
  for (int dz = 0; dz < K; dz++)
    for (int dy = 0; dy < K; dy++) {
      const float* row = mb + (size_t)(((z + dz)*Yi + y + dy)*Xi + x);
      for (int dx = 0; dx < K; dx++) mx = fmaxf(mx, row[dx]);
    }
  o[gid] = mx;
}

// ---------------- MFMA conv 32->32 ----------------
// Block = 4x4x16 output tile (256 thr, 4 waves). Wave owns 2 groups of 32
// voxels (mfma m-dim). 4 passes of 8 ci; LDS holds halo as bf16 hi/lo slabs,
// 48 B/voxel stride (bank-spread). Per tap: 2 B-frags (pack0/1) from global
// table, 1 A-frag ds_read per group, 2 mfma per group.
__global__ __launch_bounds__(256, 3)
void k_conv32m(const float* __restrict__ in, const unsigned short* __restrict__ tbl,
               const float* __restrict__ bias, const float* __restrict__ mo,
               float* __restrict__ out,
               int Zi, int Yi, int Xi, int Zo, int Yo, int Xo,
               int tilesZ, int tilesY, int tilesX) {
  __shared__ unsigned sU[NV * 12];   // 44.7 KB
  const int perIn = Zi * Yi * Xi;
  const int perOut = Zo * Yo * Xo;
  int bid = blockIdx.x;
  int txi = bid % tilesX; bid /= tilesX;
  int tyi = bid % tilesY; bid /= tilesY;
  int tzi = bid % tilesZ; int item = bid / tilesZ;
  const int z0 = tzi * TZ, y0 = tyi * TY, x0 = txi * TXT;
  const int tid = threadIdx.x;
  const int lane = tid & 63;
  const int col = lane & 31;     // co and A-row m
  const int oct = lane >> 5;
  const int wv  = tid >> 6;      // wave 0..3

  int lvBase0, lvBase1;
  {
    int vt0 = (2*wv + 0)*32 + col;
    int vt1 = (2*wv + 1)*32 + col;
    lvBase0 = ((vt0 >> 6)*IY + ((vt0 >> 4) & 3))*IX + (vt0 & 15);
    lvBase1 = ((vt1 >> 6)*IY + ((vt1 >> 4) & 3))*IX + (vt1 & 15);
  }

  floatx16 acc0, acc1;
#pragma unroll
  for (int r = 0; r < 16; ++r) { acc0[r] = 0.f; acc1[r] = 0.f; }

  const float* inb = in + (size_t)item * perIn * 32;
  const char* tb = (const char*)tbl + lane * 16;

#pragma unroll 1
  for (int p = 0; p < 4; ++p) {
    __syncthreads();
    for (int idx = tid; idx < NV; idx += 256) {
      int iz = idx / (IY * IX); int r = idx - iz * (IY * IX);
      int iy = r / IX; int ix = r - iy * IX;
      int gz = z0 + iz, gy = y0 + iy, gx = x0 + ix;
      float4 f0 = make_float4(0.f,0.f,0.f,0.f), f1 = make_float4(0.f,0.f,0.f,0.f);
      if (gz < Zi && gy < Yi && gx < Xi) {
        const float* vp = inb + (size_t)((gz * Yi + gy) * Xi + gx) * 32 + p * 8;
        f0 = *(const float4*)vp;
        f1 = *(const float4*)(vp + 4);
      }
      unsigned l0, l1, l2, l3;
      unsigned h0 = splitpair(f0.x, f0.y, l0);
      unsigned h1 = splitpair(f0.z, f0.w, l1);
      unsigned h2 = splitpair(f1.x, f1.y, l2);
      unsigned h3 = splitpair(f1.z, f1.w, l3);
      uint4 ahv = {h0, h1, h2, h3};
      uint4 alv = {l0, l1, l2, l3};
      ((uint4*)sU)[idx * 3 + 0] = ahv;
      ((uint4*)sU)[idx * 3 + 1] = alv;
    }
    __syncthreads();

    const char* tp = tb + (size_t)p * 2048;
#pragma unroll 2
    for (int tap = 0; tap < 64; ++tap) {
      int kz = tap >> 4, ky = (tap >> 2) & 3, kx = tap & 3;
      int sOff = (kz * IY + ky) * IX + kx;
      short8 b0 = *(const short8*)(tp + (size_t)tap * 8192);
      short8 b1 = *(const short8*)(tp + (size_t)tap * 8192 + 1024);
      short8 a0 = *(const short8*)((const char*)sU + (size_t)(lvBase0 + sOff) * 48 + oct * 16);
      short8 a1 = *(const short8*)((const char*)sU + (size_t)(lvBase1 + sOff) * 48 + oct * 16);
      acc0 = __builtin_amdgcn_mfma_f32_32x32x16_bf16(a0, b0, acc0, 0, 0, 0);
      acc0 = __builtin_amdgcn_mfma_f32_32x32x16_bf16(a0, b1, acc0, 0, 0, 0);
      acc1 = __builtin_amdgcn_mfma_f32_32x32x16_bf16(a1, b0, acc1, 0, 0, 0);
      acc1 = __builtin_amdgcn_mfma_f32_32x32x16_bf16(a1, b1, acc1, 0, 0, 0);
    }
  }

  // epilogue: C/D layout col=lane&31, row=(reg&3)+8*(reg>>2)+4*(lane>>5)
  const float bco = bias[col];
#pragma unroll
  for (int gg = 0; gg < 2; ++gg) {
    int vtb = (2*wv + gg) * 32;
#pragma unroll
    for (int rg = 0; rg < 16; ++rg) {
      int row = (rg & 3) + 8 * (rg >> 2) + 4 * oct;
      int vt = vtb + row;
      int oz = vt >> 6, oy = (vt >> 4) & 3, ox = vt & 15;
      int gz = z0 + oz, gy = y0 + oy, gx = x0 + ox;
      if (gz < Zo && gy < Yo && gx < Xo) {
        int ov = item * perOut + (gz * Yo + gy) * Xo + gx;
        float val = (gg == 0) ? acc0[rg] : acc1[rg];
        bool act = mo[ov] > 0.f;
        out[(size_t)ov * 32 + col] = lrelu(act ? (val + bco) : 0.f);
      }
    }
  }
}

// ---------------- LDS-tiled conv 1->32 (c1), weights in LDS ----------------
__global__ __launch_bounds__(256, 2)
void k_conv1t(const float* __restrict__ in, const float* __restrict__ wr,
              const float* __restrict__ bias, const float* __restrict__ mo,
              float* __restrict__ out,
              int Zi, int Yi, int Xi, int Zo, int Yo, int Xo,
              int tilesZ, int tilesY, int tilesX) {
  __shared__ float sinf[NV];
  __shared__ float4 wsh[512];   // 64 taps x 8 co-quads
  {
    const float4* wr4 = (const float4*)wr;
    for (int idx = threadIdx.x; idx < 512; idx += 256) wsh[idx] = wr4[idx];
  }
  const int perIn = Zi * Yi * Xi;
  const int perOut = Zo * Yo * Xo;
  int bid = blockIdx.x;
  int txi = bid % tilesX; bid /= tilesX;
  int tyi = bid % tilesY; bid /= tilesY;
  int tzi = bid % tilesZ; int item = bid / tilesZ;
  const int z0 = tzi * TZ, y0 = tyi * TY, x0 = txi * TXT;
  const int tid = threadIdx.x;
  const int ox = tid & 15, oy = (tid >> 4) & 3, oz = tid >> 6;

  const float* inb = in + (size_t)item * perIn;
  for (int idx = tid; idx < NV; idx += 256) {
    int iz = idx / (IY * IX); int r = idx - iz * (IY * IX);
    int iy = r / IX; int ix = r - iy * IX;
    int gz = z0 + iz, gy = y0 + iy, gx = x0 + ix;
    float val = 0.f;
    if (gz < Zi && gy < Yi && gx < Xi)
      val = inb[(size_t)((gz * Yi + gy) * Xi + gx)];
    sinf[idx] = val;
  }
  __syncthreads();

  float4 acc[8];
#pragma unroll
  for (int j = 0; j < 8; ++j) acc[j] = make_float4(0.f, 0.f, 0.f, 0.f);

#pragma unroll 1
  for (int tap = 0; tap < 64; ++tap) {
    int kz = tap >> 4, ky = (tap >> 2) & 3, kx = tap & 3;
    int lv = ((oz + kz) * IY + (oy + ky)) * IX + (ox + kx);
    float av = sinf[lv];
#pragma unroll
    for (int j = 0; j < 8; ++j) {
      float4 wvv = wsh[tap * 8 + j];
      acc[j].x = fmaf(av, wvv.x, acc[j].x);
      acc[j].y = fmaf(av, wvv.y, acc[j].y);
      acc[j].z = fmaf(av, wvv.z, acc[j].z);
      acc[j].w = fmaf(av, wvv.w, acc[j].w);
    }
  }

  int gz = z0 + oz, gy = y0 + oy, gx = x0 + ox;
  if (gz < Zo && gy < Yo && gx < Xo) {
    int ov = item * perOut + (gz * Yo + gy) * Xo + gx;
    bool act = mo[ov] > 0.f;
    const float4* b4 = (const float4*)bias;
    float* op = out + (size_t)ov * 32;
#pragma unroll
    for (int j = 0; j < 8; ++j) {
      float4 r = acc[j]; float4 bj = b4[j];
      r.x = lrelu(act ? (r.x + bj.x) : 0.f);
      r.y = lrelu(act ? (r.y + bj.y) : 0.f);
      r.z = lrelu(act ? (r.z + bj.z) : 0.f);
      r.w = lrelu(act ? (r.w + bj.w) : 0.f);
      *(float4*)(op + j * 4) = r;
    }
  }
}

// ---------------- LDS-tiled conv 32->1 (c7), weights in LDS ----------------
__global__ __launch_bounds__(256, 2)
void k_conv7t(const float* __restrict__ in, const float* __restrict__ wr,
              const float* __restrict__ bias, const float* __restrict__ mo,
              float* __restrict__ out,
              int Zi, int Yi, int Xi, int Zo, int Yo, int Xo,
              int tilesZ, int tilesY, int tilesX) {
  __shared__ float4 sin4[4][NV];
  __shared__ float4 wsh[512];   // 64 taps x 8 ci-quads
  {
    const float4* wr4 = (const float4*)wr;
    for (int idx = threadIdx.x; idx < 512; idx += 256) wsh[idx] = wr4[idx];
  }
  const int perIn = Zi * Yi * Xi;
  const int perOut = Zo * Yo * Xo;
  int bid = blockIdx.x;
  int txi = bid % tilesX; bid /= tilesX;
  int tyi = bid % tilesY; bid /= tilesY;
  int tzi = bid % tilesZ; int item = bid / tilesZ;
  const int z0 = tzi * TZ, y0 = tyi * TY, x0 = txi * TXT;
  const int tid = threadIdx.x;
  const int ox = tid & 15, oy = (tid >> 4) & 3, oz = tid >> 6;

  const float* inb = in + (size_t)item * perIn * 32;
  float acc = 0.f;

#pragma unroll 1
  for (int h = 0; h < 2; ++h) {
    __syncthreads();
    for (int idx = tid; idx < NV * 4; idx += 256) {
      int q = idx / NV; int v = idx - q * NV;
      int iz = v / (IY * IX); int r = v - iz * (IY * IX);
      int iy = r / IX; int ix = r - iy * IX;
      int gz = z0 + iz, gy = y0 + iy, gx = x0 + ix;
      float4 val = make_float4(0.f, 0.f, 0.f, 0.f);
      if (gz < Zi && gy < Yi && gx < Xi)
        val = *(const float4*)(inb + (size_t)((gz * Yi + gy) * Xi + gx) * 32 + h * 16 + q * 4);
      sin4[q][v] = val;
    }
    __syncthreads();
#pragma unroll 1
    for (int tap = 0; tap < 64; ++tap) {
      int kz = tap >> 4, ky = (tap >> 2) & 3, kx = tap & 3;
      int lv = ((oz + kz) * IY + (oy + ky)) * IX + (ox + kx);
      float4 a0 = sin4[0][lv];
      float4 a1 = sin4[1][lv];
      float4 a2 = sin4[2][lv];
      float4 a3 = sin4[3][lv];
      float4 w0 = wsh[tap * 8 + h * 4 + 0];
      float4 w1 = wsh[tap * 8 + h * 4 + 1];
      float4 w2 = wsh[tap * 8 + h * 4 + 2];
      float4 w3 = wsh[tap * 8 + h * 4 + 3];
      acc += a0.x*w0.x + a0.y*w0.y + a0.z*w0.z + a0.w*w0.w
           + a1.x*w1.x + a1.y*w1.y + a1.z*w1.z + a1.w*w1.w
           + a2.x*w2.x + a2.y*w2.y + a2.z*w2.z + a2.w*w2.w
           + a3.x*w3.x + a3.y*w3.y + a3.z*w3.z + a3.w*w3.w;
    }
  }

  int gz = z0 + oz, gy = y0 + oy, gx = x0 + ox;
  if (gz < Zo && gy < Yo && gx < Xo) {
    int ov = item * perOut + (gz * Yo + gy) * Xo + gx;
    bool act = mo[ov] > 0.f;
    out[ov] = lrelu(act ? (acc + bias[0]) : 0.f);
  }
}

// ---------------- batched separable sparse maxpool (C=32, float4/thread) -----------
__global__ void k_pool_z(const float* __restrict__ in, const float* __restrict__ m,
                         float* __restrict__ out, int Zi, int Yi, int Xi, int Zo, int nI) {
  int gid = blockIdx.x * blockDim.x + threadIdx.x;
  int perOut = Zo * Yi * Xi;
  int tot = nI * perOut * 8;
  if (gid >= tot) return;
  int c4 = gid & 7; int v = gid >> 3;
  int item = v / perOut;
  int r = v - item * perOut;
  int x = r % Xi; int t = r / Xi;
  int y = t % Yi; int z = t / Yi;
  int ib = item * Zi * Yi * Xi;
  float4 acc = {NINF, NINF, NINF, NINF};
  for (int j = 0; j < 5; j++) {
    int vi = ib + ((z + j)*Yi + y)*Xi + x;
    if (m[vi] > 0.f) {
      float4 val = *(const float4*)(in + (size_t)vi*32 + c4*4);
      acc.x = fmaxf(acc.x, val.x); acc.y = fmaxf(acc.y, val.y);
      acc.z = fmaxf(acc.z, val.z); acc.w = fmaxf(acc.w, val.w);
    }
  }
  *(float4*)(out + (size_t)v*32 + c4*4) = acc;
}

__global__ void k_pool_y(const float* __restrict__ in, float* __restrict__ out,
                         int Z, int Yi, int Xi, int Yo, int nI) {
  int gid = blockIdx.x * blockDim.x + threadIdx.x;
  int perOut = Z * Yo * Xi;
  int tot = nI * perOut * 8;
  if (gid >= tot) return;
  int c4 = gid & 7; int v = gid >> 3;
  int item = v / perOut;
  int r = v - item * perOut;
  int x = r % Xi; int t = r / Xi;
  int y = t % Yo; int z = t / Yo;
  int ib = item * Z * Yi * Xi;
  float4 acc = {NINF, NINF, NINF, NINF};
  for (int j = 0; j < 5; j++) {
    int vi = ib + (z*Yi + y + j)*Xi + x;
    float4 val = *(const float4*)(in + (size_t)vi*32 + c4*4);
    acc.x = fmaxf(acc.x, val.x); acc.y = fmaxf(acc.y, val.y);
    acc.z = fmaxf(acc.z, val.z); acc.w = fmaxf(acc.w, val.w);
  }
  *(float4*)(out + (size_t)v*32 + c4*4) = acc;
}

__global__ void k_pool_x(const float* __restrict__ in, const float* __restrict__ mp,
                         float* __restrict__ out, int Z, int Y, int Xi, int Xo, int nI) {
  int gid = blockIdx.x * blockDim.x + threadIdx.x;
  int perOut = Z * Y * Xo;
  int tot = nI * perOut * 8;
  if (gid >= tot) return;
  int c4 = gid & 7; int v = gid >> 3;
  int item = v / perOut;
  int r = v - item * perOut;
  int x = r % Xo; int t = r / Xo;
  int y = t % Y; int z = t / Y;
  int ib = item * Z * Y * Xi;
  float4 acc = {NINF, NINF, NINF, NINF};
  for (int j = 0; j < 5; j++) {
    int vi = ib + (z*Y + y)*Xi + x + j;
    float4 val = *(const float4*)(in + (size_t)vi*32 + c4*4);
    acc.x = fmaxf(acc.x, val.x); acc.y = fmaxf(acc.y, val.y);
    acc.z = fmaxf(acc.z, val.z); acc.w = fmaxf(acc.w, val.w);
  }
  bool act = mp[v] > 0.f;
  float4 rr;
  rr.x = act ? acc.x : 0.f; rr.y = act ? acc.y : 0.f;
  rr.z = act ? acc.z : 0.f; rr.w = act ? acc.w : 0.f;
  *(float4*)(out + (size_t)v*32 + c4*4) = rr;
}

// ---------------- final pool (C=1, direct 5^3), 21,31,36 -> 17,27,32, batched ------
__global__ void k_pool3(const float* __restrict__ xin, const float* __restrict__ m,
                        const float* __restrict__ mp, float* __restrict__ out, int nI) {
  int gid = blockIdx.x * blockDim.x + threadIdx.x;
  int perOut = 17 * 27 * 32;
  int tot = nI * perOut;
  if (gid >= tot) return;
  int item = gid / perOut;
  int r = gid - item * perOut;
  int x = r & 31; int t = r >> 5;
  int y = t % 27; int z = t / 27;
  const float* xb = xin + (size_t)item * 23436;
  const float* mb = m + (size_t)item * 23436;
  float acc = NINF;
  for (int dz = 0; dz < 5; dz++)
    for (int dy = 0; dy < 5; dy++) {
      const float* rowx = xb + (size_t)(((z + dz)*31 + y + dy)*36 + x);
      const float* rowm = mb + (size_t)(((z + dz)*31 + y + dy)*36 + x);
      for (int dx = 0; dx < 5; dx++)
        if (rowm[dx] > 0.f) acc = fmaxf(acc, rowx[dx]);
    }
  out[gid] = (mp[gid] > 0.f) ? acc : 0.f;
}

// ---------------- FC split-K partial + finalize ----------------
__global__ __launch_bounds__(256, 4)
void k_fc_part(const float* __restrict__ X, const float* __restrict__ Wm,
               float* __restrict__ part, int K, int Ncol, int Kc) {
  __shared__ float sm[16][16][8];
  int ks = blockIdx.y;
  int k0 = ks * Kc;
  int k1 = k0 + Kc; if (k1 > K) k1 = K;
  int cl = threadIdx.x & 15;
  int kt = threadIdx.x >> 4;
  int col = blockIdx.x * 16 + cl;
  float a0=0.f,a1=0.f,a2=0.f,a3=0.f,a4=0.f,a5=0.f,a6=0.f,a7=0.f;
  if (col < Ncol) {
    for (int k = k0 + kt; k < k1; k += 16) {
      float w = Wm[(size_t)k * Ncol + col];
      a0 += X[0 * K + k] * w; a1 += X[1 * K + k] * w;
      a2 += X[2 * K + k] * w; a3 += X[3 * K + k] * w;
      a4 += X[4 * K + k] * w; a5 += X[5 * K + k] * w;
      a6 += X[6 * K + k] * w; a7 += X[7 * K + k] * w;
    }
  }
  sm[kt][cl][0]=a0; sm[kt][cl][1]=a1; sm[kt][cl][2]=a2; sm[kt][cl][3]=a3;
  sm[kt][cl][4]=a4; sm[kt][cl][5]=a5; sm[kt][cl][6]=a6; sm[kt][cl][7]=a7;
  __syncthreads();
  if (threadIdx.x < 128) {
    int c = threadIdx.x & 15;
    int b = threadIdx.x >> 4;
    float s = 0.f;
#pragma unroll
    for (int k = 0; k < 16; k++) s += sm[k][c][b];
    int cc = blockIdx.x * 16 + c;
    if (cc < Ncol) part[((size_t)ks * 8 + b) * Ncol + cc] = s;
  }
}

__global__ void k_fc_fin(const float* __restrict__ part, int ns,
                         const float* __restrict__ bias, float* __restrict__ out, int Ncol) {
  int i = blockIdx.x * blockDim.x + threadIdx.x;
  if (i >= 8 * Ncol) return;
  int b = i / Ncol;
  int c = i - b * Ncol;
  float s = 0.f;
  for (int ks = 0; ks < ns; ks++) s += part[((size_t)ks * 8 + b) * Ncol + c];
  out[i] = lrelu(s + bias[c]);
}

// last FC (K=1000 -> 1), small
__global__ __launch_bounds__(256, 4)
void k_fc(const float* __restrict__ X, const float* __restrict__ Wm,
          const float* __restrict__ bias, float* __restrict__ out,
          int K, int Ncol) {
  __shared__ float sm[16][16][8];
  int cl = threadIdx.x & 15;
  int kt = threadIdx.x >> 4;
  int col = blockIdx.x * 16 + cl;
  float a0=0.f,a1=0.f,a2=0.f,a3=0.f,a4=0.f,a5=0.f,a6=0.f,a7=0.f;
  if (col < Ncol) {
    for (int k = kt; k < K; k += 16) {
      float w = Wm[(size_t)k * Ncol + col];
      a0 += X[0 * K + k] * w; a1 += X[1 * K + k] * w;
      a2 += X[2 * K + k] * w; a3 += X[3 * K + k] * w;
      a4 += X[4 * K + k] * w; a5 += X[5 * K + k] * w;
      a6 += X[6 * K + k] * w; a7 += X[7 * K + k] * w;
    }
  }
  sm[kt][cl][0]=a0; sm[kt][cl][1]=a1; sm[kt][cl][2]=a2; sm[kt][cl][3]=a3;
  sm[kt][cl][4]=a4; sm[kt][cl][5]=a5; sm[kt][cl][6]=a6; sm[kt][cl][7]=a7;
  __syncthreads();
  if (threadIdx.x < 128) {
    int c = threadIdx.x & 15;
    int b = threadIdx.x >> 4;
    float s = 0.f;
#pragma unroll
    for (int k = 0; k < 16; k++) s += sm[k][c][b];
    int cc = blockIdx.x * 16 + c;
    if (cc < Ncol) out[b * Ncol + cc] = lrelu(s + bias[cc]);
  }
}

// ---------------- host ----------------
static inline int G256(long long n) { return (int)((n + 255) / 256); }

extern "C" void kernel_launch(void* const* d_in, const int* in_sizes, int n_in,
                              void* d_out, int out_size, void* d_ws, size_t ws_size,
                              hipStream_t stream) {
  const float* feat  = (const float*)d_in[0];
  const int*   coors = (const int*)d_in[1];
  const float* w1 = (const float*)d_in[3];  const float* b1 = (const float*)d_in[4];
  const float* w2 = (const float*)d_in[5];  const float* b2 = (const float*)d_in[6];
  const float* w3 = (const float*)d_in[7];  const float* b3 = (const float*)d_in[8];
  const float* w4 = (const float*)d_in[9];  const float* b4 = (const float*)d_in[10];
  const float* w5 = (const float*)d_in[11]; const float* b5 = (const float*)d_in[12];
  const float* w6 = (const float*)d_in[13]; const float* b6 = (const float*)d_in[14];
  const float* w7 = (const float*)d_in[15]; const float* b7 = (const float*)d_in[16];
  const float* W8 = (const float*)d_in[17]; const float* b8 = (const float*)d_in[18];
  const float* W9 = (const float*)d_in[19]; const float* b9 = (const float*)d_in[20];
  const float* W10= (const float*)d_in[21]; const float* b10= (const float*)d_in[22];
  float* out = (float*)d_out;

  char* ws = (char*)d_ws;
  size_t off = 0;
  auto alloc = [&](size_t nfloats) -> float* {
    float* p = (float*)(ws + off);
    off += ((nfloats * 4 + 1023) / 1024) * 1024;
    return p;
  };

  // ---- fixed allocations ----
  float* x0  = alloc(1560000);
  float* m0  = alloc(1560000);
  float* m1  = alloc(8 * 166098);
  float* m2  = alloc(8 * 140184);
  float* mp1 = alloc(8 * 110000);
  float* m3  = alloc(8 * 90428);
  float* m4  = alloc(8 * 73304);
  float* mp2 = alloc(8 * 54000);
  float* m5  = alloc(8 * 41958);
  float* m6  = alloc(8 * 31824);
  float* m7  = alloc(8 * 23436);
  float* mp3 = alloc(8 * 14688);
  float* p3  = alloc(8 * 14688);
  float* wr1 = alloc(2048);
  float* wr7 = alloc(2048);
  unsigned short* tb2 = (unsigned short*)alloc(131072);   // 512 KB B-frag tables
  unsigned short* tb3 = (unsigned short*)alloc(131072);
  unsigned short* tb4 = (unsigned short*)alloc(131072);
  unsigned short* tb5 = (unsigned short*)alloc(131072);
  unsigned short* tb6 = (unsigned short*)alloc(131072);
  float* part= alloc(64000);
  float* h8  = alloc(8000);
  float* h9  = alloc(8000);
  size_t fixedOff = off;

  // ---- pick group size G from remaining workspace ----
  const size_t perItemAB = ((size_t)5315136*4 + 1023)/1024*1024
                         + ((size_t)4485888*4 + 1023)/1024*1024
                         + ((size_t)23436*4 + 1023)/1024*1024;
  int G = 0;
  for (int g : {8, 4, 2, 1})
    if (fixedOff + (size_t)g * perItemAB <= ws_size) { G = g; break; }
  if (G == 0) return;

  float* A  = alloc((size_t)G * 5315136);
  float* Bb = alloc((size_t)G * 4485888);
  float* x7 = alloc((size_t)G * 23436);
  unsigned* claim = (unsigned*)A;   // claim aliases A (dead before first conv use)

  // ---- init ----
  hipMemsetAsync(claim, 0, 1560000 * 4, stream);
  hipMemsetAsync(x0,    0, 1560000 * 4, stream);
  hipMemsetAsync(m0,    0, 1560000 * 4, stream);

  k_repack<<<G256(32*1*64),  256, 0, stream>>>(w1, wr1, 1, 32);
  k_repack<<<G256(1*32*64),  256, 0, stream>>>(w7, wr7, 32, 1);
  k_repack_mfma<<<128, 256, 0, stream>>>(w2, tb2);
  k_repack_mfma<<<128, 256, 0, stream>>>(w3, tb3);
  k_repack_mfma<<<128, 256, 0, stream>>>(w4, tb4);
  k_repack_mfma<<<128, 256, 0, stream>>>(w5, tb5);
  k_repack_mfma<<<128, 256, 0, stream>>>(w6, tb6);

  const int N = 80000;
  k_claim  <<<G256(N), 256, 0, stream>>>(coors, claim, N);
  k_scatter<<<G256(N), 256, 0, stream>>>(coors, feat, claim, x0, m0, N);

  // ---- all mask dilations, batched over 8 items ----
  k_dilate<<<G256(8*166098), 256, 0, stream>>>(m0,  m1,  50,60,65, 47,57,62, 4, 8);
  k_dilate<<<G256(8*140184), 256, 0, stream>>>(m1,  m2,  47,57,62, 44,54,59, 4, 8);
  k_dilate<<<G256(8*110000), 256, 0, stream>>>(m2,  mp1, 44,54,59, 40,50,55, 5, 8);
  k_dilate<<<G256(8*90428),  256, 0, stream>>>(mp1, m3,  40,50,55, 37,47,52, 4, 8);
  k_dilate<<<G256(8*73304),  256, 0, stream>>>(m3,  m4,  37,47,52, 34,44,49, 4, 8);
  k_dilate<<<G256(8*54000),  256, 0, stream>>>(m4,  mp2, 34,44,49, 30,40,45, 5, 8);
  k_dilate<<<G256(8*41958),  256, 0, stream>>>(mp2, m5,  30,40,45, 27,37,42, 4, 8);
  k_dilate<<<G256(8*31824),  256, 0, stream>>>(m5,  m6,  27,37,42, 24,34,39, 4, 8);
  k_dilate<<<G256(8*23436),  256, 0, stream>>>(m6,  m7,  24,34,39, 21,31,36, 4, 8);
  k_dilate<<<G256(8*14688),  256, 0, stream>>>(m7,  mp3, 21,31,36, 17,27,32, 5, 8);

  auto conv32 = [&](const float* in, const unsigned short* tbl, const float* bias,
                    const float* mo, float* o,
                    int Zi, int Yi, int Xi, int Zo, int Yo, int Xo, int nI) {
    int tz = (Zo + TZ - 1) / TZ, ty = (Yo + TY - 1) / TY, tx = (Xo + TXT - 1) / TXT;
    k_conv32m<<<nI * tz * ty * tx, 256, 0, stream>>>(
        in, tbl, bias, mo, o, Zi, Yi, Xi, Zo, Yo, Xo, tz, ty, tx);
  };

  for (int g0 = 0; g0 < 8; g0 += G) {
    const float* x0g  = x0  + (size_t)g0 * 195000;
    const float* m1g  = m1  + (size_t)g0 * 166098;
    const float* m2g  = m2  + (size_t)g0 * 140184;
    const float* mp1g = mp1 + (size_t)g0 * 110000;
    const float* m3g  = m3  + (size_t)g0 * 90428;
    const float* m4g  = m4  + (size_t)g0 * 73304;
    const float* mp2g = mp2 + (size_t)g0 * 54000;
    const float* m5g  = m5  + (size_t)g0 * 41958;
    const float* m6g  = m6  + (size_t)g0 * 31824;
    const float* m7g  = m7  + (size_t)g0 * 23436;
    const float* mp3g = mp3 + (size_t)g0 * 14688;

    // c1: 50,60,65 -> 47,57,62
    {
      int tz = (47 + TZ - 1) / TZ, ty = (57 + TY - 1) / TY, tx = (62 + TXT - 1) / TXT;
      k_conv1t<<<G * tz * ty * tx, 256, 0, stream>>>(
          x0g, wr1, b1, m1g, A, 50,60,65, 47,57,62, tz, ty, tx);
    }
    // c2 -> 44,54,59
    conv32(A, tb2, b2, m2g, Bb, 47,57,62, 44,54,59, G);
    // p1 -> 40,50,55
    k_pool_z<<<G256((long long)G*127440*8), 256, 0, stream>>>(Bb, m2g,  A,  44,54,59, 40, G);
    k_pool_y<<<G256((long long)G*118000*8), 256, 0, stream>>>(A,  Bb, 40,54,59, 50, G);
    k_pool_x<<<G256((long long)G*110000*8), 256, 0, stream>>>(Bb, mp1g, A,  40,50,59, 55, G);
    // c3 -> 37,47,52
    conv32(A, tb3, b3, m3g, Bb, 40,50,55, 37,47,52, G);
    // c4 -> 34,44,49
    conv32(Bb, tb4, b4, m4g, A, 37,47,52, 34,44,49, G);
    // p2 -> 30,40,45
    k_pool_z<<<G256((long long)G*64680*8), 256, 0, stream>>>(A,  m4g,  Bb, 34,44,49, 30, G);
    k_pool_y<<<G256((long long)G*58800*8), 256, 0, stream>>>(Bb, A,  30,44,49, 40, G);
    k_pool_x<<<G256((long long)G*54000*8), 256, 0, stream>>>(A,  mp2g, Bb, 30,40,49, 45, G);
    // c5 -> 27,37,42
    conv32(Bb, tb5, b5, m5g, A, 30,40,45, 27,37,42, G);
    // c6 -> 24,34,39
    conv32(A, tb6, b6, m6g, Bb, 27,37,42, 24,34,39, G);
    // c7 (32->1) -> 21,31,36
    {
      int tz = (21 + TZ - 1) / TZ, ty = (31 + TY - 1) / TY, tx = (36 + TXT - 1) / TXT;
      k_conv7t<<<G * tz * ty * tx, 256, 0, stream>>>(
          Bb, wr7, b7, m7g, x7, 24,34,39, 21,31,36, tz, ty, tx);
    }
    // p3 -> 17,27,32
    k_pool3<<<G256((long long)G*14688), 256, 0, stream>>>(
        x7, m7g, mp3g, p3 + (size_t)g0 * 14688, G);
  }

  // ---- FC head ----
  k_fc_part<<<dim3(63, 8), 256, 0, stream>>>(p3, W8, part, 14688, 1000, 1836);
  k_fc_fin <<<G256(8000), 256, 0, stream>>>(part, 8, b8, h8, 1000);
  k_fc_part<<<dim3(63, 4), 256, 0, stream>>>(h8, W9, part, 1000, 1000, 250);
  k_fc_fin <<<G256(8000), 256, 0, stream>>>(part, 4, b9, h9, 1000);
  k_fc<<<1, 256, 0, stream>>>(h9, W10, b10, out, 1000, 1);
}

// Round 7
// 3573.589 us; speedup vs baseline: 29.8896x; 1.0353x over previous
//
#include <hip/hip_runtime.h>
#include <cstddef>

// Sparse 3D CNN. R6: conv32m tile 4x4x8 (26 KB LDS -> 6 blocks/CU) for
// stage/compute overlap across blocks (R5 was latency-bound: all pipes <40%,
// 3 blocks/CU, 8 barriers/block). Separable mask dilation (3K vs K^3 taps).
// R5: MFMA bf16 hi/lo split convs (2-mfma K-pack, full 4-term product).
// Chain: 50,60,65 -> c1 47,57,62 -> c2 44,54,59 -> p1 40,50,55 -> c3 37,47,52
// -> c4 34,44,49 -> p2 30,40,45 -> c5 27,37,42 -> c6 24,34,39 -> c7 21,31,36
// -> p3 17,27,32 ; flatten 14688 -> FC 1000 -> 1000 -> 1

#define NEGSLOPE 0.01f
#define NINF (-3.0e38f)

// c1/c7 tile (fp32 VALU kernels)
#define TZ 4
#define TY 4
#define TXT 16
#define IZ 7
#define IY 7
#define IX 19
#define NV (IZ*IY*IX)    // 931

// conv32m tile (MFMA kernel)
#define CZ 4
#define CY 4
#define CX 8
#define HIY 7
#define HIX 11
#define HNV (7*HIY*HIX)  // 539 voxels * 48 B = 25.9 KB

typedef __attribute__((ext_vector_type(8)))  short  short8;    // 8 bf16
typedef __attribute__((ext_vector_type(16))) float  floatx16;  // 32x32 acc

__device__ __forceinline__ float lrelu(float v) { return v >= 0.f ? v : NEGSLOPE * v; }

__device__ __forceinline__ unsigned short f2bf(float f) {
  unsigned b = __float_as_uint(f);
  return (unsigned short)((b + 0x7fffu + ((b >> 16) & 1u)) >> 16);   // RNE
}
__device__ __forceinline__ float bf2f(unsigned short h) {
  return __uint_as_float(((unsigned)h) << 16);
}
__device__ __forceinline__ unsigned splitpair(float a, float b, unsigned& lo) {
  unsigned short ha = f2bf(a), hb = f2bf(b);
  unsigned short la = f2bf(a - bf2f(ha)), lb = f2bf(b - bf2f(hb));
  lo = (unsigned)la | ((unsigned)lb << 16);
  return (unsigned)ha | ((unsigned)hb << 16);
}

// ---------------- scatter (last-write-wins), full batch ----------------
__global__ void k_claim(const int* __restrict__ coors, unsigned* __restrict__ claim, int N) {
  int i = blockIdx.x * blockDim.x + threadIdx.x;
  if (i >= N) return;
  int b = coors[4*i], z = coors[4*i+1], y = coors[4*i+2], x = coors[4*i+3];
  int v = ((b*50 + z)*60 + y)*65 + x;
  atomicMax(&claim[v], (unsigned)(i + 1));
}

__global__ void k_scatter(const int* __restrict__ coors, const float* __restrict__ feat,
                          const unsigned* __restrict__ claim,
                          float* __restrict__ x0, float* __restrict__ m0, int N) {
  int i = blockIdx.x * blockDim.x + threadIdx.x;
  if (i >= N) return;
  int b = coors[4*i], z = coors[4*i+1], y = coors[4*i+2], x = coors[4*i+3];
  int v = ((b*50 + z)*60 + y)*65 + x;
  m0[v] = 1.f;
  if (claim[v] == (unsigned)(i + 1)) x0[v] = feat[i];
}

// ---------------- weight repack (c1/c7): w[co][ci][k64] -> wr[k64][ci][co] --------
__global__ void k_repack(const float* __restrict__ w, float* __restrict__ wr, int CI, int CO) {
  int i = blockIdx.x * blockDim.x + threadIdx.x;
  int tot = CO * CI * 64;
  if (i >= tot) return;
  int k = i & 63;
  int ci = (i >> 6) % CI;
  int co = i / (64 * CI);
  wr[(k * CI + ci) * CO + co] = w[i];
}

// ---------------- MFMA B-fragment table build for 32->32 layers ----------------
// tbl layout: [(tap*4 + pass)*2 + pack][lane 0..63][8 bf16]  (1 KB per frag)
// pack0: k 0..7 = wh(ci), k 8..15 = wl(ci); pack1 swapped. ci = pass*8 + (k&7).
__global__ void k_repack_mfma(const float* __restrict__ w, unsigned short* __restrict__ tbl) {
  int i = blockIdx.x * blockDim.x + threadIdx.x;   // 0..32767
  if (i >= 64*4*2*64) return;
  int lane = i & 63; int t = i >> 6;
  int pack = t & 1; t >>= 1;
  int pass = t & 3; int tap = t >> 2;
  int co = lane & 31; int oct = lane >> 5;
#pragma unroll
  for (int j = 0; j < 8; ++j) {
    int k = oct * 8 + j;
    int ci = pass * 8 + (k & 7);
    int part = ((k >> 3) ^ pack) & 1;
    float wv = w[((co * 32 + ci) << 6) + tap];
    unsigned short wh = f2bf(wv);
    unsigned short r = part ? f2bf(wv - bf2f(wh)) : wh;
    tbl[(size_t)i * 8 + j] = r;
  }
}

// ---------------- separable mask dilation ----------------
__global__ void kd_z(const float* __restrict__ in, float* __restrict__ o,
                     int Zi, int Yi, int Xi, int Zo, int K, int nI) {
  int gid = blockIdx.x * blockDim.x + threadIdx.x;
  int perOut = Zo * Yi * Xi;
  if (gid >= nI * perOut) return;
  int item = gid / perOut;
  int r = gid - item * perOut;
  int x = r % Xi; int t = r / Xi;
  int y = t % Yi; int z = t / Yi;
  const float* ib = in + (size_t)item * Zi * Yi * Xi;
  float mx = 0.f;
  for (int d = 0; d < K; d++) mx = fmaxf(mx, ib[((z + d) * Yi + y) * Xi + x]);
  o[gid] = mx;
}

__global__ void kd_y(const float* __restrict__ in, float* __restrict__ o,
                     int Zo, int Yi, int Xi, int Yo, int K, int nI) {
  int gid = blockIdx.x * blockDim.x + threadIdx.x;
  int perOut = Zo * Yo * Xi;
  if (gid >= nI * perOut) return;
  int item = gid / perOut;
  int r = gid - item * perOut;
  int x = r % Xi; int t = r / Xi;
  int y = t % Yo; int z = t / Yo;
  const float* ib = in + (size_t)item * Zo * Yi * Xi;
  float mx = 0.f;
  for (int d = 0; d < K; d++) mx = fmaxf(mx, ib[(z * Yi + y + d) * Xi + x]);
  o[gid] = mx;
}

__global__ void kd_x(const float* __restrict__ in, float* __restrict__ o,
                     int Zo, int Yo, int Xi, int Xo, int K, int nI) {
  int gid = blockIdx.x * blockDim.x + threadIdx.x;
  int perOut = Zo * Yo * Xo;
  if (gid >= nI * perOut) return;
  int item = gid / perOut;
  int r = gid - item * perOut;
  int x = r % Xo; int t = r / Xo;
  int y = t % Yo; int z = t / Yo;
  const float* ib = in + (size_t)item * Zo * Yo * Xi;
  float mx = 0.f;
  for (int d = 0; d < K; d++) mx = fmaxf(mx, ib[(z * Yo + y) * Xi + x + d]);
  o[gid] = mx;
}

// ---------------- MFMA conv 32->32 ----------------
// Block = 4x4x8 output tile (128 voxels, 4 waves x one 32-voxel group).
// Halo 7x7x11 staged in LDS (48 B/voxel: hi16|lo16|pad16, bank-spread),
// 4 passes of 8 ci. Per tap: 1 A ds_read_b128, 2 B global b128 (L2-hot
// table), 2 mfma 32x32x16 (pack0/1 => full hi/lo product).
__global__ __launch_bounds__(256, 6)
void k_conv32m(const float* __restrict__ in, const unsigned short* __restrict__ tbl,
               const float* __restrict__ bias, const float* __restrict__ mo,
               float* __restrict__ out,
               int Zi, int Yi, int Xi, int Zo, int Yo, int Xo,
               int tilesZ, int tilesY, int tilesX) {
  __shared__ unsigned sU[HNV * 12];   // 25.9 KB
  const int perIn = Zi * Yi * Xi;
  const int perOut = Zo * Yo * Xo;
  int bid = blockIdx.x;
  int txi = bid % tilesX; bid /= tilesX;
  int tyi = bid % tilesY; bid /= tilesY;
  int tzi = bid % tilesZ; int item = bid / tilesZ;
  const int z0 = tzi * CZ, y0 = tyi * CY, x0 = txi * CX;
  const int tid = threadIdx.x;
  const int lane = tid & 63;
  const int col = lane & 31;     // co (B n-index) and A-row m
  const int oct = lane >> 5;
  const int wv  = tid >> 6;      // wave 0..3 = oz slice

  // wave's voxel group: vt = wv*32 + col -> oz=wv, oy=(col>>3)&3, ox=col&7
  const int lvBase = ((wv) * HIY + ((col >> 3) & 3)) * HIX + (col & 7);

  floatx16 acc;
#pragma unroll
  for (int r = 0; r < 16; ++r) acc[r] = 0.f;

  const float* inb = in + (size_t)item * perIn * 32;
  const char* tb = (const char*)tbl + lane * 16;

#pragma unroll 1
  for (int p = 0; p < 4; ++p) {
    __syncthreads();
    for (int idx = tid; idx < HNV; idx += 256) {
      int iz = idx / (HIY * HIX); int r = idx - iz * (HIY * HIX);
      int iy = r / HIX; int ix = r - iy * HIX;
      int gz = z0 + iz, gy = y0 + iy, gx = x0 + ix;
      float4 f0 = make_float4(0.f,0.f,0.f,0.f), f1 = make_float4(0.f,0.f,0.f,0.f);
      if (gz < Zi && gy < Yi && gx < Xi) {
        const float* vp = inb + (size_t)((gz * Yi + gy) * Xi + gx) * 32 + p * 8;
        f0 = *(const float4*)vp;
        f1 = *(const float4*)(vp + 4);
      }
      unsigned l0, l1, l2, l3;
      unsigned h0 = splitpair(f0.x, f0.y, l0);
      unsigned h1 = splitpair(f0.z, f0.w, l1);
      unsigned h2 = splitpair(f1.x, f1.y, l2);
      unsigned h3 = splitpair(f1.z, f1.w, l3);
      uint4 ahv = {h0, h1, h2, h3};
      uint4 alv = {l0, l1, l2, l3};
      ((uint4*)sU)[idx * 3 + 0] = ahv;
      ((uint4*)sU)[idx * 3 + 1] = alv;
    }
    __syncthreads();

    const char* tp = tb + (size_t)p * 2048;
#pragma unroll 2
    for (int tap = 0; tap < 64; ++tap) {
      int kz = tap >> 4, ky = (tap >> 2) & 3, kx = tap & 3;
      int sOff = (kz * HIY + ky) * HIX + kx;
      short8 b0 = *(const short8*)(tp + (size_t)tap * 8192);
      short8 b1 = *(const short8*)(tp + (size_t)tap * 8192 + 1024);
      short8 a0 = *(const short8*)((const char*)sU + (size_t)(lvBase + sOff) * 48 + oct * 16);
      acc = __builtin_amdgcn_mfma_f32_32x32x16_bf16(a0, b0, acc, 0, 0, 0);
      acc = __builtin_amdgcn_mfma_f32_32x32x16_bf16(a0, b1, acc, 0, 0, 0);
    }
  }

  // epilogue: C/D layout col=lane&31 (co), row m=(reg&3)+8*(reg>>2)+4*oct
  const float bco = bias[col];
#pragma unroll
  for (int rg = 0; rg < 16; ++rg) {
    int row = (rg & 3) + 8 * (rg >> 2) + 4 * oct;
    int oz = wv, oy = (row >> 3) & 3, ox = row & 7;
    int gz = z0 + oz, gy = y0 + oy, gx = x0 + ox;
    if (gz < Zo && gy < Yo && gx < Xo) {
      int ov = item * perOut + (gz * Yo + gy) * Xo + gx;
      bool act = mo[ov] > 0.f;
      out[(size_t)ov * 32 + col] = lrelu(act ? (acc[rg] + bco) : 0.f);
    }
  }
}

// ---------------- LDS-tiled conv 1->32 (c1), weights in LDS ----------------
__global__ __launch_bounds__(256, 2)
void k_conv1t(const float* __restrict__ in, const float* __restrict__ wr,
              const float* __restrict__ bias, const float* __restrict__ mo,
              float* __restrict__ out,
              int Zi, int Yi, int Xi, int Zo, int Yo, int Xo,
              int tilesZ, int tilesY, int tilesX) {
  __shared__ float sinf[NV];
  __shared__ float4 wsh[512];   // 64 taps x 8 co-quads
  {
    const float4* wr4 = (const float4*)wr;
    for (int idx = threadIdx.x; idx < 512; idx += 256) wsh[idx] = wr4[idx];
  }
  const int perIn = Zi * Yi * Xi;
  const int perOut = Zo * Yo * Xo;
  int bid = blockIdx.x;
  int txi = bid % tilesX; bid /= tilesX;
  int tyi = bid % tilesY; bid /= tilesY;
  int tzi = bid % tilesZ; int item = bid / tilesZ;
  const int z0 = tzi * TZ, y0 = tyi * TY, x0 = txi * TXT;
  const int tid = threadIdx.x;
  const int ox = tid & 15, oy = (tid >> 4) & 3, oz = tid >> 6;

  const float* inb = in + (size_t)item * perIn;
  for (int idx = tid; idx < NV; idx += 256) {
    int iz = idx / (IY * IX); int r = idx - iz * (IY * IX);
    int iy = r / IX; int ix = r - iy * IX;
    int gz = z0 + iz, gy = y0 + iy, gx = x0 + ix;
    float val = 0.f;
    if (gz < Zi && gy < Yi && gx < Xi)
      val = inb[(size_t)((gz * Yi + gy) * Xi + gx)];
    sinf[idx] = val;
  }
  __syncthreads();

  float4 acc[8];
#pragma unroll
  for (int j = 0; j < 8; ++j) acc[j] = make_float4(0.f, 0.f, 0.f, 0.f);

#pragma unroll 1
  for (int tap = 0; tap < 64; ++tap) {
    int kz = tap >> 4, ky = (tap >> 2) & 3, kx = tap & 3;
    int lv = ((oz + kz) * IY + (oy + ky)) * IX + (ox + kx);
    float av = sinf[lv];
#pragma unroll
    for (int j = 0; j < 8; ++j) {
      float4 wvv = wsh[tap * 8 + j];
      acc[j].x = fmaf(av, wvv.x, acc[j].x);
      acc[j].y = fmaf(av, wvv.y, acc[j].y);
      acc[j].z = fmaf(av, wvv.z, acc[j].z);
      acc[j].w = fmaf(av, wvv.w, acc[j].w);
    }
  }

  int gz = z0 + oz, gy = y0 + oy, gx = x0 + ox;
  if (gz < Zo && gy < Yo && gx < Xo) {
    int ov = item * perOut + (gz * Yo + gy) * Xo + gx;
    bool act = mo[ov] > 0.f;
    const float4* b4 = (const float4*)bias;
    float* op = out + (size_t)ov * 32;
#pragma unroll
    for (int j = 0; j < 8; ++j) {
      float4 r = acc[j]; float4 bj = b4[j];
      r.x = lrelu(act ? (r.x + bj.x) : 0.f);
      r.y = lrelu(act ? (r.y + bj.y) : 0.f);
      r.z = lrelu(act ? (r.z + bj.z) : 0.f);
      r.w = lrelu(act ? (r.w + bj.w) : 0.f);
      *(float4*)(op + j * 4) = r;
    }
  }
}

// ---------------- LDS-tiled conv 32->1 (c7), weights in LDS ----------------
__global__ __launch_bounds__(256, 2)
void k_conv7t(const float* __restrict__ in, const float* __restrict__ wr,
              const float* __restrict__ bias, const float* __restrict__ mo,
              float* __restrict__ out,
              int Zi, int Yi, int Xi, int Zo, int Yo, int Xo,
              int tilesZ, int tilesY, int tilesX) {
  __shared__ float4 sin4[4][NV];
  __shared__ float4 wsh[512];   // 64 taps x 8 ci-quads
  {
    const float4* wr4 = (const float4*)wr;
    for (int idx = threadIdx.x; idx < 512; idx += 256) wsh[idx] = wr4[idx];
  }
  const int perIn = Zi * Yi * Xi;
  const int perOut = Zo * Yo * Xo;
  int bid = blockIdx.x;
  int txi = bid % tilesX; bid /= tilesX;
  int tyi = bid % tilesY; bid /= tilesY;
  int tzi = bid % tilesZ; int item = bid / tilesZ;
  const int z0 = tzi * TZ, y0 = tyi * TY, x0 = txi * TXT;
  const int tid = threadIdx.x;
  const int ox = tid & 15, oy = (tid >> 4) & 3, oz = tid >> 6;

  const float* inb = in + (size_t)item * perIn * 32;
  float acc = 0.f;

#pragma unroll 1
  for (int h = 0; h < 2; ++h) {
    __syncthreads();
    for (int idx = tid; idx < NV * 4; idx += 256) {
      int q = idx / NV; int v = idx - q * NV;
      int iz = v / (IY * IX); int r = v - iz * (IY * IX);
      int iy = r / IX; int ix = r - iy * IX;
      int gz = z0 + iz, gy = y0 + iy, gx = x0 + ix;
      float4 val = make_float4(0.f, 0.f, 0.f, 0.f);
      if (gz < Zi && gy < Yi && gx < Xi)
        val = *(const float4*)(inb + (size_t)((gz * Yi + gy) * Xi + gx) * 32 + h * 16 + q * 4);
      sin4[q][v] = val;
    }
    __syncthreads();
#pragma unroll 1
    for (int tap = 0; tap < 64; ++tap) {
      int kz = tap >> 4, ky = (tap >> 2) & 3, kx = tap & 3;
      int lv = ((oz + kz) * IY + (oy + ky)) * IX + (ox + kx);
      float4 a0 = sin4[0][lv];
      float4 a1 = sin4[1][lv];
      float4 a2 = sin4[2][lv];
      float4 a3 = sin4[3][lv];
      float4 w0 = wsh[tap * 8 + h * 4 + 0];
      float4 w1 = wsh[tap * 8 + h * 4 + 1];
      float4 w2 = wsh[tap * 8 + h * 4 + 2];
      float4 w3 = wsh[tap * 8 + h * 4 + 3];
      acc += a0.x*w0.x + a0.y*w0.y + a0.z*w0.z + a0.w*w0.w
           + a1.x*w1.x + a1.y*w1.y + a1.z*w1.z + a1.w*w1.w
           + a2.x*w2.x + a2.y*w2.y + a2.z*w2.z + a2.w*w2.w
           + a3.x*w3.x + a3.y*w3.y + a3.z*w3.z + a3.w*w3.w;
    }
  }

  int gz = z0 + oz, gy = y0 + oy, gx = x0 + ox;
  if (gz < Zo && gy < Yo && gx < Xo) {
    int ov = item * perOut + (gz * Yo + gy) * Xo + gx;
    bool act = mo[ov] > 0.f;
    out[ov] = lrelu(act ? (acc + bias[0]) : 0.f);
  }
}

// ---------------- batched separable sparse maxpool (C=32, float4/thread) -----------
__global__ void k_pool_z(const float* __restrict__ in, const float* __restrict__ m,
                         float* __restrict__ out, int Zi, int Yi, int Xi, int Zo, int nI) {
  int gid = blockIdx.x * blockDim.x + threadIdx.x;
  int perOut = Zo * Yi * Xi;
  int tot = nI * perOut * 8;
  if (gid >= tot) return;
  int c4 = gid & 7; int v = gid >> 3;
  int item = v / perOut;
  int r = v - item * perOut;
  int x = r % Xi; int t = r / Xi;
  int y = t % Yi; int z = t / Yi;
  int ib = item * Zi * Yi * Xi;
  float4 acc = {NINF, NINF, NINF, NINF};
  for (int j = 0; j < 5; j++) {
    int vi = ib + ((z + j)*Yi + y)*Xi + x;
    if (m[vi] > 0.f) {
      float4 val = *(const float4*)(in + (size_t)vi*32 + c4*4);
      acc.x = fmaxf(acc.x, val.x); acc.y = fmaxf(acc.y, val.y);
      acc.z = fmaxf(acc.z, val.z); acc.w = fmaxf(acc.w, val.w);
    }
  }
  *(float4*)(out + (size_t)v*32 + c4*4) = acc;
}

__global__ void k_pool_y(const float* __restrict__ in, float* __restrict__ out,
                         int Z, int Yi, int Xi, int Yo, int nI) {
  int gid = blockIdx.x * blockDim.x + threadIdx.x;
  int perOut = Z * Yo * Xi;
  int tot = nI * perOut * 8;
  if (gid >= tot) return;
  int c4 = gid & 7; int v = gid >> 3;
  int item = v / perOut;
  int r = v - item * perOut;
  int x = r % Xi; int t = r / Xi;
  int y = t % Yo; int z = t / Yo;
  int ib = item * Z * Yi * Xi;
  float4 acc = {NINF, NINF, NINF, NINF};
  for (int j = 0; j < 5; j++) {
    int vi = ib + (z*Yi + y + j)*Xi + x;
    float4 val = *(const float4*)(in + (size_t)vi*32 + c4*4);
    acc.x = fmaxf(acc.x, val.x); acc.y = fmaxf(acc.y, val.y);
    acc.z = fmaxf(acc.z, val.z); acc.w = fmaxf(acc.w, val.w);
  }
  *(float4*)(out + (size_t)v*32 + c4*4) = acc;
}

__global__ void k_pool_x(const float* __restrict__ in, const float* __restrict__ mp,
                         float* __restrict__ out, int Z, int Y, int Xi, int Xo, int nI) {
  int gid = blockIdx.x * blockDim.x + threadIdx.x;
  int perOut = Z * Y * Xo;
  int tot = nI * perOut * 8;
  if (gid >= tot) return;
  int c4 = gid & 7; int v = gid >> 3;
  int item = v / perOut;
  int r = v - item * perOut;
  int x = r % Xo; int t = r / Xo;
  int y = t % Y; int z = t / Y;
  int ib = item * Z * Y * Xi;
  float4 acc = {NINF, NINF, NINF, NINF};
  for (int j = 0; j < 5; j++) {
    int vi = ib + (z*Y + y)*Xi + x + j;
    float4 val = *(const float4*)(in + (size_t)vi*32 + c4*4);
    acc.x = fmaxf(acc.x, val.x); acc.y = fmaxf(acc.y, val.y);
    acc.z = fmaxf(acc.z, val.z); acc.w = fmaxf(acc.w, val.w);
  }
  bool act = mp[v] > 0.f;
  float4 rr;
  rr.x = act ? acc.x : 0.f; rr.y = act ? acc.y : 0.f;
  rr.z = act ? acc.z : 0.f; rr.w = act ? acc.w : 0.f;
  *(float4*)(out + (size_t)v*32 + c4*4) = rr;
}

// ---------------- final pool (C=1, direct 5^3), 21,31,36 -> 17,27,32, batched ------
__global__ void k_pool3(const float* __restrict__ xin, const float* __restrict__ m,
                        const float* __restrict__ mp, float* __restrict__ out, int nI) {
  int gid = blockIdx.x * blockDim.x + threadIdx.x;
  int perOut = 17 * 27 * 32;
  int tot = nI * perOut;
  if (gid >= tot) return;
  int item = gid / perOut;
  int r = gid - item * perOut;
  int x = r & 31; int t = r >> 5;
  int y = t % 27; int z = t / 27;
  const float* xb = xin + (size_t)item * 23436;
  const float* mb = m + (size_t)item * 23436;
  float acc = NINF;
  for (int dz = 0; dz < 5; dz++)
    for (int dy = 0; dy < 5; dy++) {
      const float* rowx = xb + (size_t)(((z + dz)*31 + y + dy)*36 + x);
      const float* rowm = mb + (size_t)(((z + dz)*31 + y + dy)*36 + x);
      for (int dx = 0; dx < 5; dx++)
        if (rowm[dx] > 0.f) acc = fmaxf(acc, rowx[dx]);
    }
  out[gid] = (mp[gid] > 0.f) ? acc : 0.f;
}

// ---------------- FC split-K partial + finalize ----------------
__global__ __launch_bounds__(256, 4)
void k_fc_part(const float* __restrict__ X, const float* __restrict__ Wm,
               float* __restrict__ part, int K, int Ncol, int Kc) {
  __shared__ float sm[16][16][8];
  int ks = blockIdx.y;
  int k0 = ks * Kc;
  int k1 = k0 + Kc; if (k1 > K) k1 = K;
  int cl = threadIdx.x & 15;
  int kt = threadIdx.x >> 4;
  int col = blockIdx.x * 16 + cl;
  float a0=0.f,a1=0.f,a2=0.f,a3=0.f,a4=0.f,a5=0.f,a6=0.f,a7=0.f;
  if (col < Ncol) {
    for (int k = k0 + kt; k < k1; k += 16) {
      float w = Wm[(size_t)k * Ncol + col];
      a0 += X[0 * K + k] * w; a1 += X[1 * K + k] * w;
      a2 += X[2 * K + k] * w; a3 += X[3 * K + k] * w;
      a4 += X[4 * K + k] * w; a5 += X[5 * K + k] * w;
      a6 += X[6 * K + k] * w; a7 += X[7 * K + k] * w;
    }
  }
  sm[kt][cl][0]=a0; sm[kt][cl][1]=a1; sm[kt][cl][2]=a2; sm[kt][cl][3]=a3;
  sm[kt][cl][4]=a4; sm[kt][cl][5]=a5; sm[kt][cl][6]=a6; sm[kt][cl][7]=a7;
  __syncthreads();
  if (threadIdx.x < 128) {
    int c = threadIdx.x & 15;
    int b = threadIdx.x >> 4;
    float s = 0.f;
#pragma unroll
    for (int k = 0; k < 16; k++) s += sm[k][c][b];
    int cc = blockIdx.x * 16 + c;
    if (cc < Ncol) part[((size_t)ks * 8 + b) * Ncol + cc] = s;
  }
}

__global__ void k_fc_fin(const float* __restrict__ part, int ns,
                         const float* __restrict__ bias, float* __restrict__ out, int Ncol) {
  int i = blockIdx.x * blockDim.x + threadIdx.x;
  if (i >= 8 * Ncol) return;
  int b = i / Ncol;
  int c = i - b * Ncol;
  float s = 0.f;
  for (int ks = 0; ks < ns; ks++) s += part[((size_t)ks * 8 + b) * Ncol + c];
  out[i] = lrelu(s + bias[c]);
}

// last FC (K=1000 -> 1), small
__global__ __launch_bounds__(256, 4)
void k_fc(const float* __restrict__ X, const float* __restrict__ Wm,
          const float* __restrict__ bias, float* __restrict__ out,
          int K, int Ncol) {
  __shared__ float sm[16][16][8];
  int cl = threadIdx.x & 15;
  int kt = threadIdx.x >> 4;
  int col = blockIdx.x * 16 + cl;
  float a0=0.f,a1=0.f,a2=0.f,a3=0.f,a4=0.f,a5=0.f,a6=0.f,a7=0.f;
  if (col < Ncol) {
    for (int k = kt; k < K; k += 16) {
      float w = Wm[(size_t)k * Ncol + col];
      a0 += X[0 * K + k] * w; a1 += X[1 * K + k] * w;
      a2 += X[2 * K + k] * w; a3 += X[3 * K + k] * w;
      a4 += X[4 * K + k] * w; a5 += X[5 * K + k] * w;
      a6 += X[6 * K + k] * w; a7 += X[7 * K + k] * w;
    }
  }
  sm[kt][cl][0]=a0; sm[kt][cl][1]=a1; sm[kt][cl][2]=a2; sm[kt][cl][3]=a3;
  sm[kt][cl][4]=a4; sm[kt][cl][5]=a5; sm[kt][cl][6]=a6; sm[kt][cl][7]=a7;
  __syncthreads();
  if (threadIdx.x < 128) {
    int c = threadIdx.x & 15;
    int b = threadIdx.x >> 4;
    float s = 0.f;
#pragma unroll
    for (int k = 0; k < 16; k++) s += sm[k][c][b];
    int cc = blockIdx.x * 16 + c;
    if (cc < Ncol) out[b * Ncol + cc] = lrelu(s + bias[cc]);
  }
}

// ---------------- host ----------------
static inline int G256(long long n) { return (int)((n + 255) / 256); }

extern "C" void kernel_launch(void* const* d_in, const int* in_sizes, int n_in,
                              void* d_out, int out_size, void* d_ws, size_t ws_size,
                              hipStream_t stream) {
  const float* feat  = (const float*)d_in[0];
  const int*   coors = (const int*)d_in[1];
  const float* w1 = (const float*)d_in[3];  const float* b1 = (const float*)d_in[4];
  const float* w2 = (const float*)d_in[5];  const float* b2 = (const float*)d_in[6];
  const float* w3 = (const float*)d_in[7];  const float* b3 = (const float*)d_in[8];
  const float* w4 = (const float*)d_in[9];  const float* b4 = (const float*)d_in[10];
  const float* w5 = (const float*)d_in[11]; const float* b5 = (const float*)d_in[12];
  const float* w6 = (const float*)d_in[13]; const float* b6 = (const float*)d_in[14];
  const float* w7 = (const float*)d_in[15]; const float* b7 = (const float*)d_in[16];
  const float* W8 = (const float*)d_in[17]; const float* b8 = (const float*)d_in[18];
  const float* W9 = (const float*)d_in[19]; const float* b9 = (const float*)d_in[20];
  const float* W10= (const float*)d_in[21]; const float* b10= (const float*)d_in[22];
  float* out = (float*)d_out;

  char* ws = (char*)d_ws;
  size_t off = 0;
  auto alloc = [&](size_t nfloats) -> float* {
    float* p = (float*)(ws + off);
    off += ((nfloats * 4 + 1023) / 1024) * 1024;
    return p;
  };

  // ---- fixed allocations ----
  float* x0  = alloc(1560000);
  float* m0  = alloc(1560000);
  float* m1  = alloc(8 * 166098);
  float* m2  = alloc(8 * 140184);
  float* mp1 = alloc(8 * 110000);
  float* m3  = alloc(8 * 90428);
  float* m4  = alloc(8 * 73304);
  float* mp2 = alloc(8 * 54000);
  float* m5  = alloc(8 * 41958);
  float* m6  = alloc(8 * 31824);
  float* m7  = alloc(8 * 23436);
  float* mp3 = alloc(8 * 14688);
  float* p3  = alloc(8 * 14688);
  float* dt1 = alloc(8 * 183300);   // separable-dilate temps
  float* dt2 = alloc(8 * 174135);
  float* wr1 = alloc(2048);
  float* wr7 = alloc(2048);
  unsigned short* tb2 = (unsigned short*)alloc(131072);   // 512 KB B-frag tables
  unsigned short* tb3 = (unsigned short*)alloc(131072);
  unsigned short* tb4 = (unsigned short*)alloc(131072);
  unsigned short* tb5 = (unsigned short*)alloc(131072);
  unsigned short* tb6 = (unsigned short*)alloc(131072);
  float* part= alloc(64000);
  float* h8  = alloc(8000);
  float* h9  = alloc(8000);
  size_t fixedOff = off;

  // ---- pick group size G from remaining workspace ----
  const size_t perItemAB = ((size_t)5315136*4 + 1023)/1024*1024
                         + ((size_t)4485888*4 + 1023)/1024*1024
                         + ((size_t)23436*4 + 1023)/1024*1024;
  int G = 0;
  for (int g : {8, 4, 2, 1})
    if (fixedOff + (size_t)g * perItemAB <= ws_size) { G = g; break; }
  if (G == 0) return;

  float* A  = alloc((size_t)G * 5315136);
  float* Bb = alloc((size_t)G * 4485888);
  float* x7 = alloc((size_t)G * 23436);
  unsigned* claim = (unsigned*)A;   // claim aliases A (dead before first conv use)

  // ---- init ----
  hipMemsetAsync(claim, 0, 1560000 * 4, stream);
  hipMemsetAsync(x0,    0, 1560000 * 4, stream);
  hipMemsetAsync(m0,    0, 1560000 * 4, stream);

  k_repack<<<G256(32*1*64),  256, 0, stream>>>(w1, wr1, 1, 32);
  k_repack<<<G256(1*32*64),  256, 0, stream>>>(w7, wr7, 32, 1);
  k_repack_mfma<<<128, 256, 0, stream>>>(w2, tb2);
  k_repack_mfma<<<128, 256, 0, stream>>>(w3, tb3);
  k_repack_mfma<<<128, 256, 0, stream>>>(w4, tb4);
  k_repack_mfma<<<128, 256, 0, stream>>>(w5, tb5);
  k_repack_mfma<<<128, 256, 0, stream>>>(w6, tb6);

  const int N = 80000;
  k_claim  <<<G256(N), 256, 0, stream>>>(coors, claim, N);
  k_scatter<<<G256(N), 256, 0, stream>>>(coors, feat, claim, x0, m0, N);

  // ---- separable mask dilations, batched over 8 items ----
  auto dil3 = [&](const float* src, float* dst,
                  int Zi, int Yi, int Xi, int Zo, int Yo, int Xo, int K) {
    kd_z<<<G256((long long)8*Zo*Yi*Xi), 256, 0, stream>>>(src, dt1, Zi,Yi,Xi, Zo, K, 8);
    kd_y<<<G256((long long)8*Zo*Yo*Xi), 256, 0, stream>>>(dt1, dt2, Zo,Yi,Xi, Yo, K, 8);
    kd_x<<<G256((long long)8*Zo*Yo*Xo), 256, 0, stream>>>(dt2, dst, Zo,Yo,Xi, Xo, K, 8);
  };
  dil3(m0,  m1,  50,60,65, 47,57,62, 4);
  dil3(m1,  m2,  47,57,62, 44,54,59, 4);
  dil3(m2,  mp1, 44,54,59, 40,50,55, 5);
  dil3(mp1, m3,  40,50,55, 37,47,52, 4);
  dil3(m3,  m4,  37,47,52, 34,44,49, 4);
  dil3(m4,  mp2, 34,44,49, 30,40,45, 5);
  dil3(mp2, m5,  30,40,45, 27,37,42, 4);
  dil3(m5,  m6,  27,37,42, 24,34,39, 4);
  dil3(m6,  m7,  24,34,39, 21,31,36, 4);
  dil3(m7,  mp3, 21,31,36, 17,27,32, 5);

  auto conv32 = [&](const float* in, const unsigned short* tbl, const float* bias,
                    const float* mo, float* o,
                    int Zi, int Yi, int Xi, int Zo, int Yo, int Xo, int nI) {
    int tz = (Zo + CZ - 1) / CZ, ty = (Yo + CY - 1) / CY, tx = (Xo + CX - 1) / CX;
    k_conv32m<<<nI * tz * ty * tx, 256, 0, stream>>>(
        in, tbl, bias, mo, o, Zi, Yi, Xi, Zo, Yo, Xo, tz, ty, tx);
  };

  for (int g0 = 0; g0 < 8; g0 += G) {
    const float* x0g  = x0  + (size_t)g0 * 195000;
    const float* m1g  = m1  + (size_t)g0 * 166098;
    const float* m2g  = m2  + (size_t)g0 * 140184;
    const float* mp1g = mp1 + (size_t)g0 * 110000;
    const float* m3g  = m3  + (size_t)g0 * 90428;
    const float* m4g  = m4  + (size_t)g0 * 73304;
    const float* mp2g = mp2 + (size_t)g0 * 54000;
    const float* m5g  = m5  + (size_t)g0 * 41958;
    const float* m6g  = m6  + (size_t)g0 * 31824;
    const float* m7g  = m7  + (size_t)g0 * 23436;
    const float* mp3g = mp3 + (size_t)g0 * 14688;

    // c1: 50,60,65 -> 47,57,62
    {
      int tz = (47 + TZ - 1) / TZ, ty = (57 + TY - 1) / TY, tx = (62 + TXT - 1) / TXT;
      k_conv1t<<<G * tz * ty * tx, 256, 0, stream>>>(
          x0g, wr1, b1, m1g, A, 50,60,65, 47,57,62, tz, ty, tx);
    }
    // c2 -> 44,54,59
    conv32(A, tb2, b2, m2g, Bb, 47,57,62, 44,54,59, G);
    // p1 -> 40,50,55
    k_pool_z<<<G256((long long)G*127440*8), 256, 0, stream>>>(Bb, m2g,  A,  44,54,59, 40, G);
    k_pool_y<<<G256((long long)G*118000*8), 256, 0, stream>>>(A,  Bb, 40,54,59, 50, G);
    k_pool_x<<<G256((long long)G*110000*8), 256, 0, stream>>>(Bb, mp1g, A,  40,50,59, 55, G);
    // c3 -> 37,47,52
    conv32(A, tb3, b3, m3g, Bb, 40,50,55, 37,47,52, G);
    // c4 -> 34,44,49
    conv32(Bb, tb4, b4, m4g, A, 37,47,52, 34,44,49, G);
    // p2 -> 30,40,45
    k_pool_z<<<G256((long long)G*64680*8), 256, 0, stream>>>(A,  m4g,  Bb, 34,44,49, 30, G);
    k_pool_y<<<G256((long long)G*58800*8), 256, 0, stream>>>(Bb, A,  30,44,49, 40, G);
    k_pool_x<<<G256((long long)G*54000*8), 256, 0, stream>>>(A,  mp2g, Bb, 30,40,49, 45, G);
    // c5 -> 27,37,42
    conv32(Bb, tb5, b5, m5g, A, 30,40,45, 27,37,42, G);
    // c6 -> 24,34,39
    conv32(A, tb6, b6, m6g, Bb, 27,37,42, 24,34,39, G);
    // c7 (32->1) -> 21,31,36
    {
      int tz = (21 + TZ - 1) / TZ, ty = (31 + TY - 1) / TY, tx = (36 + TXT - 1) / TXT;
      k_conv7t<<<G * tz * ty * tx, 256, 0, stream>>>(
          Bb, wr7, b7, m7g, x7, 24,34,39, 21,31,36, tz, ty, tx);
    }
    // p3 -> 17,27,32
    k_pool3<<<G256((long long)G*14688), 256, 0, stream>>>(
        x7, m7g, mp3g, p3 + (size_t)g0 * 14688, G);
  }

  // ---- FC head ----
  k_fc_part<<<dim3(63, 8), 256, 0, stream>>>(p3, W8, part, 14688, 1000, 1836);
  k_fc_fin <<<G256(8000), 256, 0, stream>>>(part, 8, b8, h8, 1000);
  k_fc_part<<<dim3(63, 4), 256, 0, stream>>>(h8, W9, part, 1000, 1000, 250);
  k_fc_fin <<<G256(8000), 256, 0, stream>>>(part, 4, b9, h9, 1000);
  k_fc<<<1, 256, 0, stream>>>(h9, W10, b10, out, 1000, 1);
}

// Round 8
// 3321.290 us; speedup vs baseline: 32.1601x; 1.0760x over previous
//
#include <hip/hip_runtime.h>
#include <cstddef>

// Sparse 3D CNN. R7: conv32m back to Mg=2 (2 voxel-groups/wave, halves
// per-wave B-fragment L2 traffic — R6's 447us c2 == 8.97GB B-reads / 19.6TB/s)
// and LDS voxel stride 48->40B with ds_read_b64 A-frags (48B/12w stride put
// 64 lanes on 8 banks = 8-way conflicts, 4e7 SQ_LDS_BANK_CONFLICT).
// 37.2 KB LDS -> 4 blocks/CU.
// R5/R6: MFMA bf16 hi/lo split convs (2-mfma K-pack, full 4-term product).
// Chain: 50,60,65 -> c1 47,57,62 -> c2 44,54,59 -> p1 40,50,55 -> c3 37,47,52
// -> c4 34,44,49 -> p2 30,40,45 -> c5 27,37,42 -> c6 24,34,39 -> c7 21,31,36
// -> p3 17,27,32 ; flatten 14688 -> FC 1000 -> 1000 -> 1

#define NEGSLOPE 0.01f
#define NINF (-3.0e38f)

// shared tile geometry (c1/c7 fp32 kernels AND conv32m): 4x4x16 out, 7x7x19 halo
#define TZ 4
#define TY 4
#define TXT 16
#define IZ 7
#define IY 7
#define IX 19
#define NV (IZ*IY*IX)    // 931 voxels; conv32m: 931*40B = 37.2 KB

typedef __attribute__((ext_vector_type(8)))  short    short8;    // 8 bf16
typedef __attribute__((ext_vector_type(4)))  unsigned uint4v;
typedef __attribute__((ext_vector_type(16))) float    floatx16;  // 32x32 acc

__device__ __forceinline__ float lrelu(float v) { return v >= 0.f ? v : NEGSLOPE * v; }

__device__ __forceinline__ unsigned short f2bf(float f) {
  unsigned b = __float_as_uint(f);
  return (unsigned short)((b + 0x7fffu + ((b >> 16) & 1u)) >> 16);   // RNE
}
__device__ __forceinline__ float bf2f(unsigned short h) {
  return __uint_as_float(((unsigned)h) << 16);
}
__device__ __forceinline__ unsigned splitpair(float a, float b, unsigned& lo) {
  unsigned short ha = f2bf(a), hb = f2bf(b);
  unsigned short la = f2bf(a - bf2f(ha)), lb = f2bf(b - bf2f(hb));
  lo = (unsigned)la | ((unsigned)lb << 16);
  return (unsigned)ha | ((unsigned)hb << 16);
}

// load A-frag (8 bf16) from LDS at 40B voxel stride; oct 0 = hi, oct 1 = lo
__device__ __forceinline__ short8 ld_frag(const uint2* s2, int v, int oct) {
  uint2 u0 = s2[v * 5 + oct * 2];
  uint2 u1 = s2[v * 5 + oct * 2 + 1];
  uint4v t; t.x = u0.x; t.y = u0.y; t.z = u1.x; t.w = u1.y;
  return __builtin_bit_cast(short8, t);
}

// ---------------- scatter (last-write-wins), full batch ----------------
__global__ void k_claim(const int* __restrict__ coors, unsigned* __restrict__ claim, int N) {
  int i = blockIdx.x * blockDim.x + threadIdx.x;
  if (i >= N) return;
  int b = coors[4*i], z = coors[4*i+1], y = coors[4*i+2], x = coors[4*i+3];
  int v = ((b*50 + z)*60 + y)*65 + x;
  atomicMax(&claim[v], (unsigned)(i + 1));
}

__global__ void k_scatter(const int* __restrict__ coors, const float* __restrict__ feat,
                          const unsigned* __restrict__ claim,
                          float* __restrict__ x0, float* __restrict__ m0, int N) {
  int i = blockIdx.x * blockDim.x + threadIdx.x;
  if (i >= N) return;
  int b = coors[4*i], z = coors[4*i+1], y = coors[4*i+2], x = coors[4*i+3];
  int v = ((b*50 + z)*60 + y)*65 + x;
  m0[v] = 1.f;
  if (claim[v] == (unsigned)(i + 1)) x0[v] = feat[i];
}

// ---------------- weight repack (c1/c7): w[co][ci][k64] -> wr[k64][ci][co] --------
__global__ void k_repack(const float* __restrict__ w, float* __restrict__ wr, int CI, int CO) {
  int i = blockIdx.x * blockDim.x + threadIdx.x;
  int tot = CO * CI * 64;
  if (i >= tot) return;
  int k = i & 63;
  int ci = (i >> 6) % CI;
  int co = i / (64 * CI);
  wr[(k * CI + ci) * CO + co] = w[i];
}

// ---------------- MFMA B-fragment table build for 32->32 layers ----------------
// tbl layout: [(tap*4 + pass)*2 + pack][lane 0..63][8 bf16]  (1 KB per frag)
// pack0: k 0..7 = wh(ci), k 8..15 = wl(ci); pack1 swapped. ci = pass*8 + (k&7).
__global__ void k_repack_mfma(const float* __restrict__ w, unsigned short* __restrict__ tbl) {
  int i = blockIdx.x * blockDim.x + threadIdx.x;   // 0..32767
  if (i >= 64*4*2*64) return;
  int lane = i & 63; int t = i >> 6;
  int pack = t & 1; t >>= 1;
  int pass = t & 3; int tap = t >> 2;
  int co = lane & 31; int oct = lane >> 5;
#pragma unroll
  for (int j = 0; j < 8; ++j) {
    int k = oct * 8 + j;
    int ci = pass * 8 + (k & 7);
    int part = ((k >> 3) ^ pack) & 1;
    float wv = w[((co * 32 + ci) << 6) + tap];
    unsigned short wh = f2bf(wv);
    unsigned short r = part ? f2bf(wv - bf2f(wh)) : wh;
    tbl[(size_t)i * 8 + j] = r;
  }
}

// ---------------- separable mask dilation ----------------
__global__ void kd_z(const float* __restrict__ in, float* __restrict__ o,
                     int Zi, int Yi, int Xi, int Zo, int K, int nI) {
  int gid = blockIdx.x * blockDim.x + threadIdx.x;
  int perOut = Zo * Yi * Xi;
  if (gid >= nI * perOut) return;
  int item = gid / perOut;
  int r = gid - item * perOut;
  int x = r % Xi; int t = r / Xi;
  int y = t % Yi; int z = t / Yi;
  const float* ib = in + (size_t)item * Zi * Yi * Xi;
  float mx = 0.f;
  for (int d = 0; d < K; d++) mx = fmaxf(mx, ib[((z + d) * Yi + y) * Xi + x]);
  o[gid] = mx;
}

__global__ void kd_y(const float* __restrict__ in, float* __restrict__ o,
                     int Zo, int Yi, int Xi, int Yo, int K, int nI) {
  int gid = blockIdx.x * blockDim.x + threadIdx.x;
  int perOut = Zo * Yo * Xi;
  if (gid >= nI * perOut) return;
  int item = gid / perOut;
  int r = gid - item * perOut;
  int x = r % Xi; int t = r / Xi;
  int y = t % Yo; int z = t / Yo;
  const float* ib = in + (size_t)item * Zo * Yi * Xi;
  float mx = 0.f;
  for (int d = 0; d < K; d++) mx = fmaxf(mx, ib[(z * Yi + y + d) * Xi + x]);
  o[gid] = mx;
}

__global__ void kd_x(const float* __restrict__ in, float* __restrict__ o,
                     int Zo, int Yo, int Xi, int Xo, int K, int nI) {
  int gid = blockIdx.x * blockDim.x + threadIdx.x;
  int perOut = Zo * Yo * Xo;
  if (gid >= nI * perOut) return;
  int item = gid / perOut;
  int r = gid - item * perOut;
  int x = r % Xo; int t = r / Xo;
  int y = t % Yo; int z = t / Yo;
  const float* ib = in + (size_t)item * Zo * Yo * Xi;
  float mx = 0.f;
  for (int d = 0; d < K; d++) mx = fmaxf(mx, ib[(z * Yo + y) * Xi + x + d]);
  o[gid] = mx;
}

// ---------------- MFMA conv 32->32 ----------------
// Block = 4x4x16 output tile (256 voxels, 4 waves x 2 groups of 32).
// Halo 7x7x19 staged in LDS at 40 B/voxel ([hi 16][lo 16][pad 8]), 4 passes
// of 8 ci. Per tap per wave: 2 A-frags (2x ds_read_b64 each), 2 B-frags
// (global, L2-hot 512 KB table), 4 mfma 32x32x16.
__global__ __launch_bounds__(256, 4)
void k_conv32m(const float* __restrict__ in, const unsigned short* __restrict__ tbl,
               const float* __restrict__ bias, const float* __restrict__ mo,
               float* __restrict__ out,
               int Zi, int Yi, int Xi, int Zo, int Yo, int Xo,
               int tilesZ, int tilesY, int tilesX) {
  __shared__ unsigned sU[NV * 10];   // 37.2 KB
  const int perIn = Zi * Yi * Xi;
  const int perOut = Zo * Yo * Xo;
  int bid = blockIdx.x;
  int txi = bid % tilesX; bid /= tilesX;
  int tyi = bid % tilesY; bid /= tilesY;
  int tzi = bid % tilesZ; int item = bid / tilesZ;
  const int z0 = tzi * TZ, y0 = tyi * TY, x0 = txi * TXT;
  const int tid = threadIdx.x;
  const int lane = tid & 63;
  const int col = lane & 31;     // co (B n-index) and A-row m
  const int oct = lane >> 5;
  const int wv  = tid >> 6;      // wave 0..3

  int lvBase0, lvBase1;
  {
    int vt0 = (2*wv + 0)*32 + col;
    int vt1 = (2*wv + 1)*32 + col;
    lvBase0 = ((vt0 >> 6)*IY + ((vt0 >> 4) & 3))*IX + (vt0 & 15);
    lvBase1 = ((vt1 >> 6)*IY + ((vt1 >> 4) & 3))*IX + (vt1 & 15);
  }

  floatx16 acc0, acc1;
#pragma unroll
  for (int r = 0; r < 16; ++r) { acc0[r] = 0.f; acc1[r] = 0.f; }

  const float* inb = in + (size_t)item * perIn * 32;
  const char* tb = (const char*)tbl + lane * 16;
  uint2* s2 = (uint2*)sU;

#pragma unroll 1
  for (int p = 0; p < 4; ++p) {
    __syncthreads();
    for (int idx = tid; idx < NV; idx += 256) {
      int iz = idx / (IY * IX); int r = idx - iz * (IY * IX);
      int iy = r / IX; int ix = r - iy * IX;
      int gz = z0 + iz, gy = y0 + iy, gx = x0 + ix;
      float4 f0 = make_float4(0.f,0.f,0.f,0.f), f1 = make_float4(0.f,0.f,0.f,0.f);
      if (gz < Zi && gy < Yi && gx < Xi) {
        const float* vp = inb + (size_t)((gz * Yi + gy) * Xi + gx) * 32 + p * 8;
        f0 = *(const float4*)vp;
        f1 = *(const float4*)(vp + 4);
      }
      unsigned l0, l1, l2, l3;
      unsigned h0 = splitpair(f0.x, f0.y, l0);
      unsigned h1 = splitpair(f0.z, f0.w, l1);
      unsigned h2 = splitpair(f1.x, f1.y, l2);
      unsigned h3 = splitpair(f1.z, f1.w, l3);
      s2[idx * 5 + 0] = make_uint2(h0, h1);
      s2[idx * 5 + 1] = make_uint2(h2, h3);
      s2[idx * 5 + 2] = make_uint2(l0, l1);
      s2[idx * 5 + 3] = make_uint2(l2, l3);
    }
    __syncthreads();

    const char* tp = tb + (size_t)p * 2048;
#pragma unroll 2
    for (int tap = 0; tap < 64; ++tap) {
      int kz = tap >> 4, ky = (tap >> 2) & 3, kx = tap & 3;
      int sOff = (kz * IY + ky) * IX + kx;
      short8 b0 = *(const short8*)(tp + (size_t)tap * 8192);
      short8 b1 = *(const short8*)(tp + (size_t)tap * 8192 + 1024);
      short8 a0 = ld_frag(s2, lvBase0 + sOff, oct);
      short8 a1 = ld_frag(s2, lvBase1 + sOff, oct);
      acc0 = __builtin_amdgcn_mfma_f32_32x32x16_bf16(a0, b0, acc0, 0, 0, 0);
      acc0 = __builtin_amdgcn_mfma_f32_32x32x16_bf16(a0, b1, acc0, 0, 0, 0);
      acc1 = __builtin_amdgcn_mfma_f32_32x32x16_bf16(a1, b0, acc1, 0, 0, 0);
      acc1 = __builtin_amdgcn_mfma_f32_32x32x16_bf16(a1, b1, acc1, 0, 0, 0);
    }
  }

  // epilogue: C/D layout col=lane&31 (co), row m=(reg&3)+8*(reg>>2)+4*oct
  const float bco = bias[col];
#pragma unroll
  for (int gg = 0; gg < 2; ++gg) {
    int vtb = (2*wv + gg) * 32;
#pragma unroll
    for (int rg = 0; rg < 16; ++rg) {
      int row = (rg & 3) + 8 * (rg >> 2) + 4 * oct;
      int vt = vtb + row;
      int oz = vt >> 6, oy = (vt >> 4) & 3, ox = vt & 15;
      int gz = z0 + oz, gy = y0 + oy, gx = x0 + ox;
      if (gz < Zo && gy < Yo && gx < Xo) {
        int ov = item * perOut + (gz * Yo + gy) * Xo + gx;
        float val = (gg == 0) ? acc0[rg] : acc1[rg];
        bool act = mo[ov] > 0.f;
        out[(size_t)ov * 32 + col] = lrelu(act ? (val + bco) : 0.f);
      }
    }
  }
}

// ---------------- LDS-tiled conv 1->32 (c1), weights in LDS ----------------
__global__ __launch_bounds__(256, 2)
void k_conv1t(const float* __restrict__ in, const float* __restrict__ wr,
              const float* __restrict__ bias, const float* __restrict__ mo,
              float* __restrict__ out,
              int Zi, int Yi, int Xi, int Zo, int Yo, int Xo,
              int tilesZ, int tilesY, int tilesX) {
  __shared__ float sinf[NV];
  __shared__ float4 wsh[512];   // 64 taps x 8 co-quads
  {
    const float4* wr4 = (const float4*)wr;
    for (int idx = threadIdx.x; idx < 512; idx += 256) wsh[idx] = wr4[idx];
  }
  const int perIn = Zi * Yi * Xi;
  const int perOut = Zo * Yo * Xo;
  int bid = blockIdx.x;
  int txi = bid % tilesX; bid /= tilesX;
  int tyi = bid % tilesY; bid /= tilesY;
  int tzi = bid % tilesZ; int item = bid / tilesZ;
  const int z0 = tzi * TZ, y0 = tyi * TY, x0 = txi * TXT;
  const int tid = threadIdx.x;
  const int ox = tid & 15, oy = (tid >> 4) & 3, oz = tid >> 6;

  const float* inb = in + (size_t)item * perIn;
  for (int idx = tid; idx < NV; idx += 256) {
    int iz = idx / (IY * IX); int r = idx - iz * (IY * IX);
    int iy = r / IX; int ix = r - iy * IX;
    int gz = z0 + iz, gy = y0 + iy, gx = x0 + ix;
    float val = 0.f;
    if (gz < Zi && gy < Yi && gx < Xi)
      val = inb[(size_t)((gz * Yi + gy) * Xi + gx)];
    sinf[idx] = val;
  }
  __syncthreads();

  float4 acc[8];
#pragma unroll
  for (int j = 0; j < 8; ++j) acc[j] = make_float4(0.f, 0.f, 0.f, 0.f);

#pragma unroll 1
  for (int tap = 0; tap < 64; ++tap) {
    int kz = tap >> 4, ky = (tap >> 2) & 3, kx = tap & 3;
    int lv = ((oz + kz) * IY + (oy + ky)) * IX + (ox + kx);
    float av = sinf[lv];
#pragma unroll
    for (int j = 0; j < 8; ++j) {
      float4 wvv = wsh[tap * 8 + j];
      acc[j].x = fmaf(av, wvv.x, acc[j].x);
      acc[j].y = fmaf(av, wvv.y, acc[j].y);
      acc[j].z = fmaf(av, wvv.z, acc[j].z);
      acc[j].w = fmaf(av, wvv.w, acc[j].w);
    }
  }

  int gz = z0 + oz, gy = y0 + oy, gx = x0 + ox;
  if (gz < Zo && gy < Yo && gx < Xo) {
    int ov = item * perOut + (gz * Yo + gy) * Xo + gx;
    bool act = mo[ov] > 0.f;
    const float4* b4 = (const float4*)bias;
    float* op = out + (size_t)ov * 32;
#pragma unroll
    for (int j = 0; j < 8; ++j) {
      float4 r = acc[j]; float4 bj = b4[j];
      r.x = lrelu(act ? (r.x + bj.x) : 0.f);
      r.y = lrelu(act ? (r.y + bj.y) : 0.f);
      r.z = lrelu(act ? (r.z + bj.z) : 0.f);
      r.w = lrelu(act ? (r.w + bj.w) : 0.f);
      *(float4*)(op + j * 4) = r;
    }
  }
}

// ---------------- LDS-tiled conv 32->1 (c7), weights in LDS ----------------
__global__ __launch_bounds__(256, 2)
void k_conv7t(const float* __restrict__ in, const float* __restrict__ wr,
              const float* __restrict__ bias, const float* __restrict__ mo,
              float* __restrict__ out,
              int Zi, int Yi, int Xi, int Zo, int Yo, int Xo,
              int tilesZ, int tilesY, int tilesX) {
  __shared__ float4 sin4[4][NV];
  __shared__ float4 wsh[512];   // 64 taps x 8 ci-quads
  {
    const float4* wr4 = (const float4*)wr;
    for (int idx = threadIdx.x; idx < 512; idx += 256) wsh[idx] = wr4[idx];
  }
  const int perIn = Zi * Yi * Xi;
  const int perOut = Zo * Yo * Xo;
  int bid = blockIdx.x;
  int txi = bid % tilesX; bid /= tilesX;
  int tyi = bid % tilesY; bid /= tilesY;
  int tzi = bid % tilesZ; int item = bid / tilesZ;
  const int z0 = tzi * TZ, y0 = tyi * TY, x0 = txi * TXT;
  const int tid = threadIdx.x;
  const int ox = tid & 15, oy = (tid >> 4) & 3, oz = tid >> 6;

  const float* inb = in + (size_t)item * perIn * 32;
  float acc = 0.f;

#pragma unroll 1
  for (int h = 0; h < 2; ++h) {
    __syncthreads();
    for (int idx = tid; idx < NV * 4; idx += 256) {
      int q = idx / NV; int v = idx - q * NV;
      int iz = v / (IY * IX); int r = v - iz * (IY * IX);
      int iy = r / IX; int ix = r - iy * IX;
      int gz = z0 + iz, gy = y0 + iy, gx = x0 + ix;
      float4 val = make_float4(0.f, 0.f, 0.f, 0.f);
      if (gz < Zi && gy < Yi && gx < Xi)
        val = *(const float4*)(inb + (size_t)((gz * Yi + gy) * Xi + gx) * 32 + h * 16 + q * 4);
      sin4[q][v] = val;
    }
    __syncthreads();
#pragma unroll 1
    for (int tap = 0; tap < 64; ++tap) {
      int kz = tap >> 4, ky = (tap >> 2) & 3, kx = tap & 3;
      int lv = ((oz + kz) * IY + (oy + ky)) * IX + (ox + kx);
      float4 a0 = sin4[0][lv];
      float4 a1 = sin4[1][lv];
      float4 a2 = sin4[2][lv];
      float4 a3 = sin4[3][lv];
      float4 w0 = wsh[tap * 8 + h * 4 + 0];
      float4 w1 = wsh[tap * 8 + h * 4 + 1];
      float4 w2 = wsh[tap * 8 + h * 4 + 2];
      float4 w3 = wsh[tap * 8 + h * 4 + 3];
      acc += a0.x*w0.x + a0.y*w0.y + a0.z*w0.z + a0.w*w0.w
           + a1.x*w1.x + a1.y*w1.y + a1.z*w1.z + a1.w*w1.w
           + a2.x*w2.x + a2.y*w2.y + a2.z*w2.z + a2.w*w2.w
           + a3.x*w3.x + a3.y*w3.y + a3.z*w3.z + a3.w*w3.w;
    }
  }

  int gz = z0 + oz, gy = y0 + oy, gx = x0 + ox;
  if (gz < Zo && gy < Yo && gx < Xo) {
    int ov = item * perOut + (gz * Yo + gy) * Xo + gx;
    bool act = mo[ov] > 0.f;
    out[ov] = lrelu(act ? (acc + bias[0]) : 0.f);
  }
}

// ---------------- batched separable sparse maxpool (C=32, float4/thread) -----------
__global__ void k_pool_z(const float* __restrict__ in, const float* __restrict__ m,
                         float* __restrict__ out, int Zi, int Yi, int Xi, int Zo, int nI) {
  int gid = blockIdx.x * blockDim.x + threadIdx.x;
  int perOut = Zo * Yi * Xi;
  int tot = nI * perOut * 8;
  if (gid >= tot) return;
  int c4 = gid & 7; int v = gid >> 3;
  int item = v / perOut;
  int r = v - item * perOut;
  int x = r % Xi; int t = r / Xi;
  int y = t % Yi; int z = t / Yi;
  int ib = item * Zi * Yi * Xi;
  float4 acc = {NINF, NINF, NINF, NINF};
  for (int j = 0; j < 5; j++) {
    int vi = ib + ((z + j)*Yi + y)*Xi + x;
    if (m[vi] > 0.f) {
      float4 val = *(const float4*)(in + (size_t)vi*32 + c4*4);
      acc.x = fmaxf(acc.x, val.x); acc.y = fmaxf(acc.y, val.y);
      acc.z = fmaxf(acc.z, val.z); acc.w = fmaxf(acc.w, val.w);
    }
  }
  *(float4*)(out + (size_t)v*32 + c4*4) = acc;
}

__global__ void k_pool_y(const float* __restrict__ in, float* __restrict__ out,
                         int Z, int Yi, int Xi, int Yo, int nI) {
  int gid = blockIdx.x * blockDim.x + threadIdx.x;
  int perOut = Z * Yo * Xi;
  int tot = nI * perOut * 8;
  if (gid >= tot) return;
  int c4 = gid & 7; int v = gid >> 3;
  int item = v / perOut;
  int r = v - item * perOut;
  int x = r % Xi; int t = r / Xi;
  int y = t % Yo; int z = t / Yo;
  int ib = item * Z * Yi * Xi;
  float4 acc = {NINF, NINF, NINF, NINF};
  for (int j = 0; j < 5; j++) {
    int vi = ib + (z*Yi + y + j)*Xi + x;
    float4 val = *(const float4*)(in + (size_t)vi*32 + c4*4);
    acc.x = fmaxf(acc.x, val.x); acc.y = fmaxf(acc.y, val.y);
    acc.z = fmaxf(acc.z, val.z); acc.w = fmaxf(acc.w, val.w);
  }
  *(float4*)(out + (size_t)v*32 + c4*4) = acc;
}

__global__ void k_pool_x(const float* __restrict__ in, const float* __restrict__ mp,
                         float* __restrict__ out, int Z, int Y, int Xi, int Xo, int nI) {
  int gid = blockIdx.x * blockDim.x + threadIdx.x;
  int perOut = Z * Y * Xo;
  int tot = nI * perOut * 8;
  if (gid >= tot) return;
  int c4 = gid & 7; int v = gid >> 3;
  int item = v / perOut;
  int r = v - item * perOut;
  int x = r % Xo; int t = r / Xo;
  int y = t % Y; int z = t / Y;
  int ib = item * Z * Y * Xi;
  float4 acc = {NINF, NINF, NINF, NINF};
  for (int j = 0; j < 5; j++) {
    int vi = ib + (z*Y + y)*Xi + x + j;
    float4 val = *(const float4*)(in + (size_t)vi*32 + c4*4);
    acc.x = fmaxf(acc.x, val.x); acc.y = fmaxf(acc.y, val.y);
    acc.z = fmaxf(acc.z, val.z); acc.w = fmaxf(acc.w, val.w);
  }
  bool act = mp[v] > 0.f;
  float4 rr;
  rr.x = act ? acc.x : 0.f; rr.y = act ? acc.y : 0.f;
  rr.z = act ? acc.z : 0.f; rr.w = act ? acc.w : 0.f;
  *(float4*)(out + (size_t)v*32 + c4*4) = rr;
}

// ---------------- final pool (C=1, direct 5^3), 21,31,36 -> 17,27,32, batched ------
__global__ void k_pool3(const float* __restrict__ xin, const float* __restrict__ m,
                        const float* __restrict__ mp, float* __restrict__ out, int nI) {
  int gid = blockIdx.x * blockDim.x + threadIdx.x;
  int perOut = 17 * 27 * 32;
  int tot = nI * perOut;
  if (gid >= tot) return;
  int item = gid / perOut;
  int r = gid - item * perOut;
  int x = r & 31; int t = r >> 5;
  int y = t % 27; int z = t / 27;
  const float* xb = xin + (size_t)item * 23436;
  const float* mb = m + (size_t)item * 23436;
  float acc = NINF;
  for (int dz = 0; dz < 5; dz++)
    for (int dy = 0; dy < 5; dy++) {
      const float* rowx = xb + (size_t)(((z + dz)*31 + y + dy)*36 + x);
      const float* rowm = mb + (size_t)(((z + dz)*31 + y + dy)*36 + x);
      for (int dx = 0; dx < 5; dx++)
        if (rowm[dx] > 0.f) acc = fmaxf(acc, rowx[dx]);
    }
  out[gid] = (mp[gid] > 0.f) ? acc : 0.f;
}

// ---------------- FC split-K partial + finalize ----------------
__global__ __launch_bounds__(256, 4)
void k_fc_part(const float* __restrict__ X, const float* __restrict__ Wm,
               float* __restrict__ part, int K, int Ncol, int Kc) {
  __shared__ float sm[16][16][8];
  int ks = blockIdx.y;
  int k0 = ks * Kc;
  int k1 = k0 + Kc; if (k1 > K) k1 = K;
  int cl = threadIdx.x & 15;
  int kt = threadIdx.x >> 4;
  int col = blockIdx.x * 16 + cl;
  float a0=0.f,a1=0.f,a2=0.f,a3=0.f,a4=0.f,a5=0.f,a6=0.f,a7=0.f;
  if (col < Ncol) {
    for (int k = k0 + kt; k < k1; k += 16) {
      float w = Wm[(size_t)k * Ncol + col];
      a0 += X[0 * K + k] * w; a1 += X[1 * K + k] * w;
      a2 += X[2 * K + k] * w; a3 += X[3 * K + k] * w;
      a4 += X[4 * K + k] * w; a5 += X[5 * K + k] * w;
      a6 += X[6 * K + k] * w; a7 += X[7 * K + k] * w;
    }
  }
  sm[kt][cl][0]=a0; sm[kt][cl][1]=a1; sm[kt][cl][2]=a2; sm[kt][cl][3]=a3;
  sm[kt][cl][4]=a4; sm[kt][cl][5]=a5; sm[kt][cl][6]=a6; sm[kt][cl][7]=a7;
  __syncthreads();
  if (threadIdx.x < 128) {
    int c = threadIdx.x & 15;
    int b = threadIdx.x >> 4;
    float s = 0.f;
#pragma unroll
    for (int k = 0; k < 16; k++) s += sm[k][c][b];
    int cc = blockIdx.x * 16 + c;
    if (cc < Ncol) part[((size_t)ks * 8 + b) * Ncol + cc] = s;
  }
}

__global__ void k_fc_fin(const float* __restrict__ part, int ns,
                         const float* __restrict__ bias, float* __restrict__ out, int Ncol) {
  int i = blockIdx.x * blockDim.x + threadIdx.x;
  if (i >= 8 * Ncol) return;
  int b = i / Ncol;
  int c = i - b * Ncol;
  float s = 0.f;
  for (int ks = 0; ks < ns; ks++) s += part[((size_t)ks * 8 + b) * Ncol + c];
  out[i] = lrelu(s + bias[c]);
}

// last FC (K=1000 -> 1), small
__global__ __launch_bounds__(256, 4)
void k_fc(const float* __restrict__ X, const float* __restrict__ Wm,
          const float* __restrict__ bias, float* __restrict__ out,
          int K, int Ncol) {
  __shared__ float sm[16][16][8];
  int cl = threadIdx.x & 15;
  int kt = threadIdx.x >> 4;
  int col = blockIdx.x * 16 + cl;
  float a0=0.f,a1=0.f,a2=0.f,a3=0.f,a4=0.f,a5=0.f,a6=0.f,a7=0.f;
  if (col < Ncol) {
    for (int k = kt; k < K; k += 16) {
      float w = Wm[(size_t)k * Ncol + col];
      a0 += X[0 * K + k] * w; a1 += X[1 * K + k] * w;
      a2 += X[2 * K + k] * w; a3 += X[3 * K + k] * w;
      a4 += X[4 * K + k] * w; a5 += X[5 * K + k] * w;
      a6 += X[6 * K + k] * w; a7 += X[7 * K + k] * w;
    }
  }
  sm[kt][cl][0]=a0; sm[kt][cl][1]=a1; sm[kt][cl][2]=a2; sm[kt][cl][3]=a3;
  sm[kt][cl][4]=a4; sm[kt][cl][5]=a5; sm[kt][cl][6]=a6; sm[kt][cl][7]=a7;
  __syncthreads();
  if (threadIdx.x < 128) {
    int c = threadIdx.x & 15;
    int b = threadIdx.x >> 4;
    float s = 0.f;
#pragma unroll
    for (int k = 0; k < 16; k++) s += sm[k][c][b];
    int cc = blockIdx.x * 16 + c;
    if (cc < Ncol) out[b * Ncol + cc] = lrelu(s + bias[cc]);
  }
}

// ---------------- host ----------------
static inline int G256(long long n) { return (int)((n + 255) / 256); }

extern "C" void kernel_launch(void* const* d_in, const int* in_sizes, int n_in,
                              void* d_out, int out_size, void* d_ws, size_t ws_size,
                              hipStream_t stream) {
  const float* feat  = (const float*)d_in[0];
  const int*   coors = (const int*)d_in[1];
  const float* w1 = (const float*)d_in[3];  const float* b1 = (const float*)d_in[4];
  const float* w2 = (const float*)d_in[5];  const float* b2 = (const float*)d_in[6];
  const float* w3 = (const float*)d_in[7];  const float* b3 = (const float*)d_in[8];
  const float* w4 = (const float*)d_in[9];  const float* b4 = (const float*)d_in[10];
  const float* w5 = (const float*)d_in[11]; const float* b5 = (const float*)d_in[12];
  const float* w6 = (const float*)d_in[13]; const float* b6 = (const float*)d_in[14];
  const float* w7 = (const float*)d_in[15]; const float* b7 = (const float*)d_in[16];
  const float* W8 = (const float*)d_in[17]; const float* b8 = (const float*)d_in[18];
  const float* W9 = (const float*)d_in[19]; const float* b9 = (const float*)d_in[20];
  const float* W10= (const float*)d_in[21]; const float* b10= (const float*)d_in[22];
  float* out = (float*)d_out;

  char* ws = (char*)d_ws;
  size_t off = 0;
  auto alloc = [&](size_t nfloats) -> float* {
    float* p = (float*)(ws + off);
    off += ((nfloats * 4 + 1023) / 1024) * 1024;
    return p;
  };

  // ---- fixed allocations ----
  float* x0  = alloc(1560000);
  float* m0  = alloc(1560000);
  float* m1  = alloc(8 * 166098);
  float* m2  = alloc(8 * 140184);
  float* mp1 = alloc(8 * 110000);
  float* m3  = alloc(8 * 90428);
  float* m4  = alloc(8 * 73304);
  float* mp2 = alloc(8 * 54000);
  float* m5  = alloc(8 * 41958);
  float* m6  = alloc(8 * 31824);
  float* m7  = alloc(8 * 23436);
  float* mp3 = alloc(8 * 14688);
  float* p3  = alloc(8 * 14688);
  float* dt1 = alloc(8 * 183300);   // separable-dilate temps
  float* dt2 = alloc(8 * 174135);
  float* wr1 = alloc(2048);
  float* wr7 = alloc(2048);
  unsigned short* tb2 = (unsigned short*)alloc(131072);   // 512 KB B-frag tables
  unsigned short* tb3 = (unsigned short*)alloc(131072);
  unsigned short* tb4 = (unsigned short*)alloc(131072);
  unsigned short* tb5 = (unsigned short*)alloc(131072);
  unsigned short* tb6 = (unsigned short*)alloc(131072);
  float* part= alloc(64000);
  float* h8  = alloc(8000);
  float* h9  = alloc(8000);
  size_t fixedOff = off;

  // ---- pick group size G from remaining workspace ----
  const size_t perItemAB = ((size_t)5315136*4 + 1023)/1024*1024
                         + ((size_t)4485888*4 + 1023)/1024*1024
                         + ((size_t)23436*4 + 1023)/1024*1024;
  int G = 0;
  for (int g : {8, 4, 2, 1})
    if (fixedOff + (size_t)g * perItemAB <= ws_size) { G = g; break; }
  if (G == 0) return;

  float* A  = alloc((size_t)G * 5315136);
  float* Bb = alloc((size_t)G * 4485888);
  float* x7 = alloc((size_t)G * 23436);
  unsigned* claim = (unsigned*)A;   // claim aliases A (dead before first conv use)

  // ---- init ----
  hipMemsetAsync(claim, 0, 1560000 * 4, stream);
  hipMemsetAsync(x0,    0, 1560000 * 4, stream);
  hipMemsetAsync(m0,    0, 1560000 * 4, stream);

  k_repack<<<G256(32*1*64),  256, 0, stream>>>(w1, wr1, 1, 32);
  k_repack<<<G256(1*32*64),  256, 0, stream>>>(w7, wr7, 32, 1);
  k_repack_mfma<<<128, 256, 0, stream>>>(w2, tb2);
  k_repack_mfma<<<128, 256, 0, stream>>>(w3, tb3);
  k_repack_mfma<<<128, 256, 0, stream>>>(w4, tb4);
  k_repack_mfma<<<128, 256, 0, stream>>>(w5, tb5);
  k_repack_mfma<<<128, 256, 0, stream>>>(w6, tb6);

  const int N = 80000;
  k_claim  <<<G256(N), 256, 0, stream>>>(coors, claim, N);
  k_scatter<<<G256(N), 256, 0, stream>>>(coors, feat, claim, x0, m0, N);

  // ---- separable mask dilations, batched over 8 items ----
  auto dil3 = [&](const float* src, float* dst,
                  int Zi, int Yi, int Xi, int Zo, int Yo, int Xo, int K) {
    kd_z<<<G256((long long)8*Zo*Yi*Xi), 256, 0, stream>>>(src, dt1, Zi,Yi,Xi, Zo, K, 8);
    kd_y<<<G256((long long)8*Zo*Yo*Xi), 256, 0, stream>>>(dt1, dt2, Zo,Yi,Xi, Yo, K, 8);
    kd_x<<<G256((long long)8*Zo*Yo*Xo), 256, 0, stream>>>(dt2, dst, Zo,Yo,Xi, Xo, K, 8);
  };
  dil3(m0,  m1,  50,60,65, 47,57,62, 4);
  dil3(m1,  m2,  47,57,62, 44,54,59, 4);
  dil3(m2,  mp1, 44,54,59, 40,50,55, 5);
  dil3(mp1, m3,  40,50,55, 37,47,52, 4);
  dil3(m3,  m4,  37,47,52, 34,44,49, 4);
  dil3(m4,  mp2, 34,44,49, 30,40,45, 5);
  dil3(mp2, m5,  30,40,45, 27,37,42, 4);
  dil3(m5,  m6,  27,37,42, 24,34,39, 4);
  dil3(m6,  m7,  24,34,39, 21,31,36, 4);
  dil3(m7,  mp3, 21,31,36, 17,27,32, 5);

  auto conv32 = [&](const float* in, const unsigned short* tbl, const float* bias,
                    const float* mo, float* o,
                    int Zi, int Yi, int Xi, int Zo, int Yo, int Xo, int nI) {
    int tz = (Zo + TZ - 1) / TZ, ty = (Yo + TY - 1) / TY, tx = (Xo + TXT - 1) / TXT;
    k_conv32m<<<nI * tz * ty * tx, 256, 0, stream>>>(
        in, tbl, bias, mo, o, Zi, Yi, Xi, Zo, Yo, Xo, tz, ty, tx);
  };

  for (int g0 = 0; g0 < 8; g0 += G) {
    const float* x0g  = x0  + (size_t)g0 * 195000;
    const float* m1g  = m1  + (size_t)g0 * 166098;
    const float* m2g  = m2  + (size_t)g0 * 140184;
    const float* mp1g = mp1 + (size_t)g0 * 110000;
    const float* m3g  = m3  + (size_t)g0 * 90428;
    const float* m4g  = m4  + (size_t)g0 * 73304;
    const float* mp2g = mp2 + (size_t)g0 * 54000;
    const float* m5g  = m5  + (size_t)g0 * 41958;
    const float* m6g  = m6  + (size_t)g0 * 31824;
    const float* m7g  = m7  + (size_t)g0 * 23436;
    const float* mp3g = mp3 + (size_t)g0 * 14688;

    // c1: 50,60,65 -> 47,57,62
    {
      int tz = (47 + TZ - 1) / TZ, ty = (57 + TY - 1) / TY, tx = (62 + TXT - 1) / TXT;
      k_conv1t<<<G * tz * ty * tx, 256, 0, stream>>>(
          x0g, wr1, b1, m1g, A, 50,60,65, 47,57,62, tz, ty, tx);
    }
    // c2 -> 44,54,59
    conv32(A, tb2, b2, m2g, Bb, 47,57,62, 44,54,59, G);
    // p1 -> 40,50,55
    k_pool_z<<<G256((long long)G*127440*8), 256, 0, stream>>>(Bb, m2g,  A,  44,54,59, 40, G);
    k_pool_y<<<G256((long long)G*118000*8), 256, 0, stream>>>(A,  Bb, 40,54,59, 50, G);
    k_pool_x<<<G256((long long)G*110000*8), 256, 0, stream>>>(Bb, mp1g, A,  40,50,59, 55, G);
    // c3 -> 37,47,52
    conv32(A, tb3, b3, m3g, Bb, 40,50,55, 37,47,52, G);
    // c4 -> 34,44,49
    conv32(Bb, tb4, b4, m4g, A, 37,47,52, 34,44,49, G);
    // p2 -> 30,40,45
    k_pool_z<<<G256((long long)G*64680*8), 256, 0, stream>>>(A,  m4g,  Bb, 34,44,49, 30, G);
    k_pool_y<<<G256((long long)G*58800*8), 256, 0, stream>>>(Bb, A,  30,44,49, 40, G);
    k_pool_x<<<G256((long long)G*54000*8), 256, 0, stream>>>(A,  mp2g, Bb, 30,40,49, 45, G);
    // c5 -> 27,37,42
    conv32(Bb, tb5, b5, m5g, A, 30,40,45, 27,37,42, G);
    // c6 -> 24,34,39
    conv32(A, tb6, b6, m6g, Bb, 27,37,42, 24,34,39, G);
    // c7 (32->1) -> 21,31,36
    {
      int tz = (21 + TZ - 1) / TZ, ty = (31 + TY - 1) / TY, tx = (36 + TXT - 1) / TXT;
      k_conv7t<<<G * tz * ty * tx, 256, 0, stream>>>(
          Bb, wr7, b7, m7g, x7, 24,34,39, 21,31,36, tz, ty, tx);
    }
    // p3 -> 17,27,32
    k_pool3<<<G256((long long)G*14688), 256, 0, stream>>>(
        x7, m7g, mp3g, p3 + (size_t)g0 * 14688, G);
  }

  // ---- FC head ----
  k_fc_part<<<dim3(63, 8), 256, 0, stream>>>(p3, W8, part, 14688, 1000, 1836);
  k_fc_fin <<<G256(8000), 256, 0, stream>>>(part, 8, b8, h8, 1000);
  k_fc_part<<<dim3(63, 4), 256, 0, stream>>>(h8, W9, part, 1000, 1000, 250);
  k_fc_fin <<<G256(8000), 256, 0, stream>>>(part, 4, b9, h9, 1000);
  k_fc<<<1, 256, 0, stream>>>(h9, W10, b10, out, 1000, 1);
}